// Round 1
// baseline (500.020 us; speedup 1.0000x reference)
//
#include <hip/hip_runtime.h>
#include <hip/hip_bf16.h>

#define N_NODES 100000
#define N_EDGES 1600000
#define NFEAT 128
#define NHID 128
#define NOUT 64
#define NEG_SLOPE 0.01f
#define NB1 98  // ceil(100000/1024)

__device__ __forceinline__ unsigned short f2b(float f) {
    unsigned u = __float_as_uint(f);
    unsigned r = u + 0x7FFFu + ((u >> 16) & 1u);
    return (unsigned short)(r >> 16);
}
__device__ __forceinline__ float b2f(unsigned short h) {
    return __uint_as_float(((unsigned)h) << 16);
}
__device__ __forceinline__ float lrelu(float v) {
    return v > 0.f ? v : v * NEG_SLOPE;
}

// ---- degree histogram over dst ----
__global__ void k_hist(const int* __restrict__ dst, int* __restrict__ cnt) {
    int e = blockIdx.x * 256 + threadIdx.x;
    if (e < N_EDGES) atomicAdd(&cnt[dst[e]], 1);
}

// ---- dinv = rsqrt(deg), deg = cnt + 1 (self loop) ----
__global__ void k_dinv(const int* __restrict__ cnt, float* __restrict__ dinv) {
    int i = blockIdx.x * 256 + threadIdx.x;
    if (i < N_NODES) dinv[i] = rsqrtf((float)(cnt[i] + 1));
}

// ---- scan stage 1: per-block (1024 elems) exclusive scan into rowptr, block sums out ----
__global__ __launch_bounds__(256) void k_scan1(const int* __restrict__ cnt,
                                               int* __restrict__ rowptr,
                                               int* __restrict__ bsum) {
    __shared__ int sc[256];
    int t = threadIdx.x;
    int base = blockIdx.x * 1024 + t * 4;
    int v0 = (base + 0 < N_NODES) ? cnt[base + 0] : 0;
    int v1 = (base + 1 < N_NODES) ? cnt[base + 1] : 0;
    int v2 = (base + 2 < N_NODES) ? cnt[base + 2] : 0;
    int v3 = (base + 3 < N_NODES) ? cnt[base + 3] : 0;
    int s = v0 + v1 + v2 + v3;
    sc[t] = s;
    __syncthreads();
    for (int off = 1; off < 256; off <<= 1) {
        int xv = (t >= off) ? sc[t - off] : 0;
        __syncthreads();
        sc[t] += xv;
        __syncthreads();
    }
    int pre = sc[t] - s;  // exclusive over threads
    int run = pre;
    if (base + 0 < N_NODES) { rowptr[base + 0] = run; run += v0; }
    if (base + 1 < N_NODES) { rowptr[base + 1] = run; run += v1; }
    if (base + 2 < N_NODES) { rowptr[base + 2] = run; run += v2; }
    if (base + 3 < N_NODES) { rowptr[base + 3] = run; run += v3; }
    if (t == 0) bsum[blockIdx.x] = sc[255];
}

// ---- scan stage 2: scan of block sums (NB1 <= 256) ----
__global__ __launch_bounds__(256) void k_scan2(const int* __restrict__ bsum,
                                               int* __restrict__ tops) {
    __shared__ int sc[256];
    int t = threadIdx.x;
    int s = (t < NB1) ? bsum[t] : 0;
    sc[t] = s;
    __syncthreads();
    for (int off = 1; off < 256; off <<= 1) {
        int xv = (t >= off) ? sc[t - off] : 0;
        __syncthreads();
        sc[t] += xv;
        __syncthreads();
    }
    tops[t] = sc[t] - s;
}

// ---- scan stage 3: add block tops, finalize rowptr[N] ----
__global__ void k_scan3(int* __restrict__ rowptr, const int* __restrict__ tops) {
    int i = blockIdx.x * 256 + threadIdx.x;
    if (i < N_NODES) rowptr[i] += tops[i >> 10];
    if (i == 0) rowptr[N_NODES] = N_EDGES;
}

// ---- fill CSR: entry = {src, dinv[src]} grouped by dst ----
__global__ void k_fill(const int* __restrict__ src, const int* __restrict__ dst,
                       const float* __restrict__ dinv, const int* __restrict__ rowptr,
                       int* __restrict__ cursor, uint2* __restrict__ csr) {
    int e = blockIdx.x * 256 + threadIdx.x;
    if (e < N_EDGES) {
        int s = src[e], d = dst[e];
        int p = rowptr[d] + atomicAdd(&cursor[d], 1);
        csr[p] = make_uint2((unsigned)s, __float_as_uint(dinv[s]));
    }
}

// ---- fused GEMM1: h1 = x@w1 (bf16 out), identity = x@wd + bd (f32 out) ----
// block: 256 thr, 64 rows x 192 cols, micro-tile 4x12
__global__ __launch_bounds__(256) void k_gemm1(const float* __restrict__ x,
                                               const float* __restrict__ w1,
                                               const float* __restrict__ wd,
                                               const float* __restrict__ bd,
                                               unsigned short* __restrict__ h1,
                                               float* __restrict__ identity) {
    __shared__ float xs[64][33];
    __shared__ float ws[32][192];
    const int t = threadIdx.x;
    const int ty = t >> 4, tx = t & 15;
    const int rb = blockIdx.x * 64;
    float acc[4][12];
#pragma unroll
    for (int r = 0; r < 4; r++)
#pragma unroll
        for (int c = 0; c < 12; c++) acc[r][c] = 0.f;

    for (int k0 = 0; k0 < 128; k0 += 32) {
        // x tile: 64 rows x 32 k
#pragma unroll
        for (int p = 0; p < 2; p++) {
            int row = (t >> 3) + p * 32;
            int q = t & 7;
            int grow = rb + row;
            float4 val = make_float4(0.f, 0.f, 0.f, 0.f);
            if (grow < N_NODES) val = *(const float4*)&x[grow * 128 + k0 + q * 4];
            xs[row][q * 4 + 0] = val.x;
            xs[row][q * 4 + 1] = val.y;
            xs[row][q * 4 + 2] = val.z;
            xs[row][q * 4 + 3] = val.w;
        }
        // w tile: 32 k x 192 cols (w1 cols 0..127, wd cols 128..191)
#pragma unroll
        for (int p = 0; p < 6; p++) {
            int slot = p * 256 + t;      // 0..1535 float4 slots
            int k = slot / 48;
            int col = (slot % 48) * 4;
            float4 wv;
            if (col < 128) wv = *(const float4*)&w1[(k0 + k) * 128 + col];
            else           wv = *(const float4*)&wd[(k0 + k) * 64 + (col - 128)];
            *(float4*)&ws[k][col] = wv;
        }
        __syncthreads();
#pragma unroll
        for (int kk = 0; kk < 32; kk++) {
            float xr[4];
#pragma unroll
            for (int r = 0; r < 4; r++) xr[r] = xs[ty * 4 + r][kk];
            float wr[12];
            *(float4*)&wr[0] = *(float4*)&ws[kk][tx * 12 + 0];
            *(float4*)&wr[4] = *(float4*)&ws[kk][tx * 12 + 4];
            *(float4*)&wr[8] = *(float4*)&ws[kk][tx * 12 + 8];
#pragma unroll
            for (int r = 0; r < 4; r++)
#pragma unroll
                for (int c = 0; c < 12; c++) acc[r][c] = fmaf(xr[r], wr[c], acc[r][c]);
        }
        __syncthreads();
    }
#pragma unroll
    for (int r = 0; r < 4; r++) {
        int grow = rb + ty * 4 + r;
        if (grow >= N_NODES) continue;
#pragma unroll
        for (int c = 0; c < 12; c++) {
            int col = tx * 12 + c;
            float v = acc[r][c];
            if (col < 128) h1[grow * 128 + col] = f2b(v);
            else           identity[grow * 64 + (col - 128)] = v + bd[col - 128];
        }
    }
}

// ---- GEMM2: h2 = out1(bf16) @ w2 -> bf16, 64 rows x 64 cols per block, micro 4x4 ----
__global__ __launch_bounds__(256) void k_gemm2(const unsigned short* __restrict__ a,
                                               const float* __restrict__ w2,
                                               unsigned short* __restrict__ h2) {
    __shared__ float xs[64][33];
    __shared__ float ws[32][64];
    const int t = threadIdx.x;
    const int ty = t >> 4, tx = t & 15;
    const int rb = blockIdx.x * 64;
    float acc[4][4];
#pragma unroll
    for (int r = 0; r < 4; r++)
#pragma unroll
        for (int c = 0; c < 4; c++) acc[r][c] = 0.f;

    for (int k0 = 0; k0 < 128; k0 += 32) {
#pragma unroll
        for (int p = 0; p < 2; p++) {
            int row = (t >> 3) + p * 32;
            int q = t & 7;
            int grow = rb + row;
            ushort4 hv = make_ushort4(0, 0, 0, 0);
            if (grow < N_NODES) hv = *(const ushort4*)&a[grow * 128 + k0 + q * 4];
            xs[row][q * 4 + 0] = b2f(hv.x);
            xs[row][q * 4 + 1] = b2f(hv.y);
            xs[row][q * 4 + 2] = b2f(hv.z);
            xs[row][q * 4 + 3] = b2f(hv.w);
        }
#pragma unroll
        for (int p = 0; p < 2; p++) {
            int slot = p * 256 + t;   // 0..511 float4 slots (32x16)
            int k = slot >> 4;
            int col = (slot & 15) * 4;
            *(float4*)&ws[k][col] = *(const float4*)&w2[(k0 + k) * 64 + col];
        }
        __syncthreads();
#pragma unroll
        for (int kk = 0; kk < 32; kk++) {
            float xr[4];
#pragma unroll
            for (int r = 0; r < 4; r++) xr[r] = xs[ty * 4 + r][kk];
            float4 wv = *(float4*)&ws[kk][tx * 4];
#pragma unroll
            for (int r = 0; r < 4; r++) {
                acc[r][0] = fmaf(xr[r], wv.x, acc[r][0]);
                acc[r][1] = fmaf(xr[r], wv.y, acc[r][1]);
                acc[r][2] = fmaf(xr[r], wv.z, acc[r][2]);
                acc[r][3] = fmaf(xr[r], wv.w, acc[r][3]);
            }
        }
        __syncthreads();
    }
#pragma unroll
    for (int r = 0; r < 4; r++) {
        int grow = rb + ty * 4 + r;
        if (grow >= N_NODES) continue;
#pragma unroll
        for (int c = 0; c < 4; c++) h2[grow * 64 + tx * 4 + c] = f2b(acc[r][c]);
    }
}

// ---- aggregate 1: out1 = leaky(sum_e norm*h1[src] + dinv^2*h1[i] + b1), 128 feats ----
// one wave per node, lane handles 2 feats
__global__ __launch_bounds__(256) void k_agg1(const unsigned short* __restrict__ h1,
                                              const uint2* __restrict__ csr,
                                              const int* __restrict__ rowptr,
                                              const float* __restrict__ dinv,
                                              const float* __restrict__ b1,
                                              unsigned short* __restrict__ out1) {
    int node = blockIdx.x * 4 + (threadIdx.x >> 6);
    int lane = threadIdx.x & 63;
    if (node >= N_NODES) return;
    float di = dinv[node];
    // self loop
    ushort2 hv = *(const ushort2*)&h1[node * 128 + lane * 2];
    float c0 = di * di;
    float a0 = c0 * b2f(hv.x);
    float a1 = c0 * b2f(hv.y);
    int beg = rowptr[node], end = rowptr[node + 1];
    for (int e0 = beg; e0 < end; e0 += 64) {
        int m = end - e0; if (m > 64) m = 64;
        uint2 ce = (lane < m) ? csr[e0 + lane] : make_uint2(0u, 0u);
        int s_l = (int)ce.x;
        float w_l = __uint_as_float(ce.y);
        for (int j = 0; j < m; j++) {
            int s = __shfl(s_l, j);
            float w = __shfl(w_l, j) * di;
            ushort2 h = *(const ushort2*)&h1[s * 128 + lane * 2];
            a0 = fmaf(w, b2f(h.x), a0);
            a1 = fmaf(w, b2f(h.y), a1);
        }
    }
    int f = lane * 2;
    float o0 = lrelu(a0 + b1[f]);
    float o1 = lrelu(a1 + b1[f + 1]);
    ushort2 ov; ov.x = f2b(o0); ov.y = f2b(o1);
    *(ushort2*)&out1[node * 128 + f] = ov;
}

// ---- aggregate 2 + epilogue: out = leaky(agg(h2) + b2) + identity, 64 feats ----
__global__ __launch_bounds__(256) void k_agg2(const unsigned short* __restrict__ h2,
                                              const uint2* __restrict__ csr,
                                              const int* __restrict__ rowptr,
                                              const float* __restrict__ dinv,
                                              const float* __restrict__ b2,
                                              const float* __restrict__ identity,
                                              float* __restrict__ out) {
    int node = blockIdx.x * 4 + (threadIdx.x >> 6);
    int lane = threadIdx.x & 63;
    if (node >= N_NODES) return;
    float di = dinv[node];
    float acc = di * di * b2f(h2[node * 64 + lane]);
    int beg = rowptr[node], end = rowptr[node + 1];
    for (int e0 = beg; e0 < end; e0 += 64) {
        int m = end - e0; if (m > 64) m = 64;
        uint2 ce = (lane < m) ? csr[e0 + lane] : make_uint2(0u, 0u);
        int s_l = (int)ce.x;
        float w_l = __uint_as_float(ce.y);
        for (int j = 0; j < m; j++) {
            int s = __shfl(s_l, j);
            float w = __shfl(w_l, j) * di;
            acc = fmaf(w, b2f(h2[s * 64 + lane]), acc);
        }
    }
    float o = lrelu(acc + b2[lane]) + identity[node * 64 + lane];
    out[node * 64 + lane] = o;
}

extern "C" void kernel_launch(void* const* d_in, const int* in_sizes, int n_in,
                              void* d_out, int out_size, void* d_ws, size_t ws_size,
                              hipStream_t stream) {
    const float* x  = (const float*)d_in[0];
    const int* eidx = (const int*)d_in[1];
    const float* w1 = (const float*)d_in[2];
    const float* b1 = (const float*)d_in[3];
    const float* w2 = (const float*)d_in[4];
    const float* b2 = (const float*)d_in[5];
    const float* wd = (const float*)d_in[6];
    const float* bd = (const float*)d_in[7];
    const int* src = eidx;
    const int* dst = eidx + N_EDGES;
    float* out = (float*)d_out;

    char* ws = (char*)d_ws;
    size_t off = 0;
    auto take = [&](size_t bytes) -> char* {
        char* p = ws + off;
        off = (off + bytes + 255) & ~(size_t)255;
        return p;
    };
    int* cnt        = (int*)take((size_t)N_NODES * 4);
    int* rowptr     = (int*)take((size_t)(N_NODES + 1) * 4);
    int* cursor     = (int*)take((size_t)N_NODES * 4);
    float* dinv     = (float*)take((size_t)N_NODES * 4);
    int* bsum       = (int*)take(256 * 4);
    int* tops       = (int*)take(256 * 4);
    uint2* csr      = (uint2*)take((size_t)N_EDGES * 8);
    unsigned short* h1   = (unsigned short*)take((size_t)N_NODES * 128 * 2);
    unsigned short* out1 = (unsigned short*)take((size_t)N_NODES * 128 * 2);
    unsigned short* h2   = (unsigned short*)take((size_t)N_NODES * 64 * 2);
    float* identity = (float*)take((size_t)N_NODES * 64 * 4);

    hipMemsetAsync(cnt, 0, (size_t)N_NODES * 4, stream);
    hipMemsetAsync(cursor, 0, (size_t)N_NODES * 4, stream);

    k_hist<<<(N_EDGES + 255) / 256, 256, 0, stream>>>(dst, cnt);
    k_dinv<<<(N_NODES + 255) / 256, 256, 0, stream>>>(cnt, dinv);
    k_scan1<<<NB1, 256, 0, stream>>>(cnt, rowptr, bsum);
    k_scan2<<<1, 256, 0, stream>>>(bsum, tops);
    k_scan3<<<(N_NODES + 255) / 256, 256, 0, stream>>>(rowptr, tops);
    k_fill<<<(N_EDGES + 255) / 256, 256, 0, stream>>>(src, dst, dinv, rowptr, cursor, csr);
    k_gemm1<<<(N_NODES + 63) / 64, 256, 0, stream>>>(x, w1, wd, bd, h1, identity);
    k_agg1<<<(N_NODES + 3) / 4, 256, 0, stream>>>(h1, csr, rowptr, dinv, b1, out1);
    k_gemm2<<<(N_NODES + 63) / 64, 256, 0, stream>>>(out1, w2, h2);
    k_agg2<<<(N_NODES + 3) / 4, 256, 0, stream>>>(h2, csr, rowptr, dinv, b2, identity, out);
}

// Round 4
// 437.559 us; speedup vs baseline: 1.1427x; 1.1427x over previous
//
#include <hip/hip_runtime.h>
#include <hip/hip_bf16.h>

#define N_NODES 100000
#define N_EDGES 1600000
#define NFEAT 128
#define NHID 128
#define NOUT 64
#define NEG_SLOPE 0.01f
#define NB1 98  // ceil(100000/1024)
#define LDA 136 // 128 + 8 pad (bf16) — row stride 272B, keeps 16B alignment for b128 LDS ops

typedef short bf16x8 __attribute__((ext_vector_type(8)));
typedef float f32x4 __attribute__((ext_vector_type(4)));

__device__ __forceinline__ unsigned short f2b(float f) {
    unsigned u = __float_as_uint(f);
    unsigned r = u + 0x7FFFu + ((u >> 16) & 1u);
    return (unsigned short)(r >> 16);
}
__device__ __forceinline__ float b2f(unsigned short h) {
    return __uint_as_float(((unsigned)h) << 16);
}
__device__ __forceinline__ float lrelu(float v) {
    return v > 0.f ? v : v * NEG_SLOPE;
}

// ---- degree histogram over dst ----
__global__ void k_hist(const int* __restrict__ dst, int* __restrict__ cnt) {
    int e = blockIdx.x * 256 + threadIdx.x;
    if (e < N_EDGES) atomicAdd(&cnt[dst[e]], 1);
}

// ---- dinv = rsqrt(deg), deg = cnt + 1 (self loop) ----
__global__ void k_dinv(const int* __restrict__ cnt, float* __restrict__ dinv) {
    int i = blockIdx.x * 256 + threadIdx.x;
    if (i < N_NODES) dinv[i] = rsqrtf((float)(cnt[i] + 1));
}

// ---- transposed bf16 weights: wT[192][128] = [w1 | wd]^T, w2T[64][128] ----
__global__ void k_prep(const float* __restrict__ w1, const float* __restrict__ wd,
                       const float* __restrict__ w2,
                       unsigned short* __restrict__ wT, unsigned short* __restrict__ w2T) {
    int i = blockIdx.x * 256 + threadIdx.x;
    if (i < 192 * 128) {
        int n = i >> 7, k = i & 127;
        float v = (n < 128) ? w1[k * 128 + n] : wd[k * 64 + (n - 128)];
        wT[i] = f2b(v);
    }
    if (i < 64 * 128) {
        int n = i >> 7, k = i & 127;
        w2T[i] = f2b(w2[k * 64 + n]);
    }
}

// ---- scan stage 1 ----
__global__ __launch_bounds__(256) void k_scan1(const int* __restrict__ cnt,
                                               int* __restrict__ rowptr,
                                               int* __restrict__ bsum) {
    __shared__ int sc[256];
    int t = threadIdx.x;
    int base = blockIdx.x * 1024 + t * 4;
    int v0 = (base + 0 < N_NODES) ? cnt[base + 0] : 0;
    int v1 = (base + 1 < N_NODES) ? cnt[base + 1] : 0;
    int v2 = (base + 2 < N_NODES) ? cnt[base + 2] : 0;
    int v3 = (base + 3 < N_NODES) ? cnt[base + 3] : 0;
    int s = v0 + v1 + v2 + v3;
    sc[t] = s;
    __syncthreads();
    for (int off = 1; off < 256; off <<= 1) {
        int xv = (t >= off) ? sc[t - off] : 0;
        __syncthreads();
        sc[t] += xv;
        __syncthreads();
    }
    int run = sc[t] - s;
    if (base + 0 < N_NODES) { rowptr[base + 0] = run; run += v0; }
    if (base + 1 < N_NODES) { rowptr[base + 1] = run; run += v1; }
    if (base + 2 < N_NODES) { rowptr[base + 2] = run; run += v2; }
    if (base + 3 < N_NODES) { rowptr[base + 3] = run; run += v3; }
    if (t == 0) bsum[blockIdx.x] = sc[255];
}

// ---- scan stage 2 ----
__global__ __launch_bounds__(256) void k_scan2(const int* __restrict__ bsum,
                                               int* __restrict__ tops) {
    __shared__ int sc[256];
    int t = threadIdx.x;
    int s = (t < NB1) ? bsum[t] : 0;
    sc[t] = s;
    __syncthreads();
    for (int off = 1; off < 256; off <<= 1) {
        int xv = (t >= off) ? sc[t - off] : 0;
        __syncthreads();
        sc[t] += xv;
        __syncthreads();
    }
    tops[t] = sc[t] - s;
}

// ---- scan stage 3 ----
__global__ void k_scan3(int* __restrict__ rowptr, const int* __restrict__ tops) {
    int i = blockIdx.x * 256 + threadIdx.x;
    if (i < N_NODES) rowptr[i] += tops[i >> 10];
    if (i == 0) rowptr[N_NODES] = N_EDGES;
}

// ---- fill CSR: entry = {src, dinv[src]} grouped by dst ----
__global__ void k_fill(const int* __restrict__ src, const int* __restrict__ dst,
                       const float* __restrict__ dinv, const int* __restrict__ rowptr,
                       int* __restrict__ cursor, uint2* __restrict__ csr) {
    int e = blockIdx.x * 256 + threadIdx.x;
    if (e < N_EDGES) {
        int s = src[e], d = dst[e];
        int p = rowptr[d] + atomicAdd(&cursor[d], 1);
        csr[p] = make_uint2((unsigned)s, __float_as_uint(dinv[s]));
    }
}

// ---- MFMA GEMM1: h1 = bf16(x@w1), identity = x@wd + bd ----
// block 256 thr = 4 waves (2x2), tile 128 rows x 192 cols, full K=128 in LDS
__global__ __launch_bounds__(256) void k_gemm1(const float* __restrict__ x,
                                               const unsigned short* __restrict__ wT,
                                               const float* __restrict__ bd,
                                               unsigned short* __restrict__ h1,
                                               float* __restrict__ identity) {
    __shared__ unsigned short As[128][LDA];
    const int t = threadIdx.x;
    const int rb = blockIdx.x * 128;
    {
        int row = t >> 1, half = t & 1;
        int grow = rb + row;
        if (grow < N_NODES) {
            const float* srcp = &x[(size_t)grow * 128 + half * 64];
#pragma unroll
            for (int i = 0; i < 8; i++) {
                float4 va = *(const float4*)&srcp[i * 8];
                float4 vb = *(const float4*)&srcp[i * 8 + 4];
                unsigned short u[8];
                u[0] = f2b(va.x); u[1] = f2b(va.y); u[2] = f2b(va.z); u[3] = f2b(va.w);
                u[4] = f2b(vb.x); u[5] = f2b(vb.y); u[6] = f2b(vb.z); u[7] = f2b(vb.w);
                *(bf16x8*)&As[row][half * 64 + i * 8] = *(bf16x8*)u;
            }
        } else {
            bf16x8 z = (bf16x8){0, 0, 0, 0, 0, 0, 0, 0};
#pragma unroll
            for (int i = 0; i < 8; i++) *(bf16x8*)&As[row][half * 64 + i * 8] = z;
        }
    }
    __syncthreads();
    const int wid = t >> 6, lane = t & 63;
    const int wr = wid >> 1, wc = wid & 1;
    const int mr = wr * 64, nc = wc * 96;
    const int lrow = lane & 15, lk = (lane >> 4) * 8;
    f32x4 acc[4][6];
#pragma unroll
    for (int m = 0; m < 4; m++)
#pragma unroll
        for (int n = 0; n < 6; n++) acc[m][n] = (f32x4){0.f, 0.f, 0.f, 0.f};

#pragma unroll
    for (int ki = 0; ki < 4; ki++) {
        const int k0 = ki * 32;
        bf16x8 a[4];
#pragma unroll
        for (int m = 0; m < 4; m++)
            a[m] = *(const bf16x8*)&As[mr + m * 16 + lrow][k0 + lk];
#pragma unroll
        for (int n = 0; n < 6; n++) {
            bf16x8 b = *(const bf16x8*)&wT[(size_t)(nc + n * 16 + lrow) * 128 + k0 + lk];
#pragma unroll
            for (int m = 0; m < 4; m++)
                acc[m][n] = __builtin_amdgcn_mfma_f32_16x16x32_bf16(a[m], b, acc[m][n], 0, 0, 0);
        }
    }
    const int crow0 = (lane >> 4) * 4;
#pragma unroll
    for (int m = 0; m < 4; m++) {
#pragma unroll
        for (int j = 0; j < 4; j++) {
            int grow = rb + mr + m * 16 + crow0 + j;
            if (grow >= N_NODES) continue;
#pragma unroll
            for (int n = 0; n < 6; n++) {
                int col = nc + n * 16 + lrow;
                float v = acc[m][n][j];
                if (col < 128) h1[(size_t)grow * 128 + col] = f2b(v);
                else           identity[(size_t)grow * 64 + (col - 128)] = v + bd[col - 128];
            }
        }
    }
}

// ---- MFMA GEMM2: h2 = bf16(out1 @ w2), tile 128 x 64 ----
__global__ __launch_bounds__(256) void k_gemm2(const unsigned short* __restrict__ a_in,
                                               const unsigned short* __restrict__ w2T,
                                               unsigned short* __restrict__ h2) {
    __shared__ unsigned short As[128][LDA];
    const int t = threadIdx.x;
    const int rb = blockIdx.x * 128;
    {
        int row = t >> 1, half = t & 1;
        int grow = rb + row;
        if (grow < N_NODES) {
            // 128 bf16 per row; each half-thread stages 64 bf16 = 8 x bf16x8
#pragma unroll
            for (int i = 0; i < 8; i++)
                *(bf16x8*)&As[row][half * 64 + i * 8] =
                    *(const bf16x8*)&a_in[(size_t)grow * 128 + half * 64 + i * 8];
        } else {
            bf16x8 z = (bf16x8){0, 0, 0, 0, 0, 0, 0, 0};
#pragma unroll
            for (int i = 0; i < 8; i++) *(bf16x8*)&As[row][half * 64 + i * 8] = z;
        }
    }
    __syncthreads();
    const int wid = t >> 6, lane = t & 63;
    const int wr = wid >> 1, wc = wid & 1;
    const int mr = wr * 64, nc = wc * 32;
    const int lrow = lane & 15, lk = (lane >> 4) * 8;
    f32x4 acc[4][2];
#pragma unroll
    for (int m = 0; m < 4; m++)
#pragma unroll
        for (int n = 0; n < 2; n++) acc[m][n] = (f32x4){0.f, 0.f, 0.f, 0.f};

#pragma unroll
    for (int ki = 0; ki < 4; ki++) {
        const int k0 = ki * 32;
        bf16x8 a[4];
#pragma unroll
        for (int m = 0; m < 4; m++)
            a[m] = *(const bf16x8*)&As[mr + m * 16 + lrow][k0 + lk];
#pragma unroll
        for (int n = 0; n < 2; n++) {
            bf16x8 b = *(const bf16x8*)&w2T[(size_t)(nc + n * 16 + lrow) * 128 + k0 + lk];
#pragma unroll
            for (int m = 0; m < 4; m++)
                acc[m][n] = __builtin_amdgcn_mfma_f32_16x16x32_bf16(a[m], b, acc[m][n], 0, 0, 0);
        }
    }
    const int crow0 = (lane >> 4) * 4;
#pragma unroll
    for (int m = 0; m < 4; m++) {
#pragma unroll
        for (int j = 0; j < 4; j++) {
            int grow = rb + mr + m * 16 + crow0 + j;
            if (grow >= N_NODES) continue;
#pragma unroll
            for (int n = 0; n < 2; n++) {
                int col = nc + n * 16 + lrow;
                h2[(size_t)grow * 64 + col] = f2b(acc[m][n][j]);
            }
        }
    }
}

// ---- aggregate 1: out1 = leaky(sum_e norm*h1[src] + dinv^2*h1[i] + b1), 128 feats ----
__global__ __launch_bounds__(256) void k_agg1(const unsigned short* __restrict__ h1,
                                              const uint2* __restrict__ csr,
                                              const int* __restrict__ rowptr,
                                              const float* __restrict__ dinv,
                                              const float* __restrict__ b1,
                                              unsigned short* __restrict__ out1) {
    int node = blockIdx.x * 4 + (threadIdx.x >> 6);
    int lane = threadIdx.x & 63;
    if (node >= N_NODES) return;
    float di = dinv[node];
    ushort2 hv = *(const ushort2*)&h1[node * 128 + lane * 2];
    float c0 = di * di;
    float a0 = c0 * b2f(hv.x);
    float a1 = c0 * b2f(hv.y);
    int beg = rowptr[node], end = rowptr[node + 1];
    for (int e0 = beg; e0 < end; e0 += 64) {
        int m = end - e0; if (m > 64) m = 64;
        uint2 ce = (lane < m) ? csr[e0 + lane] : make_uint2(0u, 0u);
        int s_l = (int)ce.x;
        float w_l = __uint_as_float(ce.y);
        for (int j = 0; j < m; j++) {
            int s = __shfl(s_l, j);
            float w = __shfl(w_l, j) * di;
            ushort2 h = *(const ushort2*)&h1[s * 128 + lane * 2];
            a0 = fmaf(w, b2f(h.x), a0);
            a1 = fmaf(w, b2f(h.y), a1);
        }
    }
    int f = lane * 2;
    float o0 = lrelu(a0 + b1[f]);
    float o1 = lrelu(a1 + b1[f + 1]);
    ushort2 ov; ov.x = f2b(o0); ov.y = f2b(o1);
    *(ushort2*)&out1[node * 128 + f] = ov;
}

// ---- aggregate 2 + epilogue ----
__global__ __launch_bounds__(256) void k_agg2(const unsigned short* __restrict__ h2,
                                              const uint2* __restrict__ csr,
                                              const int* __restrict__ rowptr,
                                              const float* __restrict__ dinv,
                                              const float* __restrict__ b2,
                                              const float* __restrict__ identity,
                                              float* __restrict__ out) {
    int node = blockIdx.x * 4 + (threadIdx.x >> 6);
    int lane = threadIdx.x & 63;
    if (node >= N_NODES) return;
    float di = dinv[node];
    float acc = di * di * b2f(h2[node * 64 + lane]);
    int beg = rowptr[node], end = rowptr[node + 1];
    for (int e0 = beg; e0 < end; e0 += 64) {
        int m = end - e0; if (m > 64) m = 64;
        uint2 ce = (lane < m) ? csr[e0 + lane] : make_uint2(0u, 0u);
        int s_l = (int)ce.x;
        float w_l = __uint_as_float(ce.y);
        for (int j = 0; j < m; j++) {
            int s = __shfl(s_l, j);
            float w = __shfl(w_l, j) * di;
            acc = fmaf(w, b2f(h2[s * 64 + lane]), acc);
        }
    }
    float o = lrelu(acc + b2[lane]) + identity[node * 64 + lane];
    out[node * 64 + lane] = o;
}

extern "C" void kernel_launch(void* const* d_in, const int* in_sizes, int n_in,
                              void* d_out, int out_size, void* d_ws, size_t ws_size,
                              hipStream_t stream) {
    const float* x  = (const float*)d_in[0];
    const int* eidx = (const int*)d_in[1];
    const float* w1 = (const float*)d_in[2];
    const float* b1 = (const float*)d_in[3];
    const float* w2 = (const float*)d_in[4];
    const float* b2 = (const float*)d_in[5];
    const float* wd = (const float*)d_in[6];
    const float* bd = (const float*)d_in[7];
    const int* src = eidx;
    const int* dst = eidx + N_EDGES;
    float* out = (float*)d_out;

    char* ws = (char*)d_ws;
    size_t off = 0;
    auto take = [&](size_t bytes) -> char* {
        char* p = ws + off;
        off = (off + bytes + 255) & ~(size_t)255;
        return p;
    };
    int* cnt        = (int*)take((size_t)N_NODES * 4);
    int* rowptr     = (int*)take((size_t)(N_NODES + 1) * 4);
    int* cursor     = (int*)take((size_t)N_NODES * 4);
    float* dinv     = (float*)take((size_t)N_NODES * 4);
    int* bsum       = (int*)take(256 * 4);
    int* tops       = (int*)take(256 * 4);
    uint2* csr      = (uint2*)take((size_t)N_EDGES * 8);
    unsigned short* h1   = (unsigned short*)take((size_t)N_NODES * 128 * 2);
    unsigned short* out1 = (unsigned short*)take((size_t)N_NODES * 128 * 2);
    unsigned short* h2   = (unsigned short*)take((size_t)N_NODES * 64 * 2);
    float* identity = (float*)take((size_t)N_NODES * 64 * 4);
    unsigned short* wT   = (unsigned short*)take((size_t)192 * 128 * 2);
    unsigned short* w2T  = (unsigned short*)take((size_t)64 * 128 * 2);

    hipMemsetAsync(cnt, 0, (size_t)N_NODES * 4, stream);
    hipMemsetAsync(cursor, 0, (size_t)N_NODES * 4, stream);

    k_hist<<<(N_EDGES + 255) / 256, 256, 0, stream>>>(dst, cnt);
    k_prep<<<(192 * 128 + 255) / 256, 256, 0, stream>>>(w1, wd, w2, wT, w2T);
    k_dinv<<<(N_NODES + 255) / 256, 256, 0, stream>>>(cnt, dinv);
    k_scan1<<<NB1, 256, 0, stream>>>(cnt, rowptr, bsum);
    k_scan2<<<1, 256, 0, stream>>>(bsum, tops);
    k_scan3<<<(N_NODES + 255) / 256, 256, 0, stream>>>(rowptr, tops);
    k_fill<<<(N_EDGES + 255) / 256, 256, 0, stream>>>(src, dst, dinv, rowptr, cursor, csr);
    k_gemm1<<<(N_NODES + 127) / 128, 256, 0, stream>>>(x, wT, bd, h1, identity);
    k_agg1<<<(N_NODES + 3) / 4, 256, 0, stream>>>(h1, csr, rowptr, dinv, b1, out1);
    k_gemm2<<<(N_NODES + 127) / 128, 256, 0, stream>>>(out1, w2T, h2);
    k_agg2<<<(N_NODES + 3) / 4, 256, 0, stream>>>(h2, csr, rowptr, dinv, b2, identity, out);
}

// Round 5
// 374.264 us; speedup vs baseline: 1.3360x; 1.1691x over previous
//
#include <hip/hip_runtime.h>
#include <hip/hip_bf16.h>

#define N_NODES 100000
#define N_EDGES 1600000
#define NFEAT 128
#define NHID 128
#define NOUT 64
#define NEG_SLOPE 0.01f
#define NB1 98  // ceil(100000/1024)
#define LDA 136 // 128 + 8 pad (bf16) — row stride 272B, keeps 16B alignment for b128 LDS ops

typedef short bf16x8 __attribute__((ext_vector_type(8)));
typedef float f32x4 __attribute__((ext_vector_type(4)));

__device__ __forceinline__ unsigned short f2b(float f) {
    unsigned u = __float_as_uint(f);
    unsigned r = u + 0x7FFFu + ((u >> 16) & 1u);
    return (unsigned short)(r >> 16);
}
__device__ __forceinline__ float b2f(unsigned short h) {
    return __uint_as_float(((unsigned)h) << 16);
}
__device__ __forceinline__ float blo(unsigned d) { return __uint_as_float(d << 16); }
__device__ __forceinline__ float bhi(unsigned d) { return __uint_as_float(d & 0xFFFF0000u); }
__device__ __forceinline__ float lrelu(float v) {
    return v > 0.f ? v : v * NEG_SLOPE;
}

// ---- degree histogram over dst ----
__global__ void k_hist(const int* __restrict__ dst, int* __restrict__ cnt) {
    int e = blockIdx.x * 256 + threadIdx.x;
    if (e < N_EDGES) atomicAdd(&cnt[dst[e]], 1);
}

// ---- dinv = rsqrt(deg), deg = cnt + 1 (self loop) ----
__global__ void k_dinv(const int* __restrict__ cnt, float* __restrict__ dinv) {
    int i = blockIdx.x * 256 + threadIdx.x;
    if (i < N_NODES) dinv[i] = rsqrtf((float)(cnt[i] + 1));
}

// ---- transposed bf16 weights: wT[192][128] = [w1 | wd]^T, w2T[64][128] ----
__global__ void k_prep(const float* __restrict__ w1, const float* __restrict__ wd,
                       const float* __restrict__ w2,
                       unsigned short* __restrict__ wT, unsigned short* __restrict__ w2T) {
    int i = blockIdx.x * 256 + threadIdx.x;
    if (i < 192 * 128) {
        int n = i >> 7, k = i & 127;
        float v = (n < 128) ? w1[k * 128 + n] : wd[k * 64 + (n - 128)];
        wT[i] = f2b(v);
    }
    if (i < 64 * 128) {
        int n = i >> 7, k = i & 127;
        w2T[i] = f2b(w2[k * 64 + n]);
    }
}

// ---- scan stage 1 ----
__global__ __launch_bounds__(256) void k_scan1(const int* __restrict__ cnt,
                                               int* __restrict__ rowptr,
                                               int* __restrict__ bsum) {
    __shared__ int sc[256];
    int t = threadIdx.x;
    int base = blockIdx.x * 1024 + t * 4;
    int v0 = (base + 0 < N_NODES) ? cnt[base + 0] : 0;
    int v1 = (base + 1 < N_NODES) ? cnt[base + 1] : 0;
    int v2 = (base + 2 < N_NODES) ? cnt[base + 2] : 0;
    int v3 = (base + 3 < N_NODES) ? cnt[base + 3] : 0;
    int s = v0 + v1 + v2 + v3;
    sc[t] = s;
    __syncthreads();
    for (int off = 1; off < 256; off <<= 1) {
        int xv = (t >= off) ? sc[t - off] : 0;
        __syncthreads();
        sc[t] += xv;
        __syncthreads();
    }
    int run = sc[t] - s;
    if (base + 0 < N_NODES) { rowptr[base + 0] = run; run += v0; }
    if (base + 1 < N_NODES) { rowptr[base + 1] = run; run += v1; }
    if (base + 2 < N_NODES) { rowptr[base + 2] = run; run += v2; }
    if (base + 3 < N_NODES) { rowptr[base + 3] = run; run += v3; }
    if (t == 0) bsum[blockIdx.x] = sc[255];
}

// ---- scan stage 2 ----
__global__ __launch_bounds__(256) void k_scan2(const int* __restrict__ bsum,
                                               int* __restrict__ tops) {
    __shared__ int sc[256];
    int t = threadIdx.x;
    int s = (t < NB1) ? bsum[t] : 0;
    sc[t] = s;
    __syncthreads();
    for (int off = 1; off < 256; off <<= 1) {
        int xv = (t >= off) ? sc[t - off] : 0;
        __syncthreads();
        sc[t] += xv;
        __syncthreads();
    }
    tops[t] = sc[t] - s;
}

// ---- scan stage 3 ----
__global__ void k_scan3(int* __restrict__ rowptr, const int* __restrict__ tops) {
    int i = blockIdx.x * 256 + threadIdx.x;
    if (i < N_NODES) rowptr[i] += tops[i >> 10];
    if (i == 0) rowptr[N_NODES] = N_EDGES;
}

// ---- fill CSR: entry = {src, dinv[src]} grouped by dst ----
__global__ void k_fill(const int* __restrict__ src, const int* __restrict__ dst,
                       const float* __restrict__ dinv, const int* __restrict__ rowptr,
                       int* __restrict__ cursor, uint2* __restrict__ csr) {
    int e = blockIdx.x * 256 + threadIdx.x;
    if (e < N_EDGES) {
        int s = src[e], d = dst[e];
        int p = rowptr[d] + atomicAdd(&cursor[d], 1);
        csr[p] = make_uint2((unsigned)s, __float_as_uint(dinv[s]));
    }
}

// ---- MFMA GEMM1: h1 = bf16(x@w1), identity = x@wd + bd ----
__global__ __launch_bounds__(256) void k_gemm1(const float* __restrict__ x,
                                               const unsigned short* __restrict__ wT,
                                               const float* __restrict__ bd,
                                               unsigned short* __restrict__ h1,
                                               float* __restrict__ identity) {
    __shared__ unsigned short As[128][LDA];
    const int t = threadIdx.x;
    const int rb = blockIdx.x * 128;
    {
        int row = t >> 1, half = t & 1;
        int grow = rb + row;
        if (grow < N_NODES) {
            const float* srcp = &x[(size_t)grow * 128 + half * 64];
#pragma unroll
            for (int i = 0; i < 8; i++) {
                float4 va = *(const float4*)&srcp[i * 8];
                float4 vb = *(const float4*)&srcp[i * 8 + 4];
                unsigned short u[8];
                u[0] = f2b(va.x); u[1] = f2b(va.y); u[2] = f2b(va.z); u[3] = f2b(va.w);
                u[4] = f2b(vb.x); u[5] = f2b(vb.y); u[6] = f2b(vb.z); u[7] = f2b(vb.w);
                *(bf16x8*)&As[row][half * 64 + i * 8] = *(bf16x8*)u;
            }
        } else {
            bf16x8 z = (bf16x8){0, 0, 0, 0, 0, 0, 0, 0};
#pragma unroll
            for (int i = 0; i < 8; i++) *(bf16x8*)&As[row][half * 64 + i * 8] = z;
        }
    }
    __syncthreads();
    const int wid = t >> 6, lane = t & 63;
    const int wr = wid >> 1, wc = wid & 1;
    const int mr = wr * 64, nc = wc * 96;
    const int lrow = lane & 15, lk = (lane >> 4) * 8;
    f32x4 acc[4][6];
#pragma unroll
    for (int m = 0; m < 4; m++)
#pragma unroll
        for (int n = 0; n < 6; n++) acc[m][n] = (f32x4){0.f, 0.f, 0.f, 0.f};

#pragma unroll
    for (int ki = 0; ki < 4; ki++) {
        const int k0 = ki * 32;
        bf16x8 a[4];
#pragma unroll
        for (int m = 0; m < 4; m++)
            a[m] = *(const bf16x8*)&As[mr + m * 16 + lrow][k0 + lk];
#pragma unroll
        for (int n = 0; n < 6; n++) {
            bf16x8 b = *(const bf16x8*)&wT[(size_t)(nc + n * 16 + lrow) * 128 + k0 + lk];
#pragma unroll
            for (int m = 0; m < 4; m++)
                acc[m][n] = __builtin_amdgcn_mfma_f32_16x16x32_bf16(a[m], b, acc[m][n], 0, 0, 0);
        }
    }
    const int crow0 = (lane >> 4) * 4;
#pragma unroll
    for (int m = 0; m < 4; m++) {
#pragma unroll
        for (int j = 0; j < 4; j++) {
            int grow = rb + mr + m * 16 + crow0 + j;
            if (grow >= N_NODES) continue;
#pragma unroll
            for (int n = 0; n < 6; n++) {
                int col = nc + n * 16 + lrow;
                float v = acc[m][n][j];
                if (col < 128) h1[(size_t)grow * 128 + col] = f2b(v);
                else           identity[(size_t)grow * 64 + (col - 128)] = v + bd[col - 128];
            }
        }
    }
}

// ---- MFMA GEMM2: h2 = bf16(out1 @ w2), tile 128 x 64 ----
__global__ __launch_bounds__(256) void k_gemm2(const unsigned short* __restrict__ a_in,
                                               const unsigned short* __restrict__ w2T,
                                               unsigned short* __restrict__ h2) {
    __shared__ unsigned short As[128][LDA];
    const int t = threadIdx.x;
    const int rb = blockIdx.x * 128;
    {
        int row = t >> 1, half = t & 1;
        int grow = rb + row;
        if (grow < N_NODES) {
#pragma unroll
            for (int i = 0; i < 8; i++)
                *(bf16x8*)&As[row][half * 64 + i * 8] =
                    *(const bf16x8*)&a_in[(size_t)grow * 128 + half * 64 + i * 8];
        } else {
            bf16x8 z = (bf16x8){0, 0, 0, 0, 0, 0, 0, 0};
#pragma unroll
            for (int i = 0; i < 8; i++) *(bf16x8*)&As[row][half * 64 + i * 8] = z;
        }
    }
    __syncthreads();
    const int wid = t >> 6, lane = t & 63;
    const int wr = wid >> 1, wc = wid & 1;
    const int mr = wr * 64, nc = wc * 32;
    const int lrow = lane & 15, lk = (lane >> 4) * 8;
    f32x4 acc[4][2];
#pragma unroll
    for (int m = 0; m < 4; m++)
#pragma unroll
        for (int n = 0; n < 2; n++) acc[m][n] = (f32x4){0.f, 0.f, 0.f, 0.f};

#pragma unroll
    for (int ki = 0; ki < 4; ki++) {
        const int k0 = ki * 32;
        bf16x8 a[4];
#pragma unroll
        for (int m = 0; m < 4; m++)
            a[m] = *(const bf16x8*)&As[mr + m * 16 + lrow][k0 + lk];
#pragma unroll
        for (int n = 0; n < 2; n++) {
            bf16x8 b = *(const bf16x8*)&w2T[(size_t)(nc + n * 16 + lrow) * 128 + k0 + lk];
#pragma unroll
            for (int m = 0; m < 4; m++)
                acc[m][n] = __builtin_amdgcn_mfma_f32_16x16x32_bf16(a[m], b, acc[m][n], 0, 0, 0);
        }
    }
    const int crow0 = (lane >> 4) * 4;
#pragma unroll
    for (int m = 0; m < 4; m++) {
#pragma unroll
        for (int j = 0; j < 4; j++) {
            int grow = rb + mr + m * 16 + crow0 + j;
            if (grow >= N_NODES) continue;
#pragma unroll
            for (int n = 0; n < 2; n++) {
                int col = nc + n * 16 + lrow;
                h2[(size_t)grow * 64 + col] = f2b(acc[m][n][j]);
            }
        }
    }
}

// ---- aggregate 1: out1 = leaky(sum_e norm*h1[src] + dinv^2*h1[i] + b1), 128 feats ----
// wave = 1 node; 4 groups x 16 lanes; group g handles edge e0+g, lane covers 8 feats (16B)
__global__ __launch_bounds__(256) void k_agg1(const unsigned short* __restrict__ h1,
                                              const uint2* __restrict__ csr,
                                              const int* __restrict__ rowptr,
                                              const float* __restrict__ dinv,
                                              const float* __restrict__ b1,
                                              unsigned short* __restrict__ out1) {
    int node = blockIdx.x * 4 + (threadIdx.x >> 6);
    if (node >= N_NODES) return;
    const int lane = threadIdx.x & 63;
    const int g = lane >> 4;   // edge slot 0..3
    const int l = lane & 15;   // feature chunk: [l*8, l*8+8)
    const float di = dinv[node];
    float a[8];
#pragma unroll
    for (int i = 0; i < 8; i++) a[i] = 0.f;
    const int beg = rowptr[node], end = rowptr[node + 1];
    for (int e0 = beg; e0 < end; e0 += 4) {
        int e = e0 + g;
        uint2 ce = csr[e];  // csr padded with 8 zeroed entries; mask weight only
        float w = (e < end) ? __uint_as_float(ce.y) * di : 0.f;
        uint4 h = *(const uint4*)&h1[(size_t)ce.x * 128 + l * 8];
        a[0] = fmaf(w, blo(h.x), a[0]);
        a[1] = fmaf(w, bhi(h.x), a[1]);
        a[2] = fmaf(w, blo(h.y), a[2]);
        a[3] = fmaf(w, bhi(h.y), a[3]);
        a[4] = fmaf(w, blo(h.z), a[4]);
        a[5] = fmaf(w, bhi(h.z), a[5]);
        a[6] = fmaf(w, blo(h.w), a[6]);
        a[7] = fmaf(w, bhi(h.w), a[7]);
    }
    // reduce across the 4 groups
#pragma unroll
    for (int i = 0; i < 8; i++) {
        a[i] += __shfl_xor(a[i], 16);
        a[i] += __shfl_xor(a[i], 32);
    }
    if (g == 0) {
        float di2 = di * di;
        uint4 hs = *(const uint4*)&h1[(size_t)node * 128 + l * 8];
        a[0] = fmaf(di2, blo(hs.x), a[0]);
        a[1] = fmaf(di2, bhi(hs.x), a[1]);
        a[2] = fmaf(di2, blo(hs.y), a[2]);
        a[3] = fmaf(di2, bhi(hs.y), a[3]);
        a[4] = fmaf(di2, blo(hs.z), a[4]);
        a[5] = fmaf(di2, bhi(hs.z), a[5]);
        a[6] = fmaf(di2, blo(hs.w), a[6]);
        a[7] = fmaf(di2, bhi(hs.w), a[7]);
        float4 b0 = *(const float4*)&b1[l * 8];
        float4 b4 = *(const float4*)&b1[l * 8 + 4];
        float v0 = lrelu(a[0] + b0.x), v1 = lrelu(a[1] + b0.y);
        float v2 = lrelu(a[2] + b0.z), v3 = lrelu(a[3] + b0.w);
        float v4 = lrelu(a[4] + b4.x), v5 = lrelu(a[5] + b4.y);
        float v6 = lrelu(a[6] + b4.z), v7 = lrelu(a[7] + b4.w);
        uint4 ov;
        ov.x = (unsigned)f2b(v0) | ((unsigned)f2b(v1) << 16);
        ov.y = (unsigned)f2b(v2) | ((unsigned)f2b(v3) << 16);
        ov.z = (unsigned)f2b(v4) | ((unsigned)f2b(v5) << 16);
        ov.w = (unsigned)f2b(v6) | ((unsigned)f2b(v7) << 16);
        *(uint4*)&out1[(size_t)node * 128 + l * 8] = ov;
    }
}

// ---- aggregate 2 + epilogue: out = leaky(agg(h2) + b2) + identity, 64 feats ----
// wave = 1 node; 4 groups x 16 lanes; lane covers 4 feats (8B)
__global__ __launch_bounds__(256) void k_agg2(const unsigned short* __restrict__ h2,
                                              const uint2* __restrict__ csr,
                                              const int* __restrict__ rowptr,
                                              const float* __restrict__ dinv,
                                              const float* __restrict__ b2,
                                              const float* __restrict__ identity,
                                              float* __restrict__ out) {
    int node = blockIdx.x * 4 + (threadIdx.x >> 6);
    if (node >= N_NODES) return;
    const int lane = threadIdx.x & 63;
    const int g = lane >> 4;
    const int l = lane & 15;   // feature chunk: [l*4, l*4+4)
    const float di = dinv[node];
    float a[4];
#pragma unroll
    for (int i = 0; i < 4; i++) a[i] = 0.f;
    const int beg = rowptr[node], end = rowptr[node + 1];
    for (int e0 = beg; e0 < end; e0 += 4) {
        int e = e0 + g;
        uint2 ce = csr[e];
        float w = (e < end) ? __uint_as_float(ce.y) * di : 0.f;
        uint2 h = *(const uint2*)&h2[(size_t)ce.x * 64 + l * 4];
        a[0] = fmaf(w, blo(h.x), a[0]);
        a[1] = fmaf(w, bhi(h.x), a[1]);
        a[2] = fmaf(w, blo(h.y), a[2]);
        a[3] = fmaf(w, bhi(h.y), a[3]);
    }
#pragma unroll
    for (int i = 0; i < 4; i++) {
        a[i] += __shfl_xor(a[i], 16);
        a[i] += __shfl_xor(a[i], 32);
    }
    if (g == 0) {
        float di2 = di * di;
        uint2 hs = *(const uint2*)&h2[(size_t)node * 64 + l * 4];
        a[0] = fmaf(di2, blo(hs.x), a[0]);
        a[1] = fmaf(di2, bhi(hs.x), a[1]);
        a[2] = fmaf(di2, blo(hs.y), a[2]);
        a[3] = fmaf(di2, bhi(hs.y), a[3]);
        float4 bb = *(const float4*)&b2[l * 4];
        float4 idv = *(const float4*)&identity[(size_t)node * 64 + l * 4];
        float4 o;
        o.x = lrelu(a[0] + bb.x) + idv.x;
        o.y = lrelu(a[1] + bb.y) + idv.y;
        o.z = lrelu(a[2] + bb.z) + idv.z;
        o.w = lrelu(a[3] + bb.w) + idv.w;
        *(float4*)&out[(size_t)node * 64 + l * 4] = o;
    }
}

extern "C" void kernel_launch(void* const* d_in, const int* in_sizes, int n_in,
                              void* d_out, int out_size, void* d_ws, size_t ws_size,
                              hipStream_t stream) {
    const float* x  = (const float*)d_in[0];
    const int* eidx = (const int*)d_in[1];
    const float* w1 = (const float*)d_in[2];
    const float* b1 = (const float*)d_in[3];
    const float* w2 = (const float*)d_in[4];
    const float* b2 = (const float*)d_in[5];
    const float* wd = (const float*)d_in[6];
    const float* bd = (const float*)d_in[7];
    const int* src = eidx;
    const int* dst = eidx + N_EDGES;
    float* out = (float*)d_out;

    char* ws = (char*)d_ws;
    size_t off = 0;
    auto take = [&](size_t bytes) -> char* {
        char* p = ws + off;
        off = (off + bytes + 255) & ~(size_t)255;
        return p;
    };
    int* cnt        = (int*)take((size_t)N_NODES * 4);
    int* rowptr     = (int*)take((size_t)(N_NODES + 1) * 4);
    int* cursor     = (int*)take((size_t)N_NODES * 4);
    float* dinv     = (float*)take((size_t)N_NODES * 4);
    int* bsum       = (int*)take(256 * 4);
    int* tops       = (int*)take(256 * 4);
    uint2* csr      = (uint2*)take((size_t)(N_EDGES + 8) * 8);  // +8 zeroed pad entries
    unsigned short* h1   = (unsigned short*)take((size_t)N_NODES * 128 * 2);
    unsigned short* out1 = (unsigned short*)take((size_t)N_NODES * 128 * 2);
    unsigned short* h2   = (unsigned short*)take((size_t)N_NODES * 64 * 2);
    float* identity = (float*)take((size_t)N_NODES * 64 * 4);
    unsigned short* wT   = (unsigned short*)take((size_t)192 * 128 * 2);
    unsigned short* w2T  = (unsigned short*)take((size_t)64 * 128 * 2);

    hipMemsetAsync(cnt, 0, (size_t)N_NODES * 4, stream);
    hipMemsetAsync(cursor, 0, (size_t)N_NODES * 4, stream);
    hipMemsetAsync(csr + N_EDGES, 0, 8 * sizeof(uint2), stream);

    k_hist<<<(N_EDGES + 255) / 256, 256, 0, stream>>>(dst, cnt);
    k_prep<<<(192 * 128 + 255) / 256, 256, 0, stream>>>(w1, wd, w2, wT, w2T);
    k_dinv<<<(N_NODES + 255) / 256, 256, 0, stream>>>(cnt, dinv);
    k_scan1<<<NB1, 256, 0, stream>>>(cnt, rowptr, bsum);
    k_scan2<<<1, 256, 0, stream>>>(bsum, tops);
    k_scan3<<<(N_NODES + 255) / 256, 256, 0, stream>>>(rowptr, tops);
    k_fill<<<(N_EDGES + 255) / 256, 256, 0, stream>>>(src, dst, dinv, rowptr, cursor, csr);
    k_gemm1<<<(N_NODES + 127) / 128, 256, 0, stream>>>(x, wT, bd, h1, identity);
    k_agg1<<<(N_NODES + 3) / 4, 256, 0, stream>>>(h1, csr, rowptr, dinv, b1, out1);
    k_gemm2<<<(N_NODES + 127) / 128, 256, 0, stream>>>(out1, w2T, h2);
    k_agg2<<<(N_NODES + 3) / 4, 256, 0, stream>>>(h2, csr, rowptr, dinv, b2, identity, out);
}

// Round 6
// 323.369 us; speedup vs baseline: 1.5463x; 1.1574x over previous
//
#include <hip/hip_runtime.h>
#include <hip/hip_bf16.h>

#define N_NODES 100000
#define N_EDGES 1600000
#define NFEAT 128
#define NHID 128
#define NOUT 64
#define NEG_SLOPE 0.01f
#define NB1 98   // ceil(100000/1024)
#define LDA 136  // 128 + 8 pad (bf16) — row stride 272B, keeps 16B alignment for b128 LDS ops
#define BKT_SHIFT 8
#define NBKT 391          // ceil(100000/256) buckets of 256 nodes
#define EPB_A 4096        // edges per block in fillA
#define NBA 391           // ceil(1600000/4096)
#define MAXB 6144         // LDS entry cap per bucket (mean 4096, sigma 64 — 32 sigma headroom)

typedef short bf16x8 __attribute__((ext_vector_type(8)));
typedef float f32x4 __attribute__((ext_vector_type(4)));

__device__ __forceinline__ unsigned short f2b(float f) {
    unsigned u = __float_as_uint(f);
    unsigned r = u + 0x7FFFu + ((u >> 16) & 1u);
    return (unsigned short)(r >> 16);
}
__device__ __forceinline__ float b2f(unsigned short h) {
    return __uint_as_float(((unsigned)h) << 16);
}
__device__ __forceinline__ float blo(unsigned d) { return __uint_as_float(d << 16); }
__device__ __forceinline__ float bhi(unsigned d) { return __uint_as_float(d & 0xFFFF0000u); }
__device__ __forceinline__ float lrelu(float v) {
    return v > 0.f ? v : v * NEG_SLOPE;
}

// ---- degree histogram over dst ----
__global__ void k_hist(const int* __restrict__ dst, int* __restrict__ cnt) {
    int e = blockIdx.x * 256 + threadIdx.x;
    if (e < N_EDGES) atomicAdd(&cnt[dst[e]], 1);
}

// ---- dinv = rsqrt(deg), deg = cnt + 1 (self loop) ----
__global__ void k_dinv(const int* __restrict__ cnt, float* __restrict__ dinv) {
    int i = blockIdx.x * 256 + threadIdx.x;
    if (i < N_NODES) dinv[i] = rsqrtf((float)(cnt[i] + 1));
}

// ---- transposed bf16 weights: wT[192][128] = [w1 | wd]^T, w2T[64][128] ----
__global__ void k_prep(const float* __restrict__ w1, const float* __restrict__ wd,
                       const float* __restrict__ w2,
                       unsigned short* __restrict__ wT, unsigned short* __restrict__ w2T) {
    int i = blockIdx.x * 256 + threadIdx.x;
    if (i < 192 * 128) {
        int n = i >> 7, k = i & 127;
        float v = (n < 128) ? w1[k * 128 + n] : wd[k * 64 + (n - 128)];
        wT[i] = f2b(v);
    }
    if (i < 64 * 128) {
        int n = i >> 7, k = i & 127;
        w2T[i] = f2b(w2[k * 64 + n]);
    }
}

// ---- scan stage 1 ----
__global__ __launch_bounds__(256) void k_scan1(const int* __restrict__ cnt,
                                               int* __restrict__ rowptr,
                                               int* __restrict__ bsum) {
    __shared__ int sc[256];
    int t = threadIdx.x;
    int base = blockIdx.x * 1024 + t * 4;
    int v0 = (base + 0 < N_NODES) ? cnt[base + 0] : 0;
    int v1 = (base + 1 < N_NODES) ? cnt[base + 1] : 0;
    int v2 = (base + 2 < N_NODES) ? cnt[base + 2] : 0;
    int v3 = (base + 3 < N_NODES) ? cnt[base + 3] : 0;
    int s = v0 + v1 + v2 + v3;
    sc[t] = s;
    __syncthreads();
    for (int off = 1; off < 256; off <<= 1) {
        int xv = (t >= off) ? sc[t - off] : 0;
        __syncthreads();
        sc[t] += xv;
        __syncthreads();
    }
    int run = sc[t] - s;
    if (base + 0 < N_NODES) { rowptr[base + 0] = run; run += v0; }
    if (base + 1 < N_NODES) { rowptr[base + 1] = run; run += v1; }
    if (base + 2 < N_NODES) { rowptr[base + 2] = run; run += v2; }
    if (base + 3 < N_NODES) { rowptr[base + 3] = run; run += v3; }
    if (t == 0) bsum[blockIdx.x] = sc[255];
}

// ---- scan stage 2 ----
__global__ __launch_bounds__(256) void k_scan2(const int* __restrict__ bsum,
                                               int* __restrict__ tops) {
    __shared__ int sc[256];
    int t = threadIdx.x;
    int s = (t < NB1) ? bsum[t] : 0;
    sc[t] = s;
    __syncthreads();
    for (int off = 1; off < 256; off <<= 1) {
        int xv = (t >= off) ? sc[t - off] : 0;
        __syncthreads();
        sc[t] += xv;
        __syncthreads();
    }
    tops[t] = sc[t] - s;
}

// ---- scan stage 3 ----
__global__ void k_scan3(int* __restrict__ rowptr, const int* __restrict__ tops) {
    int i = blockIdx.x * 256 + threadIdx.x;
    if (i < N_NODES) rowptr[i] += tops[i >> 10];
    if (i == 0) rowptr[N_NODES] = N_EDGES;
}

// ---- bucket cursor init: bcur[b] = rowptr[b*256] ----
__global__ void k_binit(const int* __restrict__ rowptr, int* __restrict__ bcur) {
    int i = blockIdx.x * 256 + threadIdx.x;
    if (i < NBKT) bcur[i] = rowptr[i << BKT_SHIFT];
}

// ---- fillA: coarse bucket scatter, per-block LDS binning -> {src, dst} into bucket regions ----
__global__ __launch_bounds__(256) void k_fillA(const int* __restrict__ src,
                                               const int* __restrict__ dst,
                                               int* __restrict__ bcur,
                                               uint2* __restrict__ csr) {
    __shared__ int lcnt[NBKT];
    __shared__ int lbase[NBKT];
    const int t = threadIdx.x;
    const int e0 = blockIdx.x * EPB_A;
    const int nd = min(EPB_A, N_EDGES - e0);
    for (int i = t; i < NBKT; i += 256) lcnt[i] = 0;
    __syncthreads();
    for (int i = t; i < nd; i += 256) {
        int d = dst[e0 + i];
        atomicAdd(&lcnt[d >> BKT_SHIFT], 1);
    }
    __syncthreads();
    for (int i = t; i < NBKT; i += 256)
        lbase[i] = lcnt[i] ? atomicAdd(&bcur[i], lcnt[i]) : 0;
    __syncthreads();
    for (int i = t; i < NBKT; i += 256) lcnt[i] = 0;  // reuse as run offsets
    __syncthreads();
    for (int i = t; i < nd; i += 256) {
        int s = src[e0 + i];
        int d = dst[e0 + i];
        int b = d >> BKT_SHIFT;
        int off = atomicAdd(&lcnt[b], 1);
        csr[lbase[b] + off] = make_uint2((unsigned)s, (unsigned)d);
    }
}

// ---- fillB: in-place fine permutation within each bucket; entry -> {src, dinv[src]} ----
__global__ __launch_bounds__(256) void k_fillB(const float* __restrict__ dinv,
                                               const int* __restrict__ rowptr,
                                               uint2* __restrict__ csr) {
    __shared__ uint2 lbuf[MAXB];
    __shared__ int lcur[256];
    __shared__ int lrp[256];
    const int t = threadIdx.x;
    const int b = blockIdx.x;
    const int n0 = b << BKT_SHIFT;
    const int n1 = min(n0 + 256, N_NODES);
    const int R0 = rowptr[n0], R1 = rowptr[n1];
    const int cnt = R1 - R0;
    for (int i = t; i < cnt; i += 256) lbuf[i] = csr[R0 + i];
    if (n0 + t < n1) lrp[t] = rowptr[n0 + t];
    lcur[t] = 0;
    __syncthreads();  // all region reads complete before any region write
    for (int i = t; i < cnt; i += 256) {
        uint2 e = lbuf[i];
        int li = (int)e.y & 255;  // d - n0 (n0 is 256-aligned)
        int r = atomicAdd(&lcur[li], 1);
        int p = lrp[li] + r;
        csr[p] = make_uint2(e.x, __float_as_uint(dinv[e.x]));
    }
}

// ---- MFMA GEMM1: h1 = bf16(x@w1), identity = x@wd + bd ----
__global__ __launch_bounds__(256) void k_gemm1(const float* __restrict__ x,
                                               const unsigned short* __restrict__ wT,
                                               const float* __restrict__ bd,
                                               unsigned short* __restrict__ h1,
                                               float* __restrict__ identity) {
    __shared__ unsigned short As[128][LDA];
    const int t = threadIdx.x;
    const int rb = blockIdx.x * 128;
    {
        int row = t >> 1, half = t & 1;
        int grow = rb + row;
        if (grow < N_NODES) {
            const float* srcp = &x[(size_t)grow * 128 + half * 64];
#pragma unroll
            for (int i = 0; i < 8; i++) {
                float4 va = *(const float4*)&srcp[i * 8];
                float4 vb = *(const float4*)&srcp[i * 8 + 4];
                unsigned short u[8];
                u[0] = f2b(va.x); u[1] = f2b(va.y); u[2] = f2b(va.z); u[3] = f2b(va.w);
                u[4] = f2b(vb.x); u[5] = f2b(vb.y); u[6] = f2b(vb.z); u[7] = f2b(vb.w);
                *(bf16x8*)&As[row][half * 64 + i * 8] = *(bf16x8*)u;
            }
        } else {
            bf16x8 z = (bf16x8){0, 0, 0, 0, 0, 0, 0, 0};
#pragma unroll
            for (int i = 0; i < 8; i++) *(bf16x8*)&As[row][half * 64 + i * 8] = z;
        }
    }
    __syncthreads();
    const int wid = t >> 6, lane = t & 63;
    const int wr = wid >> 1, wc = wid & 1;
    const int mr = wr * 64, nc = wc * 96;
    const int lrow = lane & 15, lk = (lane >> 4) * 8;
    f32x4 acc[4][6];
#pragma unroll
    for (int m = 0; m < 4; m++)
#pragma unroll
        for (int n = 0; n < 6; n++) acc[m][n] = (f32x4){0.f, 0.f, 0.f, 0.f};

#pragma unroll
    for (int ki = 0; ki < 4; ki++) {
        const int k0 = ki * 32;
        bf16x8 a[4];
#pragma unroll
        for (int m = 0; m < 4; m++)
            a[m] = *(const bf16x8*)&As[mr + m * 16 + lrow][k0 + lk];
#pragma unroll
        for (int n = 0; n < 6; n++) {
            bf16x8 b = *(const bf16x8*)&wT[(size_t)(nc + n * 16 + lrow) * 128 + k0 + lk];
#pragma unroll
            for (int m = 0; m < 4; m++)
                acc[m][n] = __builtin_amdgcn_mfma_f32_16x16x32_bf16(a[m], b, acc[m][n], 0, 0, 0);
        }
    }
    const int crow0 = (lane >> 4) * 4;
#pragma unroll
    for (int m = 0; m < 4; m++) {
#pragma unroll
        for (int j = 0; j < 4; j++) {
            int grow = rb + mr + m * 16 + crow0 + j;
            if (grow >= N_NODES) continue;
#pragma unroll
            for (int n = 0; n < 6; n++) {
                int col = nc + n * 16 + lrow;
                float v = acc[m][n][j];
                if (col < 128) h1[(size_t)grow * 128 + col] = f2b(v);
                else           identity[(size_t)grow * 64 + (col - 128)] = v + bd[col - 128];
            }
        }
    }
}

// ---- MFMA GEMM2: h2 = bf16(out1 @ w2), tile 128 x 64 ----
__global__ __launch_bounds__(256) void k_gemm2(const unsigned short* __restrict__ a_in,
                                               const unsigned short* __restrict__ w2T,
                                               unsigned short* __restrict__ h2) {
    __shared__ unsigned short As[128][LDA];
    const int t = threadIdx.x;
    const int rb = blockIdx.x * 128;
    {
        int row = t >> 1, half = t & 1;
        int grow = rb + row;
        if (grow < N_NODES) {
#pragma unroll
            for (int i = 0; i < 8; i++)
                *(bf16x8*)&As[row][half * 64 + i * 8] =
                    *(const bf16x8*)&a_in[(size_t)grow * 128 + half * 64 + i * 8];
        } else {
            bf16x8 z = (bf16x8){0, 0, 0, 0, 0, 0, 0, 0};
#pragma unroll
            for (int i = 0; i < 8; i++) *(bf16x8*)&As[row][half * 64 + i * 8] = z;
        }
    }
    __syncthreads();
    const int wid = t >> 6, lane = t & 63;
    const int wr = wid >> 1, wc = wid & 1;
    const int mr = wr * 64, nc = wc * 32;
    const int lrow = lane & 15, lk = (lane >> 4) * 8;
    f32x4 acc[4][2];
#pragma unroll
    for (int m = 0; m < 4; m++)
#pragma unroll
        for (int n = 0; n < 2; n++) acc[m][n] = (f32x4){0.f, 0.f, 0.f, 0.f};

#pragma unroll
    for (int ki = 0; ki < 4; ki++) {
        const int k0 = ki * 32;
        bf16x8 a[4];
#pragma unroll
        for (int m = 0; m < 4; m++)
            a[m] = *(const bf16x8*)&As[mr + m * 16 + lrow][k0 + lk];
#pragma unroll
        for (int n = 0; n < 2; n++) {
            bf16x8 b = *(const bf16x8*)&w2T[(size_t)(nc + n * 16 + lrow) * 128 + k0 + lk];
#pragma unroll
            for (int m = 0; m < 4; m++)
                acc[m][n] = __builtin_amdgcn_mfma_f32_16x16x32_bf16(a[m], b, acc[m][n], 0, 0, 0);
        }
    }
    const int crow0 = (lane >> 4) * 4;
#pragma unroll
    for (int m = 0; m < 4; m++) {
#pragma unroll
        for (int j = 0; j < 4; j++) {
            int grow = rb + mr + m * 16 + crow0 + j;
            if (grow >= N_NODES) continue;
#pragma unroll
            for (int n = 0; n < 2; n++) {
                int col = nc + n * 16 + lrow;
                h2[(size_t)grow * 64 + col] = f2b(acc[m][n][j]);
            }
        }
    }
}

// ---- aggregate 1: out1 = leaky(sum_e norm*h1[src] + dinv^2*h1[i] + b1), 128 feats ----
// wave = 1 node; 4 groups x 16 lanes; group g handles edge e0+g, lane covers 8 feats (16B)
__global__ __launch_bounds__(256) void k_agg1(const unsigned short* __restrict__ h1,
                                              const uint2* __restrict__ csr,
                                              const int* __restrict__ rowptr,
                                              const float* __restrict__ dinv,
                                              const float* __restrict__ b1,
                                              unsigned short* __restrict__ out1) {
    int node = blockIdx.x * 4 + (threadIdx.x >> 6);
    if (node >= N_NODES) return;
    const int lane = threadIdx.x & 63;
    const int g = lane >> 4;   // edge slot 0..3
    const int l = lane & 15;   // feature chunk: [l*8, l*8+8)
    const float di = dinv[node];
    float a[8];
#pragma unroll
    for (int i = 0; i < 8; i++) a[i] = 0.f;
    const int beg = rowptr[node], end = rowptr[node + 1];
    for (int e0 = beg; e0 < end; e0 += 4) {
        int e = e0 + g;
        uint2 ce = csr[e];  // csr padded with 8 zeroed entries; mask weight only
        float w = (e < end) ? __uint_as_float(ce.y) * di : 0.f;
        uint4 h = *(const uint4*)&h1[(size_t)ce.x * 128 + l * 8];
        a[0] = fmaf(w, blo(h.x), a[0]);
        a[1] = fmaf(w, bhi(h.x), a[1]);
        a[2] = fmaf(w, blo(h.y), a[2]);
        a[3] = fmaf(w, bhi(h.y), a[3]);
        a[4] = fmaf(w, blo(h.z), a[4]);
        a[5] = fmaf(w, bhi(h.z), a[5]);
        a[6] = fmaf(w, blo(h.w), a[6]);
        a[7] = fmaf(w, bhi(h.w), a[7]);
    }
#pragma unroll
    for (int i = 0; i < 8; i++) {
        a[i] += __shfl_xor(a[i], 16);
        a[i] += __shfl_xor(a[i], 32);
    }
    if (g == 0) {
        float di2 = di * di;
        uint4 hs = *(const uint4*)&h1[(size_t)node * 128 + l * 8];
        a[0] = fmaf(di2, blo(hs.x), a[0]);
        a[1] = fmaf(di2, bhi(hs.x), a[1]);
        a[2] = fmaf(di2, blo(hs.y), a[2]);
        a[3] = fmaf(di2, bhi(hs.y), a[3]);
        a[4] = fmaf(di2, blo(hs.z), a[4]);
        a[5] = fmaf(di2, bhi(hs.z), a[5]);
        a[6] = fmaf(di2, blo(hs.w), a[6]);
        a[7] = fmaf(di2, bhi(hs.w), a[7]);
        float4 b0 = *(const float4*)&b1[l * 8];
        float4 b4 = *(const float4*)&b1[l * 8 + 4];
        float v0 = lrelu(a[0] + b0.x), v1 = lrelu(a[1] + b0.y);
        float v2 = lrelu(a[2] + b0.z), v3 = lrelu(a[3] + b0.w);
        float v4 = lrelu(a[4] + b4.x), v5 = lrelu(a[5] + b4.y);
        float v6 = lrelu(a[6] + b4.z), v7 = lrelu(a[7] + b4.w);
        uint4 ov;
        ov.x = (unsigned)f2b(v0) | ((unsigned)f2b(v1) << 16);
        ov.y = (unsigned)f2b(v2) | ((unsigned)f2b(v3) << 16);
        ov.z = (unsigned)f2b(v4) | ((unsigned)f2b(v5) << 16);
        ov.w = (unsigned)f2b(v6) | ((unsigned)f2b(v7) << 16);
        *(uint4*)&out1[(size_t)node * 128 + l * 8] = ov;
    }
}

// ---- aggregate 2 + epilogue: out = leaky(agg(h2) + b2) + identity, 64 feats ----
__global__ __launch_bounds__(256) void k_agg2(const unsigned short* __restrict__ h2,
                                              const uint2* __restrict__ csr,
                                              const int* __restrict__ rowptr,
                                              const float* __restrict__ dinv,
                                              const float* __restrict__ b2,
                                              const float* __restrict__ identity,
                                              float* __restrict__ out) {
    int node = blockIdx.x * 4 + (threadIdx.x >> 6);
    if (node >= N_NODES) return;
    const int lane = threadIdx.x & 63;
    const int g = lane >> 4;
    const int l = lane & 15;   // feature chunk: [l*4, l*4+4)
    const float di = dinv[node];
    float a[4];
#pragma unroll
    for (int i = 0; i < 4; i++) a[i] = 0.f;
    const int beg = rowptr[node], end = rowptr[node + 1];
    for (int e0 = beg; e0 < end; e0 += 4) {
        int e = e0 + g;
        uint2 ce = csr[e];
        float w = (e < end) ? __uint_as_float(ce.y) * di : 0.f;
        uint2 h = *(const uint2*)&h2[(size_t)ce.x * 64 + l * 4];
        a[0] = fmaf(w, blo(h.x), a[0]);
        a[1] = fmaf(w, bhi(h.x), a[1]);
        a[2] = fmaf(w, blo(h.y), a[2]);
        a[3] = fmaf(w, bhi(h.y), a[3]);
    }
#pragma unroll
    for (int i = 0; i < 4; i++) {
        a[i] += __shfl_xor(a[i], 16);
        a[i] += __shfl_xor(a[i], 32);
    }
    if (g == 0) {
        float di2 = di * di;
        uint2 hs = *(const uint2*)&h2[(size_t)node * 64 + l * 4];
        a[0] = fmaf(di2, blo(hs.x), a[0]);
        a[1] = fmaf(di2, bhi(hs.x), a[1]);
        a[2] = fmaf(di2, blo(hs.y), a[2]);
        a[3] = fmaf(di2, bhi(hs.y), a[3]);
        float4 bb = *(const float4*)&b2[l * 4];
        float4 idv = *(const float4*)&identity[(size_t)node * 64 + l * 4];
        float4 o;
        o.x = lrelu(a[0] + bb.x) + idv.x;
        o.y = lrelu(a[1] + bb.y) + idv.y;
        o.z = lrelu(a[2] + bb.z) + idv.z;
        o.w = lrelu(a[3] + bb.w) + idv.w;
        *(float4*)&out[(size_t)node * 64 + l * 4] = o;
    }
}

extern "C" void kernel_launch(void* const* d_in, const int* in_sizes, int n_in,
                              void* d_out, int out_size, void* d_ws, size_t ws_size,
                              hipStream_t stream) {
    const float* x  = (const float*)d_in[0];
    const int* eidx = (const int*)d_in[1];
    const float* w1 = (const float*)d_in[2];
    const float* b1 = (const float*)d_in[3];
    const float* w2 = (const float*)d_in[4];
    const float* b2 = (const float*)d_in[5];
    const float* wd = (const float*)d_in[6];
    const float* bd = (const float*)d_in[7];
    const int* src = eidx;
    const int* dst = eidx + N_EDGES;
    float* out = (float*)d_out;

    char* ws = (char*)d_ws;
    size_t off = 0;
    auto take = [&](size_t bytes) -> char* {
        char* p = ws + off;
        off = (off + bytes + 255) & ~(size_t)255;
        return p;
    };
    int* cnt        = (int*)take((size_t)N_NODES * 4);
    int* rowptr     = (int*)take((size_t)(N_NODES + 1) * 4);
    int* bcur       = (int*)take((size_t)NBKT * 4);
    float* dinv     = (float*)take((size_t)N_NODES * 4);
    int* bsum       = (int*)take(256 * 4);
    int* tops       = (int*)take(256 * 4);
    uint2* csr      = (uint2*)take((size_t)(N_EDGES + 8) * 8);  // +8 zeroed pad entries
    unsigned short* h1   = (unsigned short*)take((size_t)N_NODES * 128 * 2);
    unsigned short* out1 = (unsigned short*)take((size_t)N_NODES * 128 * 2);
    unsigned short* h2   = (unsigned short*)take((size_t)N_NODES * 64 * 2);
    float* identity = (float*)take((size_t)N_NODES * 64 * 4);
    unsigned short* wT   = (unsigned short*)take((size_t)192 * 128 * 2);
    unsigned short* w2T  = (unsigned short*)take((size_t)64 * 128 * 2);

    hipMemsetAsync(cnt, 0, (size_t)N_NODES * 4, stream);
    hipMemsetAsync(csr + N_EDGES, 0, 8 * sizeof(uint2), stream);

    k_hist<<<(N_EDGES + 255) / 256, 256, 0, stream>>>(dst, cnt);
    k_prep<<<(192 * 128 + 255) / 256, 256, 0, stream>>>(w1, wd, w2, wT, w2T);
    k_dinv<<<(N_NODES + 255) / 256, 256, 0, stream>>>(cnt, dinv);
    k_scan1<<<NB1, 256, 0, stream>>>(cnt, rowptr, bsum);
    k_scan2<<<1, 256, 0, stream>>>(bsum, tops);
    k_scan3<<<(N_NODES + 255) / 256, 256, 0, stream>>>(rowptr, tops);
    k_binit<<<(NBKT + 255) / 256, 256, 0, stream>>>(rowptr, bcur);
    k_fillA<<<NBA, 256, 0, stream>>>(src, dst, bcur, csr);
    k_fillB<<<NBKT, 256, 0, stream>>>(dinv, rowptr, csr);
    k_gemm1<<<(N_NODES + 127) / 128, 256, 0, stream>>>(x, wT, bd, h1, identity);
    k_agg1<<<(N_NODES + 3) / 4, 256, 0, stream>>>(h1, csr, rowptr, dinv, b1, out1);
    k_gemm2<<<(N_NODES + 127) / 128, 256, 0, stream>>>(out1, w2T, h2);
    k_agg2<<<(N_NODES + 3) / 4, 256, 0, stream>>>(h2, csr, rowptr, dinv, b2, identity, out);
}

// Round 7
// 315.274 us; speedup vs baseline: 1.5860x; 1.0257x over previous
//
#include <hip/hip_runtime.h>
#include <hip/hip_bf16.h>

#define N_NODES 100000
#define N_EDGES 1600000
#define NFEAT 128
#define NHID 128
#define NOUT 64
#define NEG_SLOPE 0.01f
#define NB1 98   // ceil(100000/1024)
#define LDA 136  // 128 + 8 pad (bf16) — row stride 272B, keeps 16B alignment for b128 LDS ops
#define BKT_SHIFT 8
#define NBKT 391          // ceil(100000/256) buckets of 256 nodes
#define EPB_A 4096        // edges per block in fillA
#define NBA 391           // ceil(1600000/4096)
#define MAXB 6144         // LDS entry cap per bucket

typedef short bf16x8 __attribute__((ext_vector_type(8)));
typedef float f32x4 __attribute__((ext_vector_type(4)));
typedef float f32x2 __attribute__((ext_vector_type(2)));

__device__ __forceinline__ unsigned short f2b(float f) {
    unsigned u = __float_as_uint(f);
    unsigned r = u + 0x7FFFu + ((u >> 16) & 1u);
    return (unsigned short)(r >> 16);
}
__device__ __forceinline__ float b2f(unsigned short h) {
    return __uint_as_float(((unsigned)h) << 16);
}
__device__ __forceinline__ float blo(unsigned d) { return __uint_as_float(d << 16); }
__device__ __forceinline__ float bhi(unsigned d) { return __uint_as_float(d & 0xFFFF0000u); }
__device__ __forceinline__ float lrelu(float v) {
    return v > 0.f ? v : v * NEG_SLOPE;
}
// OCP e4m3 via gfx950 HW converts
__device__ __forceinline__ unsigned char f2fp8(float f) {
    return (unsigned char)(__builtin_amdgcn_cvt_pk_fp8_f32(f, f, 0, false) & 0xFF);
}

// ---- degree histogram over dst ----
__global__ void k_hist(const int* __restrict__ dst, int* __restrict__ cnt) {
    int e = blockIdx.x * 256 + threadIdx.x;
    if (e < N_EDGES) atomicAdd(&cnt[dst[e]], 1);
}

// ---- dinv = rsqrt(deg), deg = cnt + 1 (self loop) ----
__global__ void k_dinv(const int* __restrict__ cnt, float* __restrict__ dinv) {
    int i = blockIdx.x * 256 + threadIdx.x;
    if (i < N_NODES) dinv[i] = rsqrtf((float)(cnt[i] + 1));
}

// ---- transposed bf16 weights: wT[192][128] = [w1 | wd]^T, w2T[64][128] ----
__global__ void k_prep(const float* __restrict__ w1, const float* __restrict__ wd,
                       const float* __restrict__ w2,
                       unsigned short* __restrict__ wT, unsigned short* __restrict__ w2T) {
    int i = blockIdx.x * 256 + threadIdx.x;
    if (i < 192 * 128) {
        int n = i >> 7, k = i & 127;
        float v = (n < 128) ? w1[k * 128 + n] : wd[k * 64 + (n - 128)];
        wT[i] = f2b(v);
    }
    if (i < 64 * 128) {
        int n = i >> 7, k = i & 127;
        w2T[i] = f2b(w2[k * 64 + n]);
    }
}

// ---- scan stage 1 ----
__global__ __launch_bounds__(256) void k_scan1(const int* __restrict__ cnt,
                                               int* __restrict__ rowptr,
                                               int* __restrict__ bsum) {
    __shared__ int sc[256];
    int t = threadIdx.x;
    int base = blockIdx.x * 1024 + t * 4;
    int v0 = (base + 0 < N_NODES) ? cnt[base + 0] : 0;
    int v1 = (base + 1 < N_NODES) ? cnt[base + 1] : 0;
    int v2 = (base + 2 < N_NODES) ? cnt[base + 2] : 0;
    int v3 = (base + 3 < N_NODES) ? cnt[base + 3] : 0;
    int s = v0 + v1 + v2 + v3;
    sc[t] = s;
    __syncthreads();
    for (int off = 1; off < 256; off <<= 1) {
        int xv = (t >= off) ? sc[t - off] : 0;
        __syncthreads();
        sc[t] += xv;
        __syncthreads();
    }
    int run = sc[t] - s;
    if (base + 0 < N_NODES) { rowptr[base + 0] = run; run += v0; }
    if (base + 1 < N_NODES) { rowptr[base + 1] = run; run += v1; }
    if (base + 2 < N_NODES) { rowptr[base + 2] = run; run += v2; }
    if (base + 3 < N_NODES) { rowptr[base + 3] = run; run += v3; }
    if (t == 0) bsum[blockIdx.x] = sc[255];
}

// ---- scan stage 2 ----
__global__ __launch_bounds__(256) void k_scan2(const int* __restrict__ bsum,
                                               int* __restrict__ tops) {
    __shared__ int sc[256];
    int t = threadIdx.x;
    int s = (t < NB1) ? bsum[t] : 0;
    sc[t] = s;
    __syncthreads();
    for (int off = 1; off < 256; off <<= 1) {
        int xv = (t >= off) ? sc[t - off] : 0;
        __syncthreads();
        sc[t] += xv;
        __syncthreads();
    }
    tops[t] = sc[t] - s;
}

// ---- scan stage 3 ----
__global__ void k_scan3(int* __restrict__ rowptr, const int* __restrict__ tops) {
    int i = blockIdx.x * 256 + threadIdx.x;
    if (i < N_NODES) rowptr[i] += tops[i >> 10];
    if (i == 0) rowptr[N_NODES] = N_EDGES;
}

// ---- bucket cursor init ----
__global__ void k_binit(const int* __restrict__ rowptr, int* __restrict__ bcur) {
    int i = blockIdx.x * 256 + threadIdx.x;
    if (i < NBKT) bcur[i] = rowptr[i << BKT_SHIFT];
}

// ---- fillA: coarse bucket scatter ----
__global__ __launch_bounds__(256) void k_fillA(const int* __restrict__ src,
                                               const int* __restrict__ dst,
                                               int* __restrict__ bcur,
                                               uint2* __restrict__ csr) {
    __shared__ int lcnt[NBKT];
    __shared__ int lbase[NBKT];
    const int t = threadIdx.x;
    const int e0 = blockIdx.x * EPB_A;
    const int nd = min(EPB_A, N_EDGES - e0);
    for (int i = t; i < NBKT; i += 256) lcnt[i] = 0;
    __syncthreads();
    for (int i = t; i < nd; i += 256) {
        int d = dst[e0 + i];
        atomicAdd(&lcnt[d >> BKT_SHIFT], 1);
    }
    __syncthreads();
    for (int i = t; i < NBKT; i += 256)
        lbase[i] = lcnt[i] ? atomicAdd(&bcur[i], lcnt[i]) : 0;
    __syncthreads();
    for (int i = t; i < NBKT; i += 256) lcnt[i] = 0;
    __syncthreads();
    for (int i = t; i < nd; i += 256) {
        int s = src[e0 + i];
        int d = dst[e0 + i];
        int b = d >> BKT_SHIFT;
        int off = atomicAdd(&lcnt[b], 1);
        csr[lbase[b] + off] = make_uint2((unsigned)s, (unsigned)d);
    }
}

// ---- fillB: in-place fine permutation within each bucket ----
__global__ __launch_bounds__(256) void k_fillB(const float* __restrict__ dinv,
                                               const int* __restrict__ rowptr,
                                               uint2* __restrict__ csr) {
    __shared__ uint2 lbuf[MAXB];
    __shared__ int lcur[256];
    __shared__ int lrp[256];
    const int t = threadIdx.x;
    const int b = blockIdx.x;
    const int n0 = b << BKT_SHIFT;
    const int n1 = min(n0 + 256, N_NODES);
    const int R0 = rowptr[n0], R1 = rowptr[n1];
    const int cnt = R1 - R0;
    for (int i = t; i < cnt; i += 256) lbuf[i] = csr[R0 + i];
    if (n0 + t < n1) lrp[t] = rowptr[n0 + t];
    lcur[t] = 0;
    __syncthreads();
    for (int i = t; i < cnt; i += 256) {
        uint2 e = lbuf[i];
        int li = (int)e.y & 255;
        int r = atomicAdd(&lcur[li], 1);
        int p = lrp[li] + r;
        csr[p] = make_uint2(e.x, __float_as_uint(dinv[e.x]));
    }
}

// ---- MFMA GEMM1: h1 = fp8(x@w1), identity = x@wd + bd ----
__global__ __launch_bounds__(256) void k_gemm1(const float* __restrict__ x,
                                               const unsigned short* __restrict__ wT,
                                               const float* __restrict__ bd,
                                               unsigned char* __restrict__ h1,
                                               float* __restrict__ identity) {
    __shared__ unsigned short As[128][LDA];
    const int t = threadIdx.x;
    const int rb = blockIdx.x * 128;
    {
        int row = t >> 1, half = t & 1;
        int grow = rb + row;
        if (grow < N_NODES) {
            const float* srcp = &x[(size_t)grow * 128 + half * 64];
#pragma unroll
            for (int i = 0; i < 8; i++) {
                float4 va = *(const float4*)&srcp[i * 8];
                float4 vb = *(const float4*)&srcp[i * 8 + 4];
                unsigned short u[8];
                u[0] = f2b(va.x); u[1] = f2b(va.y); u[2] = f2b(va.z); u[3] = f2b(va.w);
                u[4] = f2b(vb.x); u[5] = f2b(vb.y); u[6] = f2b(vb.z); u[7] = f2b(vb.w);
                *(bf16x8*)&As[row][half * 64 + i * 8] = *(bf16x8*)u;
            }
        } else {
            bf16x8 z = (bf16x8){0, 0, 0, 0, 0, 0, 0, 0};
#pragma unroll
            for (int i = 0; i < 8; i++) *(bf16x8*)&As[row][half * 64 + i * 8] = z;
        }
    }
    __syncthreads();
    const int wid = t >> 6, lane = t & 63;
    const int wr = wid >> 1, wc = wid & 1;
    const int mr = wr * 64, nc = wc * 96;
    const int lrow = lane & 15, lk = (lane >> 4) * 8;
    f32x4 acc[4][6];
#pragma unroll
    for (int m = 0; m < 4; m++)
#pragma unroll
        for (int n = 0; n < 6; n++) acc[m][n] = (f32x4){0.f, 0.f, 0.f, 0.f};

#pragma unroll
    for (int ki = 0; ki < 4; ki++) {
        const int k0 = ki * 32;
        bf16x8 a[4];
#pragma unroll
        for (int m = 0; m < 4; m++)
            a[m] = *(const bf16x8*)&As[mr + m * 16 + lrow][k0 + lk];
#pragma unroll
        for (int n = 0; n < 6; n++) {
            bf16x8 b = *(const bf16x8*)&wT[(size_t)(nc + n * 16 + lrow) * 128 + k0 + lk];
#pragma unroll
            for (int m = 0; m < 4; m++)
                acc[m][n] = __builtin_amdgcn_mfma_f32_16x16x32_bf16(a[m], b, acc[m][n], 0, 0, 0);
        }
    }
    const int crow0 = (lane >> 4) * 4;
#pragma unroll
    for (int m = 0; m < 4; m++) {
#pragma unroll
        for (int j = 0; j < 4; j++) {
            int grow = rb + mr + m * 16 + crow0 + j;
            if (grow >= N_NODES) continue;
#pragma unroll
            for (int n = 0; n < 6; n++) {
                int col = nc + n * 16 + lrow;
                float v = acc[m][n][j];
                if (col < 128) h1[(size_t)grow * 128 + col] = f2fp8(v);
                else           identity[(size_t)grow * 64 + (col - 128)] = v + bd[col - 128];
            }
        }
    }
}

// ---- MFMA GEMM2: h2 = fp8(out1 @ w2), tile 128 x 64 ----
__global__ __launch_bounds__(256) void k_gemm2(const unsigned short* __restrict__ a_in,
                                               const unsigned short* __restrict__ w2T,
                                               unsigned char* __restrict__ h2) {
    __shared__ unsigned short As[128][LDA];
    const int t = threadIdx.x;
    const int rb = blockIdx.x * 128;
    {
        int row = t >> 1, half = t & 1;
        int grow = rb + row;
        if (grow < N_NODES) {
#pragma unroll
            for (int i = 0; i < 8; i++)
                *(bf16x8*)&As[row][half * 64 + i * 8] =
                    *(const bf16x8*)&a_in[(size_t)grow * 128 + half * 64 + i * 8];
        } else {
            bf16x8 z = (bf16x8){0, 0, 0, 0, 0, 0, 0, 0};
#pragma unroll
            for (int i = 0; i < 8; i++) *(bf16x8*)&As[row][half * 64 + i * 8] = z;
        }
    }
    __syncthreads();
    const int wid = t >> 6, lane = t & 63;
    const int wr = wid >> 1, wc = wid & 1;
    const int mr = wr * 64, nc = wc * 32;
    const int lrow = lane & 15, lk = (lane >> 4) * 8;
    f32x4 acc[4][2];
#pragma unroll
    for (int m = 0; m < 4; m++)
#pragma unroll
        for (int n = 0; n < 2; n++) acc[m][n] = (f32x4){0.f, 0.f, 0.f, 0.f};

#pragma unroll
    for (int ki = 0; ki < 4; ki++) {
        const int k0 = ki * 32;
        bf16x8 a[4];
#pragma unroll
        for (int m = 0; m < 4; m++)
            a[m] = *(const bf16x8*)&As[mr + m * 16 + lrow][k0 + lk];
#pragma unroll
        for (int n = 0; n < 2; n++) {
            bf16x8 b = *(const bf16x8*)&w2T[(size_t)(nc + n * 16 + lrow) * 128 + k0 + lk];
#pragma unroll
            for (int m = 0; m < 4; m++)
                acc[m][n] = __builtin_amdgcn_mfma_f32_16x16x32_bf16(a[m], b, acc[m][n], 0, 0, 0);
        }
    }
    const int crow0 = (lane >> 4) * 4;
#pragma unroll
    for (int m = 0; m < 4; m++) {
#pragma unroll
        for (int j = 0; j < 4; j++) {
            int grow = rb + mr + m * 16 + crow0 + j;
            if (grow >= N_NODES) continue;
#pragma unroll
            for (int n = 0; n < 2; n++) {
                int col = nc + n * 16 + lrow;
                h2[(size_t)grow * 64 + col] = f2fp8(acc[m][n][j]);
            }
        }
    }
}

// ---- aggregate 1: out1 = leaky(sum_e norm*h1[src] + dinv^2*h1[i] + b1), 128 feats, fp8 h1 ----
// wave = 1 node; 4 groups x 16 lanes; group g handles edge e0+g, lane covers 8 feats (8B fp8)
__global__ __launch_bounds__(256) void k_agg1(const unsigned char* __restrict__ h1,
                                              const uint2* __restrict__ csr,
                                              const int* __restrict__ rowptr,
                                              const float* __restrict__ dinv,
                                              const float* __restrict__ b1,
                                              unsigned short* __restrict__ out1) {
    int node = blockIdx.x * 4 + (threadIdx.x >> 6);
    if (node >= N_NODES) return;
    const int lane = threadIdx.x & 63;
    const int g = lane >> 4;   // edge slot 0..3
    const int l = lane & 15;   // feature chunk: [l*8, l*8+8)
    const float di = dinv[node];
    float a[8];
#pragma unroll
    for (int i = 0; i < 8; i++) a[i] = 0.f;
    const int beg = rowptr[node], end = rowptr[node + 1];
    for (int e0 = beg; e0 < end; e0 += 4) {
        int e = e0 + g;
        uint2 ce = csr[e];  // csr padded; safe
        if (e < end) {
            float w = __uint_as_float(ce.y) * di;
            uint2 h = *(const uint2*)&h1[(size_t)ce.x * 128 + l * 8];
            f32x2 f0 = __builtin_amdgcn_cvt_pk_f32_fp8(h.x, false);
            f32x2 f1 = __builtin_amdgcn_cvt_pk_f32_fp8(h.x, true);
            f32x2 f2 = __builtin_amdgcn_cvt_pk_f32_fp8(h.y, false);
            f32x2 f3 = __builtin_amdgcn_cvt_pk_f32_fp8(h.y, true);
            a[0] = fmaf(w, f0.x, a[0]);
            a[1] = fmaf(w, f0.y, a[1]);
            a[2] = fmaf(w, f1.x, a[2]);
            a[3] = fmaf(w, f1.y, a[3]);
            a[4] = fmaf(w, f2.x, a[4]);
            a[5] = fmaf(w, f2.y, a[5]);
            a[6] = fmaf(w, f3.x, a[6]);
            a[7] = fmaf(w, f3.y, a[7]);
        }
    }
#pragma unroll
    for (int i = 0; i < 8; i++) {
        a[i] += __shfl_xor(a[i], 16);
        a[i] += __shfl_xor(a[i], 32);
    }
    if (g == 0) {
        float di2 = di * di;
        uint2 hs = *(const uint2*)&h1[(size_t)node * 128 + l * 8];
        f32x2 s0 = __builtin_amdgcn_cvt_pk_f32_fp8(hs.x, false);
        f32x2 s1 = __builtin_amdgcn_cvt_pk_f32_fp8(hs.x, true);
        f32x2 s2 = __builtin_amdgcn_cvt_pk_f32_fp8(hs.y, false);
        f32x2 s3 = __builtin_amdgcn_cvt_pk_f32_fp8(hs.y, true);
        a[0] = fmaf(di2, s0.x, a[0]);
        a[1] = fmaf(di2, s0.y, a[1]);
        a[2] = fmaf(di2, s1.x, a[2]);
        a[3] = fmaf(di2, s1.y, a[3]);
        a[4] = fmaf(di2, s2.x, a[4]);
        a[5] = fmaf(di2, s2.y, a[5]);
        a[6] = fmaf(di2, s3.x, a[6]);
        a[7] = fmaf(di2, s3.y, a[7]);
        float4 b0 = *(const float4*)&b1[l * 8];
        float4 b4 = *(const float4*)&b1[l * 8 + 4];
        float v0 = lrelu(a[0] + b0.x), v1 = lrelu(a[1] + b0.y);
        float v2 = lrelu(a[2] + b0.z), v3 = lrelu(a[3] + b0.w);
        float v4 = lrelu(a[4] + b4.x), v5 = lrelu(a[5] + b4.y);
        float v6 = lrelu(a[6] + b4.z), v7 = lrelu(a[7] + b4.w);
        uint4 ov;
        ov.x = (unsigned)f2b(v0) | ((unsigned)f2b(v1) << 16);
        ov.y = (unsigned)f2b(v2) | ((unsigned)f2b(v3) << 16);
        ov.z = (unsigned)f2b(v4) | ((unsigned)f2b(v5) << 16);
        ov.w = (unsigned)f2b(v6) | ((unsigned)f2b(v7) << 16);
        *(uint4*)&out1[(size_t)node * 128 + l * 8] = ov;
    }
}

// ---- aggregate 2 + epilogue: out = leaky(agg(h2) + b2) + identity, 64 feats, fp8 h2 ----
__global__ __launch_bounds__(256) void k_agg2(const unsigned char* __restrict__ h2,
                                              const uint2* __restrict__ csr,
                                              const int* __restrict__ rowptr,
                                              const float* __restrict__ dinv,
                                              const float* __restrict__ b2,
                                              const float* __restrict__ identity,
                                              float* __restrict__ out) {
    int node = blockIdx.x * 4 + (threadIdx.x >> 6);
    if (node >= N_NODES) return;
    const int lane = threadIdx.x & 63;
    const int g = lane >> 4;
    const int l = lane & 15;   // feature chunk: [l*4, l*4+4)
    const float di = dinv[node];
    float a[4];
#pragma unroll
    for (int i = 0; i < 4; i++) a[i] = 0.f;
    const int beg = rowptr[node], end = rowptr[node + 1];
    for (int e0 = beg; e0 < end; e0 += 4) {
        int e = e0 + g;
        uint2 ce = csr[e];
        if (e < end) {
            float w = __uint_as_float(ce.y) * di;
            unsigned h = *(const unsigned*)&h2[(size_t)ce.x * 64 + l * 4];
            f32x2 f0 = __builtin_amdgcn_cvt_pk_f32_fp8(h, false);
            f32x2 f1 = __builtin_amdgcn_cvt_pk_f32_fp8(h, true);
            a[0] = fmaf(w, f0.x, a[0]);
            a[1] = fmaf(w, f0.y, a[1]);
            a[2] = fmaf(w, f1.x, a[2]);
            a[3] = fmaf(w, f1.y, a[3]);
        }
    }
#pragma unroll
    for (int i = 0; i < 4; i++) {
        a[i] += __shfl_xor(a[i], 16);
        a[i] += __shfl_xor(a[i], 32);
    }
    if (g == 0) {
        float di2 = di * di;
        unsigned hs = *(const unsigned*)&h2[(size_t)node * 64 + l * 4];
        f32x2 s0 = __builtin_amdgcn_cvt_pk_f32_fp8(hs, false);
        f32x2 s1 = __builtin_amdgcn_cvt_pk_f32_fp8(hs, true);
        a[0] = fmaf(di2, s0.x, a[0]);
        a[1] = fmaf(di2, s0.y, a[1]);
        a[2] = fmaf(di2, s1.x, a[2]);
        a[3] = fmaf(di2, s1.y, a[3]);
        float4 bb = *(const float4*)&b2[l * 4];
        float4 idv = *(const float4*)&identity[(size_t)node * 64 + l * 4];
        float4 o;
        o.x = lrelu(a[0] + bb.x) + idv.x;
        o.y = lrelu(a[1] + bb.y) + idv.y;
        o.z = lrelu(a[2] + bb.z) + idv.z;
        o.w = lrelu(a[3] + bb.w) + idv.w;
        *(float4*)&out[(size_t)node * 64 + l * 4] = o;
    }
}

extern "C" void kernel_launch(void* const* d_in, const int* in_sizes, int n_in,
                              void* d_out, int out_size, void* d_ws, size_t ws_size,
                              hipStream_t stream) {
    const float* x  = (const float*)d_in[0];
    const int* eidx = (const int*)d_in[1];
    const float* w1 = (const float*)d_in[2];
    const float* b1 = (const float*)d_in[3];
    const float* w2 = (const float*)d_in[4];
    const float* b2 = (const float*)d_in[5];
    const float* wd = (const float*)d_in[6];
    const float* bd = (const float*)d_in[7];
    const int* src = eidx;
    const int* dst = eidx + N_EDGES;
    float* out = (float*)d_out;

    char* ws = (char*)d_ws;
    size_t off = 0;
    auto take = [&](size_t bytes) -> char* {
        char* p = ws + off;
        off = (off + bytes + 255) & ~(size_t)255;
        return p;
    };
    int* cnt        = (int*)take((size_t)N_NODES * 4);
    int* rowptr     = (int*)take((size_t)(N_NODES + 1) * 4);
    int* bcur       = (int*)take((size_t)NBKT * 4);
    float* dinv     = (float*)take((size_t)N_NODES * 4);
    int* bsum       = (int*)take(256 * 4);
    int* tops       = (int*)take(256 * 4);
    uint2* csr      = (uint2*)take((size_t)(N_EDGES + 8) * 8);  // +8 zeroed pad entries
    unsigned char* h1   = (unsigned char*)take((size_t)N_NODES * 128);
    unsigned short* out1 = (unsigned short*)take((size_t)N_NODES * 128 * 2);
    unsigned char* h2   = (unsigned char*)take((size_t)N_NODES * 64);
    float* identity = (float*)take((size_t)N_NODES * 64 * 4);
    unsigned short* wT   = (unsigned short*)take((size_t)192 * 128 * 2);
    unsigned short* w2T  = (unsigned short*)take((size_t)64 * 128 * 2);

    hipMemsetAsync(cnt, 0, (size_t)N_NODES * 4, stream);
    hipMemsetAsync(csr + N_EDGES, 0, 8 * sizeof(uint2), stream);

    k_hist<<<(N_EDGES + 255) / 256, 256, 0, stream>>>(dst, cnt);
    k_prep<<<(192 * 128 + 255) / 256, 256, 0, stream>>>(w1, wd, w2, wT, w2T);
    k_dinv<<<(N_NODES + 255) / 256, 256, 0, stream>>>(cnt, dinv);
    k_scan1<<<NB1, 256, 0, stream>>>(cnt, rowptr, bsum);
    k_scan2<<<1, 256, 0, stream>>>(bsum, tops);
    k_scan3<<<(N_NODES + 255) / 256, 256, 0, stream>>>(rowptr, tops);
    k_binit<<<(NBKT + 255) / 256, 256, 0, stream>>>(rowptr, bcur);
    k_fillA<<<NBA, 256, 0, stream>>>(src, dst, bcur, csr);
    k_fillB<<<NBKT, 256, 0, stream>>>(dinv, rowptr, csr);
    k_gemm1<<<(N_NODES + 127) / 128, 256, 0, stream>>>(x, wT, bd, h1, identity);
    k_agg1<<<(N_NODES + 3) / 4, 256, 0, stream>>>(h1, csr, rowptr, dinv, b1, out1);
    k_gemm2<<<(N_NODES + 127) / 128, 256, 0, stream>>>(out1, w2T, h2);
    k_agg2<<<(N_NODES + 3) / 4, 256, 0, stream>>>(h2, csr, rowptr, dinv, b2, identity, out);
}

// Round 8
// 293.043 us; speedup vs baseline: 1.7063x; 1.0759x over previous
//
#include <hip/hip_runtime.h>
#include <hip/hip_bf16.h>

#define N_NODES 100000
#define N_EDGES 1600000
#define NFEAT 128
#define NHID 128
#define NOUT 64
#define NEG_SLOPE 0.01f
#define NB1 98   // ceil(100000/1024)
#define LDA 136  // 128 + 8 pad (bf16) — row stride 272B, keeps 16B alignment for b128 LDS ops
#define BKT_SHIFT 8
#define NBKT 391          // ceil(100000/256) buckets of 256 nodes
#define EPB_A 4096        // edges per block in fillA
#define NBA 391           // ceil(1600000/4096)
#define MAXB 6144         // LDS entry cap per bucket

typedef short bf16x8 __attribute__((ext_vector_type(8)));
typedef float f32x4 __attribute__((ext_vector_type(4)));
typedef float f32x2 __attribute__((ext_vector_type(2)));

__device__ __forceinline__ unsigned short f2b(float f) {
    unsigned u = __float_as_uint(f);
    unsigned r = u + 0x7FFFu + ((u >> 16) & 1u);
    return (unsigned short)(r >> 16);
}
__device__ __forceinline__ float b2f(unsigned short h) {
    return __uint_as_float(((unsigned)h) << 16);
}
__device__ __forceinline__ float lrelu(float v) {
    return v > 0.f ? v : v * NEG_SLOPE;
}
// OCP e4m3 via gfx950 HW converts
__device__ __forceinline__ unsigned char f2fp8(float f) {
    return (unsigned char)(__builtin_amdgcn_cvt_pk_fp8_f32(f, f, 0, false) & 0xFF);
}

// ---- degree histogram over dst ----
__global__ void k_hist(const int* __restrict__ dst, int* __restrict__ cnt) {
    int e = blockIdx.x * 256 + threadIdx.x;
    if (e < N_EDGES) atomicAdd(&cnt[dst[e]], 1);
}

// ---- dinv = rsqrt(deg), deg = cnt + 1 (self loop) ----
__global__ void k_dinv(const int* __restrict__ cnt, float* __restrict__ dinv) {
    int i = blockIdx.x * 256 + threadIdx.x;
    if (i < N_NODES) dinv[i] = rsqrtf((float)(cnt[i] + 1));
}

// ---- transposed bf16 weights: wT[192][128] = [w1 | wd]^T, w2T[64][128] ----
__global__ void k_prep(const float* __restrict__ w1, const float* __restrict__ wd,
                       const float* __restrict__ w2,
                       unsigned short* __restrict__ wT, unsigned short* __restrict__ w2T) {
    int i = blockIdx.x * 256 + threadIdx.x;
    if (i < 192 * 128) {
        int n = i >> 7, k = i & 127;
        float v = (n < 128) ? w1[k * 128 + n] : wd[k * 64 + (n - 128)];
        wT[i] = f2b(v);
    }
    if (i < 64 * 128) {
        int n = i >> 7, k = i & 127;
        w2T[i] = f2b(w2[k * 64 + n]);
    }
}

// ---- scan stage 1 ----
__global__ __launch_bounds__(256) void k_scan1(const int* __restrict__ cnt,
                                               int* __restrict__ rowptr,
                                               int* __restrict__ bsum) {
    __shared__ int sc[256];
    int t = threadIdx.x;
    int base = blockIdx.x * 1024 + t * 4;
    int v0 = (base + 0 < N_NODES) ? cnt[base + 0] : 0;
    int v1 = (base + 1 < N_NODES) ? cnt[base + 1] : 0;
    int v2 = (base + 2 < N_NODES) ? cnt[base + 2] : 0;
    int v3 = (base + 3 < N_NODES) ? cnt[base + 3] : 0;
    int s = v0 + v1 + v2 + v3;
    sc[t] = s;
    __syncthreads();
    for (int off = 1; off < 256; off <<= 1) {
        int xv = (t >= off) ? sc[t - off] : 0;
        __syncthreads();
        sc[t] += xv;
        __syncthreads();
    }
    int run = sc[t] - s;
    if (base + 0 < N_NODES) { rowptr[base + 0] = run; run += v0; }
    if (base + 1 < N_NODES) { rowptr[base + 1] = run; run += v1; }
    if (base + 2 < N_NODES) { rowptr[base + 2] = run; run += v2; }
    if (base + 3 < N_NODES) { rowptr[base + 3] = run; run += v3; }
    if (t == 0) bsum[blockIdx.x] = sc[255];
}

// ---- scan stage 2 ----
__global__ __launch_bounds__(256) void k_scan2(const int* __restrict__ bsum,
                                               int* __restrict__ tops) {
    __shared__ int sc[256];
    int t = threadIdx.x;
    int s = (t < NB1) ? bsum[t] : 0;
    sc[t] = s;
    __syncthreads();
    for (int off = 1; off < 256; off <<= 1) {
        int xv = (t >= off) ? sc[t - off] : 0;
        __syncthreads();
        sc[t] += xv;
        __syncthreads();
    }
    tops[t] = sc[t] - s;
}

// ---- scan stage 3 ----
__global__ void k_scan3(int* __restrict__ rowptr, const int* __restrict__ tops) {
    int i = blockIdx.x * 256 + threadIdx.x;
    if (i < N_NODES) rowptr[i] += tops[i >> 10];
    if (i == 0) rowptr[N_NODES] = N_EDGES;
}

// ---- bucket cursor init ----
__global__ void k_binit(const int* __restrict__ rowptr, int* __restrict__ bcur) {
    int i = blockIdx.x * 256 + threadIdx.x;
    if (i < NBKT) bcur[i] = rowptr[i << BKT_SHIFT];
}

// ---- fillA: coarse bucket scatter ----
__global__ __launch_bounds__(256) void k_fillA(const int* __restrict__ src,
                                               const int* __restrict__ dst,
                                               int* __restrict__ bcur,
                                               uint2* __restrict__ csr) {
    __shared__ int lcnt[NBKT];
    __shared__ int lbase[NBKT];
    const int t = threadIdx.x;
    const int e0 = blockIdx.x * EPB_A;
    const int nd = min(EPB_A, N_EDGES - e0);
    for (int i = t; i < NBKT; i += 256) lcnt[i] = 0;
    __syncthreads();
    for (int i = t; i < nd; i += 256) {
        int d = dst[e0 + i];
        atomicAdd(&lcnt[d >> BKT_SHIFT], 1);
    }
    __syncthreads();
    for (int i = t; i < NBKT; i += 256)
        lbase[i] = lcnt[i] ? atomicAdd(&bcur[i], lcnt[i]) : 0;
    __syncthreads();
    for (int i = t; i < NBKT; i += 256) lcnt[i] = 0;
    __syncthreads();
    for (int i = t; i < nd; i += 256) {
        int s = src[e0 + i];
        int d = dst[e0 + i];
        int b = d >> BKT_SHIFT;
        int off = atomicAdd(&lcnt[b], 1);
        csr[lbase[b] + off] = make_uint2((unsigned)s, (unsigned)d);
    }
}

// ---- fillB: in-place fine permutation within each bucket ----
__global__ __launch_bounds__(256) void k_fillB(const float* __restrict__ dinv,
                                               const int* __restrict__ rowptr,
                                               uint2* __restrict__ csr) {
    __shared__ uint2 lbuf[MAXB];
    __shared__ int lcur[256];
    __shared__ int lrp[256];
    const int t = threadIdx.x;
    const int b = blockIdx.x;
    const int n0 = b << BKT_SHIFT;
    const int n1 = min(n0 + 256, N_NODES);
    const int R0 = rowptr[n0], R1 = rowptr[n1];
    const int cnt = R1 - R0;
    for (int i = t; i < cnt; i += 256) lbuf[i] = csr[R0 + i];
    if (n0 + t < n1) lrp[t] = rowptr[n0 + t];
    lcur[t] = 0;
    __syncthreads();
    for (int i = t; i < cnt; i += 256) {
        uint2 e = lbuf[i];
        int li = (int)e.y & 255;
        int r = atomicAdd(&lcur[li], 1);
        int p = lrp[li] + r;
        csr[p] = make_uint2(e.x, __float_as_uint(dinv[e.x]));
    }
}

// ---- MFMA GEMM1: h1 = fp8(x@w1), identity = x@wd + bd ----
__global__ __launch_bounds__(256) void k_gemm1(const float* __restrict__ x,
                                               const unsigned short* __restrict__ wT,
                                               const float* __restrict__ bd,
                                               unsigned char* __restrict__ h1,
                                               float* __restrict__ identity) {
    __shared__ unsigned short As[128][LDA];
    const int t = threadIdx.x;
    const int rb = blockIdx.x * 128;
    {
        int row = t >> 1, half = t & 1;
        int grow = rb + row;
        if (grow < N_NODES) {
            const float* srcp = &x[(size_t)grow * 128 + half * 64];
#pragma unroll
            for (int i = 0; i < 8; i++) {
                float4 va = *(const float4*)&srcp[i * 8];
                float4 vb = *(const float4*)&srcp[i * 8 + 4];
                unsigned short u[8];
                u[0] = f2b(va.x); u[1] = f2b(va.y); u[2] = f2b(va.z); u[3] = f2b(va.w);
                u[4] = f2b(vb.x); u[5] = f2b(vb.y); u[6] = f2b(vb.z); u[7] = f2b(vb.w);
                *(bf16x8*)&As[row][half * 64 + i * 8] = *(bf16x8*)u;
            }
        } else {
            bf16x8 z = (bf16x8){0, 0, 0, 0, 0, 0, 0, 0};
#pragma unroll
            for (int i = 0; i < 8; i++) *(bf16x8*)&As[row][half * 64 + i * 8] = z;
        }
    }
    __syncthreads();
    const int wid = t >> 6, lane = t & 63;
    const int wr = wid >> 1, wc = wid & 1;
    const int mr = wr * 64, nc = wc * 96;
    const int lrow = lane & 15, lk = (lane >> 4) * 8;
    f32x4 acc[4][6];
#pragma unroll
    for (int m = 0; m < 4; m++)
#pragma unroll
        for (int n = 0; n < 6; n++) acc[m][n] = (f32x4){0.f, 0.f, 0.f, 0.f};

#pragma unroll
    for (int ki = 0; ki < 4; ki++) {
        const int k0 = ki * 32;
        bf16x8 a[4];
#pragma unroll
        for (int m = 0; m < 4; m++)
            a[m] = *(const bf16x8*)&As[mr + m * 16 + lrow][k0 + lk];
#pragma unroll
        for (int n = 0; n < 6; n++) {
            bf16x8 b = *(const bf16x8*)&wT[(size_t)(nc + n * 16 + lrow) * 128 + k0 + lk];
#pragma unroll
            for (int m = 0; m < 4; m++)
                acc[m][n] = __builtin_amdgcn_mfma_f32_16x16x32_bf16(a[m], b, acc[m][n], 0, 0, 0);
        }
    }
    const int crow0 = (lane >> 4) * 4;
#pragma unroll
    for (int m = 0; m < 4; m++) {
#pragma unroll
        for (int j = 0; j < 4; j++) {
            int grow = rb + mr + m * 16 + crow0 + j;
            if (grow >= N_NODES) continue;
#pragma unroll
            for (int n = 0; n < 6; n++) {
                int col = nc + n * 16 + lrow;
                float v = acc[m][n][j];
                if (col < 128) h1[(size_t)grow * 128 + col] = f2fp8(v);
                else           identity[(size_t)grow * 64 + (col - 128)] = v + bd[col - 128];
            }
        }
    }
}

// ---- MFMA GEMM2: h2 = fp8(out1 @ w2), tile 128 x 64 ----
__global__ __launch_bounds__(256) void k_gemm2(const unsigned short* __restrict__ a_in,
                                               const unsigned short* __restrict__ w2T,
                                               unsigned char* __restrict__ h2) {
    __shared__ unsigned short As[128][LDA];
    const int t = threadIdx.x;
    const int rb = blockIdx.x * 128;
    {
        int row = t >> 1, half = t & 1;
        int grow = rb + row;
        if (grow < N_NODES) {
#pragma unroll
            for (int i = 0; i < 8; i++)
                *(bf16x8*)&As[row][half * 64 + i * 8] =
                    *(const bf16x8*)&a_in[(size_t)grow * 128 + half * 64 + i * 8];
        } else {
            bf16x8 z = (bf16x8){0, 0, 0, 0, 0, 0, 0, 0};
#pragma unroll
            for (int i = 0; i < 8; i++) *(bf16x8*)&As[row][half * 64 + i * 8] = z;
        }
    }
    __syncthreads();
    const int wid = t >> 6, lane = t & 63;
    const int wr = wid >> 1, wc = wid & 1;
    const int mr = wr * 64, nc = wc * 32;
    const int lrow = lane & 15, lk = (lane >> 4) * 8;
    f32x4 acc[4][2];
#pragma unroll
    for (int m = 0; m < 4; m++)
#pragma unroll
        for (int n = 0; n < 2; n++) acc[m][n] = (f32x4){0.f, 0.f, 0.f, 0.f};

#pragma unroll
    for (int ki = 0; ki < 4; ki++) {
        const int k0 = ki * 32;
        bf16x8 a[4];
#pragma unroll
        for (int m = 0; m < 4; m++)
            a[m] = *(const bf16x8*)&As[mr + m * 16 + lrow][k0 + lk];
#pragma unroll
        for (int n = 0; n < 2; n++) {
            bf16x8 b = *(const bf16x8*)&w2T[(size_t)(nc + n * 16 + lrow) * 128 + k0 + lk];
#pragma unroll
            for (int m = 0; m < 4; m++)
                acc[m][n] = __builtin_amdgcn_mfma_f32_16x16x32_bf16(a[m], b, acc[m][n], 0, 0, 0);
        }
    }
    const int crow0 = (lane >> 4) * 4;
#pragma unroll
    for (int m = 0; m < 4; m++) {
#pragma unroll
        for (int j = 0; j < 4; j++) {
            int grow = rb + mr + m * 16 + crow0 + j;
            if (grow >= N_NODES) continue;
#pragma unroll
            for (int n = 0; n < 2; n++) {
                int col = nc + n * 16 + lrow;
                h2[(size_t)grow * 64 + col] = f2fp8(acc[m][n][j]);
            }
        }
    }
}

// ---- aggregate 1: out1 = leaky(sum_e norm*h1[src] + dinv^2*h1[i] + b1), 128 feats, fp8 h1 ----
// wave = 1 node; 8 groups x 8 lanes; group g handles edge e0+g, lane covers 16 feats (16B fp8)
// csr entry for next iteration prefetched to hide the csr->gather serial chain
__global__ __launch_bounds__(256) void k_agg1(const unsigned char* __restrict__ h1,
                                              const uint2* __restrict__ csr,
                                              const int* __restrict__ rowptr,
                                              const float* __restrict__ dinv,
                                              const float* __restrict__ b1,
                                              unsigned short* __restrict__ out1) {
    int node = blockIdx.x * 4 + (threadIdx.x >> 6);
    if (node >= N_NODES) return;
    const int lane = threadIdx.x & 63;
    const int g = lane >> 3;   // edge slot 0..7
    const int l = lane & 7;    // feature chunk: [l*16, l*16+16)
    const float di = dinv[node];
    float a[16];
#pragma unroll
    for (int i = 0; i < 16; i++) a[i] = 0.f;
    const int beg = rowptr[node], end = rowptr[node + 1];
    uint2 ce = csr[beg + g];                 // csr padded with 16 zeroed entries
    for (int e0 = beg; e0 < end; e0 += 8) {
        uint2 ce_n = csr[e0 + 8 + g];        // prefetch next iteration's entry
        int e = e0 + g;
        if (e < end) {
            float w = __uint_as_float(ce.y) * di;
            uint4 h = *(const uint4*)&h1[(size_t)ce.x * 128 + l * 16];
            f32x2 f0 = __builtin_amdgcn_cvt_pk_f32_fp8(h.x, false);
            f32x2 f1 = __builtin_amdgcn_cvt_pk_f32_fp8(h.x, true);
            f32x2 f2 = __builtin_amdgcn_cvt_pk_f32_fp8(h.y, false);
            f32x2 f3 = __builtin_amdgcn_cvt_pk_f32_fp8(h.y, true);
            f32x2 f4 = __builtin_amdgcn_cvt_pk_f32_fp8(h.z, false);
            f32x2 f5 = __builtin_amdgcn_cvt_pk_f32_fp8(h.z, true);
            f32x2 f6 = __builtin_amdgcn_cvt_pk_f32_fp8(h.w, false);
            f32x2 f7 = __builtin_amdgcn_cvt_pk_f32_fp8(h.w, true);
            a[0]  = fmaf(w, f0.x, a[0]);  a[1]  = fmaf(w, f0.y, a[1]);
            a[2]  = fmaf(w, f1.x, a[2]);  a[3]  = fmaf(w, f1.y, a[3]);
            a[4]  = fmaf(w, f2.x, a[4]);  a[5]  = fmaf(w, f2.y, a[5]);
            a[6]  = fmaf(w, f3.x, a[6]);  a[7]  = fmaf(w, f3.y, a[7]);
            a[8]  = fmaf(w, f4.x, a[8]);  a[9]  = fmaf(w, f4.y, a[9]);
            a[10] = fmaf(w, f5.x, a[10]); a[11] = fmaf(w, f5.y, a[11]);
            a[12] = fmaf(w, f6.x, a[12]); a[13] = fmaf(w, f6.y, a[13]);
            a[14] = fmaf(w, f7.x, a[14]); a[15] = fmaf(w, f7.y, a[15]);
        }
        ce = ce_n;
    }
#pragma unroll
    for (int i = 0; i < 16; i++) {
        a[i] += __shfl_xor(a[i], 8);
        a[i] += __shfl_xor(a[i], 16);
        a[i] += __shfl_xor(a[i], 32);
    }
    if (g == 0) {
        float di2 = di * di;
        uint4 hs = *(const uint4*)&h1[(size_t)node * 128 + l * 16];
        f32x2 s0 = __builtin_amdgcn_cvt_pk_f32_fp8(hs.x, false);
        f32x2 s1 = __builtin_amdgcn_cvt_pk_f32_fp8(hs.x, true);
        f32x2 s2 = __builtin_amdgcn_cvt_pk_f32_fp8(hs.y, false);
        f32x2 s3 = __builtin_amdgcn_cvt_pk_f32_fp8(hs.y, true);
        f32x2 s4 = __builtin_amdgcn_cvt_pk_f32_fp8(hs.z, false);
        f32x2 s5 = __builtin_amdgcn_cvt_pk_f32_fp8(hs.z, true);
        f32x2 s6 = __builtin_amdgcn_cvt_pk_f32_fp8(hs.w, false);
        f32x2 s7 = __builtin_amdgcn_cvt_pk_f32_fp8(hs.w, true);
        a[0]  = fmaf(di2, s0.x, a[0]);  a[1]  = fmaf(di2, s0.y, a[1]);
        a[2]  = fmaf(di2, s1.x, a[2]);  a[3]  = fmaf(di2, s1.y, a[3]);
        a[4]  = fmaf(di2, s2.x, a[4]);  a[5]  = fmaf(di2, s2.y, a[5]);
        a[6]  = fmaf(di2, s3.x, a[6]);  a[7]  = fmaf(di2, s3.y, a[7]);
        a[8]  = fmaf(di2, s4.x, a[8]);  a[9]  = fmaf(di2, s4.y, a[9]);
        a[10] = fmaf(di2, s5.x, a[10]); a[11] = fmaf(di2, s5.y, a[11]);
        a[12] = fmaf(di2, s6.x, a[12]); a[13] = fmaf(di2, s6.y, a[13]);
        a[14] = fmaf(di2, s7.x, a[14]); a[15] = fmaf(di2, s7.y, a[15]);
        const float* bp = &b1[l * 16];
        float4 b0 = *(const float4*)&bp[0];
        float4 b4 = *(const float4*)&bp[4];
        float4 b8 = *(const float4*)&bp[8];
        float4 bc = *(const float4*)&bp[12];
        float v0  = lrelu(a[0]  + b0.x), v1  = lrelu(a[1]  + b0.y);
        float v2  = lrelu(a[2]  + b0.z), v3  = lrelu(a[3]  + b0.w);
        float v4  = lrelu(a[4]  + b4.x), v5  = lrelu(a[5]  + b4.y);
        float v6  = lrelu(a[6]  + b4.z), v7  = lrelu(a[7]  + b4.w);
        float v8  = lrelu(a[8]  + b8.x), v9  = lrelu(a[9]  + b8.y);
        float v10 = lrelu(a[10] + b8.z), v11 = lrelu(a[11] + b8.w);
        float v12 = lrelu(a[12] + bc.x), v13 = lrelu(a[13] + bc.y);
        float v14 = lrelu(a[14] + bc.z), v15 = lrelu(a[15] + bc.w);
        uint4 o0, o1;
        o0.x = (unsigned)f2b(v0)  | ((unsigned)f2b(v1)  << 16);
        o0.y = (unsigned)f2b(v2)  | ((unsigned)f2b(v3)  << 16);
        o0.z = (unsigned)f2b(v4)  | ((unsigned)f2b(v5)  << 16);
        o0.w = (unsigned)f2b(v6)  | ((unsigned)f2b(v7)  << 16);
        o1.x = (unsigned)f2b(v8)  | ((unsigned)f2b(v9)  << 16);
        o1.y = (unsigned)f2b(v10) | ((unsigned)f2b(v11) << 16);
        o1.z = (unsigned)f2b(v12) | ((unsigned)f2b(v13) << 16);
        o1.w = (unsigned)f2b(v14) | ((unsigned)f2b(v15) << 16);
        *(uint4*)&out1[(size_t)node * 128 + l * 16]     = o0;
        *(uint4*)&out1[(size_t)node * 128 + l * 16 + 8] = o1;
    }
}

// ---- aggregate 2 + epilogue: out = leaky(agg(h2) + b2) + identity, 64 feats, fp8 h2 ----
// wave = 1 node; 8 groups x 8 lanes; lane covers 8 feats (8B fp8); csr prefetch as agg1
__global__ __launch_bounds__(256) void k_agg2(const unsigned char* __restrict__ h2,
                                              const uint2* __restrict__ csr,
                                              const int* __restrict__ rowptr,
                                              const float* __restrict__ dinv,
                                              const float* __restrict__ b2,
                                              const float* __restrict__ identity,
                                              float* __restrict__ out) {
    int node = blockIdx.x * 4 + (threadIdx.x >> 6);
    if (node >= N_NODES) return;
    const int lane = threadIdx.x & 63;
    const int g = lane >> 3;
    const int l = lane & 7;    // feature chunk: [l*8, l*8+8)
    const float di = dinv[node];
    float a[8];
#pragma unroll
    for (int i = 0; i < 8; i++) a[i] = 0.f;
    const int beg = rowptr[node], end = rowptr[node + 1];
    uint2 ce = csr[beg + g];
    for (int e0 = beg; e0 < end; e0 += 8) {
        uint2 ce_n = csr[e0 + 8 + g];
        int e = e0 + g;
        if (e < end) {
            float w = __uint_as_float(ce.y) * di;
            uint2 h = *(const uint2*)&h2[(size_t)ce.x * 64 + l * 8];
            f32x2 f0 = __builtin_amdgcn_cvt_pk_f32_fp8(h.x, false);
            f32x2 f1 = __builtin_amdgcn_cvt_pk_f32_fp8(h.x, true);
            f32x2 f2 = __builtin_amdgcn_cvt_pk_f32_fp8(h.y, false);
            f32x2 f3 = __builtin_amdgcn_cvt_pk_f32_fp8(h.y, true);
            a[0] = fmaf(w, f0.x, a[0]); a[1] = fmaf(w, f0.y, a[1]);
            a[2] = fmaf(w, f1.x, a[2]); a[3] = fmaf(w, f1.y, a[3]);
            a[4] = fmaf(w, f2.x, a[4]); a[5] = fmaf(w, f2.y, a[5]);
            a[6] = fmaf(w, f3.x, a[6]); a[7] = fmaf(w, f3.y, a[7]);
        }
        ce = ce_n;
    }
#pragma unroll
    for (int i = 0; i < 8; i++) {
        a[i] += __shfl_xor(a[i], 8);
        a[i] += __shfl_xor(a[i], 16);
        a[i] += __shfl_xor(a[i], 32);
    }
    if (g == 0) {
        float di2 = di * di;
        uint2 hs = *(const uint2*)&h2[(size_t)node * 64 + l * 8];
        f32x2 s0 = __builtin_amdgcn_cvt_pk_f32_fp8(hs.x, false);
        f32x2 s1 = __builtin_amdgcn_cvt_pk_f32_fp8(hs.x, true);
        f32x2 s2 = __builtin_amdgcn_cvt_pk_f32_fp8(hs.y, false);
        f32x2 s3 = __builtin_amdgcn_cvt_pk_f32_fp8(hs.y, true);
        a[0] = fmaf(di2, s0.x, a[0]); a[1] = fmaf(di2, s0.y, a[1]);
        a[2] = fmaf(di2, s1.x, a[2]); a[3] = fmaf(di2, s1.y, a[3]);
        a[4] = fmaf(di2, s2.x, a[4]); a[5] = fmaf(di2, s2.y, a[5]);
        a[6] = fmaf(di2, s3.x, a[6]); a[7] = fmaf(di2, s3.y, a[7]);
        const float* bp = &b2[l * 8];
        float4 bb0 = *(const float4*)&bp[0];
        float4 bb4 = *(const float4*)&bp[4];
        const float* ip = &identity[(size_t)node * 64 + l * 8];
        float4 id0 = *(const float4*)&ip[0];
        float4 id4 = *(const float4*)&ip[4];
        float4 o0, o1;
        o0.x = lrelu(a[0] + bb0.x) + id0.x;
        o0.y = lrelu(a[1] + bb0.y) + id0.y;
        o0.z = lrelu(a[2] + bb0.z) + id0.z;
        o0.w = lrelu(a[3] + bb0.w) + id0.w;
        o1.x = lrelu(a[4] + bb4.x) + id4.x;
        o1.y = lrelu(a[5] + bb4.y) + id4.y;
        o1.z = lrelu(a[6] + bb4.z) + id4.z;
        o1.w = lrelu(a[7] + bb4.w) + id4.w;
        float* op = &out[(size_t)node * 64 + l * 8];
        *(float4*)&op[0] = o0;
        *(float4*)&op[4] = o1;
    }
}

extern "C" void kernel_launch(void* const* d_in, const int* in_sizes, int n_in,
                              void* d_out, int out_size, void* d_ws, size_t ws_size,
                              hipStream_t stream) {
    const float* x  = (const float*)d_in[0];
    const int* eidx = (const int*)d_in[1];
    const float* w1 = (const float*)d_in[2];
    const float* b1 = (const float*)d_in[3];
    const float* w2 = (const float*)d_in[4];
    const float* b2 = (const float*)d_in[5];
    const float* wd = (const float*)d_in[6];
    const float* bd = (const float*)d_in[7];
    const int* src = eidx;
    const int* dst = eidx + N_EDGES;
    float* out = (float*)d_out;

    char* ws = (char*)d_ws;
    size_t off = 0;
    auto take = [&](size_t bytes) -> char* {
        char* p = ws + off;
        off = (off + bytes + 255) & ~(size_t)255;
        return p;
    };
    int* cnt        = (int*)take((size_t)N_NODES * 4);
    int* rowptr     = (int*)take((size_t)(N_NODES + 1) * 4);
    int* bcur       = (int*)take((size_t)NBKT * 4);
    float* dinv     = (float*)take((size_t)N_NODES * 4);
    int* bsum       = (int*)take(256 * 4);
    int* tops       = (int*)take(256 * 4);
    uint2* csr      = (uint2*)take((size_t)(N_EDGES + 16) * 8);  // +16 zeroed pad entries
    unsigned char* h1   = (unsigned char*)take((size_t)N_NODES * 128);
    unsigned short* out1 = (unsigned short*)take((size_t)N_NODES * 128 * 2);
    unsigned char* h2   = (unsigned char*)take((size_t)N_NODES * 64);
    float* identity = (float*)take((size_t)N_NODES * 64 * 4);
    unsigned short* wT   = (unsigned short*)take((size_t)192 * 128 * 2);
    unsigned short* w2T  = (unsigned short*)take((size_t)64 * 128 * 2);

    hipMemsetAsync(cnt, 0, (size_t)N_NODES * 4, stream);
    hipMemsetAsync(csr + N_EDGES, 0, 16 * sizeof(uint2), stream);

    k_hist<<<(N_EDGES + 255) / 256, 256, 0, stream>>>(dst, cnt);
    k_prep<<<(192 * 128 + 255) / 256, 256, 0, stream>>>(w1, wd, w2, wT, w2T);
    k_dinv<<<(N_NODES + 255) / 256, 256, 0, stream>>>(cnt, dinv);
    k_scan1<<<NB1, 256, 0, stream>>>(cnt, rowptr, bsum);
    k_scan2<<<1, 256, 0, stream>>>(bsum, tops);
    k_scan3<<<(N_NODES + 255) / 256, 256, 0, stream>>>(rowptr, tops);
    k_binit<<<(NBKT + 255) / 256, 256, 0, stream>>>(rowptr, bcur);
    k_fillA<<<NBA, 256, 0, stream>>>(src, dst, bcur, csr);
    k_fillB<<<NBKT, 256, 0, stream>>>(dinv, rowptr, csr);
    k_gemm1<<<(N_NODES + 127) / 128, 256, 0, stream>>>(x, wT, bd, h1, identity);
    k_agg1<<<(N_NODES + 3) / 4, 256, 0, stream>>>(h1, csr, rowptr, dinv, b1, out1);
    k_gemm2<<<(N_NODES + 127) / 128, 256, 0, stream>>>(out1, w2T, h2);
    k_agg2<<<(N_NODES + 3) / 4, 256, 0, stream>>>(h2, csr, rowptr, dinv, b2, identity, out);
}

// Round 11
// 292.406 us; speedup vs baseline: 1.7100x; 1.0022x over previous
//
#include <hip/hip_runtime.h>
#include <hip/hip_bf16.h>

#define N_NODES 100000
#define N_EDGES 1600000
#define NFEAT 128
#define NHID 128
#define NOUT 64
#define NEG_SLOPE 0.01f
#define NB1 98   // ceil(100000/1024)
#define LDA 136  // 128 + 8 pad (bf16) — row stride 272B, keeps 16B alignment for b128 LDS ops
#define BKT_SHIFT 8
#define NBKT 391          // ceil(100000/256) buckets of 256 nodes
#define EPB_A 4096        // edges per block in fillA
#define NBA 391           // ceil(1600000/4096)
#define MAXB 6144         // LDS entry cap per bucket

typedef short bf16x8 __attribute__((ext_vector_type(8)));
typedef float f32x4 __attribute__((ext_vector_type(4)));
typedef float f32x2 __attribute__((ext_vector_type(2)));

__device__ __forceinline__ unsigned short f2b(float f) {
    unsigned u = __float_as_uint(f);
    unsigned r = u + 0x7FFFu + ((u >> 16) & 1u);
    return (unsigned short)(r >> 16);
}
__device__ __forceinline__ float b2f(unsigned short h) {
    return __uint_as_float(((unsigned)h) << 16);
}
__device__ __forceinline__ float lrelu(float v) {
    return v > 0.f ? v : v * NEG_SLOPE;
}
// OCP e4m3 via gfx950 HW converts
__device__ __forceinline__ unsigned char f2fp8(float f) {
    return (unsigned char)(__builtin_amdgcn_cvt_pk_fp8_f32(f, f, 0, false) & 0xFF);
}

// ---- degree histogram over dst ----
__global__ void k_hist(const int* __restrict__ dst, int* __restrict__ cnt) {
    int e = blockIdx.x * 256 + threadIdx.x;
    if (e < N_EDGES) atomicAdd(&cnt[dst[e]], 1);
}

// ---- dinv = rsqrt(deg), deg = cnt + 1 (self loop) ----
__global__ void k_dinv(const int* __restrict__ cnt, float* __restrict__ dinv) {
    int i = blockIdx.x * 256 + threadIdx.x;
    if (i < N_NODES) dinv[i] = rsqrtf((float)(cnt[i] + 1));
}

// ---- transposed bf16 weights: wT[192][128] = [w1 | wd]^T, w2T[64][128] ----
__global__ void k_prep(const float* __restrict__ w1, const float* __restrict__ wd,
                       const float* __restrict__ w2,
                       unsigned short* __restrict__ wT, unsigned short* __restrict__ w2T) {
    int i = blockIdx.x * 256 + threadIdx.x;
    if (i < 192 * 128) {
        int n = i >> 7, k = i & 127;
        float v = (n < 128) ? w1[k * 128 + n] : wd[k * 64 + (n - 128)];
        wT[i] = f2b(v);
    }
    if (i < 64 * 128) {
        int n = i >> 7, k = i & 127;
        w2T[i] = f2b(w2[k * 64 + n]);
    }
}

// ---- scan stage 1 ----
__global__ __launch_bounds__(256) void k_scan1(const int* __restrict__ cnt,
                                               int* __restrict__ rowptr,
                                               int* __restrict__ bsum) {
    __shared__ int sc[256];
    int t = threadIdx.x;
    int base = blockIdx.x * 1024 + t * 4;
    int v0 = (base + 0 < N_NODES) ? cnt[base + 0] : 0;
    int v1 = (base + 1 < N_NODES) ? cnt[base + 1] : 0;
    int v2 = (base + 2 < N_NODES) ? cnt[base + 2] : 0;
    int v3 = (base + 3 < N_NODES) ? cnt[base + 3] : 0;
    int s = v0 + v1 + v2 + v3;
    sc[t] = s;
    __syncthreads();
    for (int off = 1; off < 256; off <<= 1) {
        int xv = (t >= off) ? sc[t - off] : 0;
        __syncthreads();
        sc[t] += xv;
        __syncthreads();
    }
    int run = sc[t] - s;
    if (base + 0 < N_NODES) { rowptr[base + 0] = run; run += v0; }
    if (base + 1 < N_NODES) { rowptr[base + 1] = run; run += v1; }
    if (base + 2 < N_NODES) { rowptr[base + 2] = run; run += v2; }
    if (base + 3 < N_NODES) { rowptr[base + 3] = run; run += v3; }
    if (t == 0) bsum[blockIdx.x] = sc[255];
}

// ---- scan stage 2 ----
__global__ __launch_bounds__(256) void k_scan2(const int* __restrict__ bsum,
                                               int* __restrict__ tops) {
    __shared__ int sc[256];
    int t = threadIdx.x;
    int s = (t < NB1) ? bsum[t] : 0;
    sc[t] = s;
    __syncthreads();
    for (int off = 1; off < 256; off <<= 1) {
        int xv = (t >= off) ? sc[t - off] : 0;
        __syncthreads();
        sc[t] += xv;
        __syncthreads();
    }
    tops[t] = sc[t] - s;
}

// ---- scan stage 3 ----
__global__ void k_scan3(int* __restrict__ rowptr, const int* __restrict__ tops) {
    int i = blockIdx.x * 256 + threadIdx.x;
    if (i < N_NODES) rowptr[i] += tops[i >> 10];
    if (i == 0) rowptr[N_NODES] = N_EDGES;
}

// ---- bucket cursor init ----
__global__ void k_binit(const int* __restrict__ rowptr, int* __restrict__ bcur) {
    int i = blockIdx.x * 256 + threadIdx.x;
    if (i < NBKT) bcur[i] = rowptr[i << BKT_SHIFT];
}

// ---- fillA: coarse bucket scatter ----
__global__ __launch_bounds__(256) void k_fillA(const int* __restrict__ src,
                                               const int* __restrict__ dst,
                                               int* __restrict__ bcur,
                                               uint2* __restrict__ csr) {
    __shared__ int lcnt[NBKT];
    __shared__ int lbase[NBKT];
    const int t = threadIdx.x;
    const int e0 = blockIdx.x * EPB_A;
    const int nd = min(EPB_A, N_EDGES - e0);
    for (int i = t; i < NBKT; i += 256) lcnt[i] = 0;
    __syncthreads();
    for (int i = t; i < nd; i += 256) {
        int d = dst[e0 + i];
        atomicAdd(&lcnt[d >> BKT_SHIFT], 1);
    }
    __syncthreads();
    for (int i = t; i < NBKT; i += 256)
        lbase[i] = lcnt[i] ? atomicAdd(&bcur[i], lcnt[i]) : 0;
    __syncthreads();
    for (int i = t; i < NBKT; i += 256) lcnt[i] = 0;
    __syncthreads();
    for (int i = t; i < nd; i += 256) {
        int s = src[e0 + i];
        int d = dst[e0 + i];
        int b = d >> BKT_SHIFT;
        int off = atomicAdd(&lcnt[b], 1);
        csr[lbase[b] + off] = make_uint2((unsigned)s, (unsigned)d);
    }
}

// ---- fillB: in-place fine permutation within each bucket ----
__global__ __launch_bounds__(256) void k_fillB(const float* __restrict__ dinv,
                                               const int* __restrict__ rowptr,
                                               uint2* __restrict__ csr) {
    __shared__ uint2 lbuf[MAXB];
    __shared__ int lcur[256];
    __shared__ int lrp[256];
    const int t = threadIdx.x;
    const int b = blockIdx.x;
    const int n0 = b << BKT_SHIFT;
    const int n1 = min(n0 + 256, N_NODES);
    const int R0 = rowptr[n0], R1 = rowptr[n1];
    const int cnt = R1 - R0;
    for (int i = t; i < cnt; i += 256) lbuf[i] = csr[R0 + i];
    if (n0 + t < n1) lrp[t] = rowptr[n0 + t];
    lcur[t] = 0;
    __syncthreads();
    for (int i = t; i < cnt; i += 256) {
        uint2 e = lbuf[i];
        int li = (int)e.y & 255;
        int r = atomicAdd(&lcur[li], 1);
        int p = lrp[li] + r;
        csr[p] = make_uint2(e.x, __float_as_uint(dinv[e.x]));
    }
}

// ---- MFMA GEMM1: h1 = fp8(x@w1), identity = x@wd + bd ----
__global__ __launch_bounds__(256) void k_gemm1(const float* __restrict__ x,
                                               const unsigned short* __restrict__ wT,
                                               const float* __restrict__ bd,
                                               unsigned char* __restrict__ h1,
                                               float* __restrict__ identity) {
    __shared__ unsigned short As[128][LDA];
    const int t = threadIdx.x;
    const int rb = blockIdx.x * 128;
    {
        int row = t >> 1, half = t & 1;
        int grow = rb + row;
        if (grow < N_NODES) {
            const float* srcp = &x[(size_t)grow * 128 + half * 64];
#pragma unroll
            for (int i = 0; i < 8; i++) {
                float4 va = *(const float4*)&srcp[i * 8];
                float4 vb = *(const float4*)&srcp[i * 8 + 4];
                unsigned short u[8];
                u[0] = f2b(va.x); u[1] = f2b(va.y); u[2] = f2b(va.z); u[3] = f2b(va.w);
                u[4] = f2b(vb.x); u[5] = f2b(vb.y); u[6] = f2b(vb.z); u[7] = f2b(vb.w);
                *(bf16x8*)&As[row][half * 64 + i * 8] = *(bf16x8*)u;
            }
        } else {
            bf16x8 z = (bf16x8){0, 0, 0, 0, 0, 0, 0, 0};
#pragma unroll
            for (int i = 0; i < 8; i++) *(bf16x8*)&As[row][half * 64 + i * 8] = z;
        }
    }
    __syncthreads();
    const int wid = t >> 6, lane = t & 63;
    const int wr = wid >> 1, wc = wid & 1;
    const int mr = wr * 64, nc = wc * 96;
    const int lrow = lane & 15, lk = (lane >> 4) * 8;
    f32x4 acc[4][6];
#pragma unroll
    for (int m = 0; m < 4; m++)
#pragma unroll
        for (int n = 0; n < 6; n++) acc[m][n] = (f32x4){0.f, 0.f, 0.f, 0.f};

#pragma unroll
    for (int ki = 0; ki < 4; ki++) {
        const int k0 = ki * 32;
        bf16x8 a[4];
#pragma unroll
        for (int m = 0; m < 4; m++)
            a[m] = *(const bf16x8*)&As[mr + m * 16 + lrow][k0 + lk];
#pragma unroll
        for (int n = 0; n < 6; n++) {
            bf16x8 b = *(const bf16x8*)&wT[(size_t)(nc + n * 16 + lrow) * 128 + k0 + lk];
#pragma unroll
            for (int m = 0; m < 4; m++)
                acc[m][n] = __builtin_amdgcn_mfma_f32_16x16x32_bf16(a[m], b, acc[m][n], 0, 0, 0);
        }
    }
    const int crow0 = (lane >> 4) * 4;
#pragma unroll
    for (int m = 0; m < 4; m++) {
#pragma unroll
        for (int j = 0; j < 4; j++) {
            int grow = rb + mr + m * 16 + crow0 + j;
            if (grow >= N_NODES) continue;
#pragma unroll
            for (int n = 0; n < 6; n++) {
                int col = nc + n * 16 + lrow;
                float v = acc[m][n][j];
                if (col < 128) h1[(size_t)grow * 128 + col] = f2fp8(v);
                else           identity[(size_t)grow * 64 + (col - 128)] = v + bd[col - 128];
            }
        }
    }
}

// ---- MFMA GEMM2: h2 = fp8(out1 @ w2), tile 128 x 64 ----
__global__ __launch_bounds__(256) void k_gemm2(const unsigned short* __restrict__ a_in,
                                               const unsigned short* __restrict__ w2T,
                                               unsigned char* __restrict__ h2) {
    __shared__ unsigned short As[128][LDA];
    const int t = threadIdx.x;
    const int rb = blockIdx.x * 128;
    {
        int row = t >> 1, half = t & 1;
        int grow = rb + row;
        if (grow < N_NODES) {
#pragma unroll
            for (int i = 0; i < 8; i++)
                *(bf16x8*)&As[row][half * 64 + i * 8] =
                    *(const bf16x8*)&a_in[(size_t)grow * 128 + half * 64 + i * 8];
        } else {
            bf16x8 z = (bf16x8){0, 0, 0, 0, 0, 0, 0, 0};
#pragma unroll
            for (int i = 0; i < 8; i++) *(bf16x8*)&As[row][half * 64 + i * 8] = z;
        }
    }
    __syncthreads();
    const int wid = t >> 6, lane = t & 63;
    const int wr = wid >> 1, wc = wid & 1;
    const int mr = wr * 64, nc = wc * 32;
    const int lrow = lane & 15, lk = (lane >> 4) * 8;
    f32x4 acc[4][2];
#pragma unroll
    for (int m = 0; m < 4; m++)
#pragma unroll
        for (int n = 0; n < 2; n++) acc[m][n] = (f32x4){0.f, 0.f, 0.f, 0.f};

#pragma unroll
    for (int ki = 0; ki < 4; ki++) {
        const int k0 = ki * 32;
        bf16x8 a[4];
#pragma unroll
        for (int m = 0; m < 4; m++)
            a[m] = *(const bf16x8*)&As[mr + m * 16 + lrow][k0 + lk];
#pragma unroll
        for (int n = 0; n < 2; n++) {
            bf16x8 b = *(const bf16x8*)&w2T[(size_t)(nc + n * 16 + lrow) * 128 + k0 + lk];
#pragma unroll
            for (int m = 0; m < 4; m++)
                acc[m][n] = __builtin_amdgcn_mfma_f32_16x16x32_bf16(a[m], b, acc[m][n], 0, 0, 0);
        }
    }
    const int crow0 = (lane >> 4) * 4;
#pragma unroll
    for (int m = 0; m < 4; m++) {
#pragma unroll
        for (int j = 0; j < 4; j++) {
            int grow = rb + mr + m * 16 + crow0 + j;
            if (grow >= N_NODES) continue;
#pragma unroll
            for (int n = 0; n < 2; n++) {
                int col = nc + n * 16 + lrow;
                h2[(size_t)grow * 64 + col] = f2fp8(acc[m][n][j]);
            }
        }
    }
}

// ---- aggregate 1: out1 = leaky(sum_e norm*h1[src] + dinv^2*h1[i] + b1), 128 feats, fp8 h1 ----
// wave = 1 node; 8 groups x 8 lanes; lane covers 16 feats; packed f32x2 FMA (v_pk_fma_f32)
__global__ __launch_bounds__(256) void k_agg1(const unsigned char* __restrict__ h1,
                                              const uint2* __restrict__ csr,
                                              const int* __restrict__ rowptr,
                                              const float* __restrict__ dinv,
                                              const float* __restrict__ b1,
                                              unsigned short* __restrict__ out1) {
    int node = blockIdx.x * 4 + (threadIdx.x >> 6);
    if (node >= N_NODES) return;
    const int lane = threadIdx.x & 63;
    const int g = lane >> 3;   // edge slot 0..7
    const int l = lane & 7;    // feature chunk: [l*16, l*16+16)
    const float di = dinv[node];
    f32x2 a2[8];
#pragma unroll
    for (int i = 0; i < 8; i++) a2[i] = (f32x2){0.f, 0.f};
    const int beg = rowptr[node], end = rowptr[node + 1];
    uint2 ce = csr[beg + g];                 // csr padded with 16 zeroed entries
    for (int e0 = beg; e0 < end; e0 += 8) {
        uint2 ce_n = csr[e0 + 8 + g];        // prefetch next iteration's entry
        int e = e0 + g;
        if (e < end) {
            float w = __uint_as_float(ce.y) * di;
            f32x2 w2 = (f32x2){w, w};
            uint4 h = *(const uint4*)&h1[(size_t)ce.x * 128 + l * 16];
            a2[0] = __builtin_elementwise_fma(w2, __builtin_amdgcn_cvt_pk_f32_fp8(h.x, false), a2[0]);
            a2[1] = __builtin_elementwise_fma(w2, __builtin_amdgcn_cvt_pk_f32_fp8(h.x, true),  a2[1]);
            a2[2] = __builtin_elementwise_fma(w2, __builtin_amdgcn_cvt_pk_f32_fp8(h.y, false), a2[2]);
            a2[3] = __builtin_elementwise_fma(w2, __builtin_amdgcn_cvt_pk_f32_fp8(h.y, true),  a2[3]);
            a2[4] = __builtin_elementwise_fma(w2, __builtin_amdgcn_cvt_pk_f32_fp8(h.z, false), a2[4]);
            a2[5] = __builtin_elementwise_fma(w2, __builtin_amdgcn_cvt_pk_f32_fp8(h.z, true),  a2[5]);
            a2[6] = __builtin_elementwise_fma(w2, __builtin_amdgcn_cvt_pk_f32_fp8(h.w, false), a2[6]);
            a2[7] = __builtin_elementwise_fma(w2, __builtin_amdgcn_cvt_pk_f32_fp8(h.w, true),  a2[7]);
        }
        ce = ce_n;
    }
    float a[16];
#pragma unroll
    for (int i = 0; i < 8; i++) { a[2 * i] = a2[i].x; a[2 * i + 1] = a2[i].y; }
#pragma unroll
    for (int i = 0; i < 16; i++) {
        a[i] += __shfl_xor(a[i], 8);
        a[i] += __shfl_xor(a[i], 16);
        a[i] += __shfl_xor(a[i], 32);
    }
    if (g == 0) {
        float di2 = di * di;
        uint4 hs = *(const uint4*)&h1[(size_t)node * 128 + l * 16];
        f32x2 s0 = __builtin_amdgcn_cvt_pk_f32_fp8(hs.x, false);
        f32x2 s1 = __builtin_amdgcn_cvt_pk_f32_fp8(hs.x, true);
        f32x2 s2 = __builtin_amdgcn_cvt_pk_f32_fp8(hs.y, false);
        f32x2 s3 = __builtin_amdgcn_cvt_pk_f32_fp8(hs.y, true);
        f32x2 s4 = __builtin_amdgcn_cvt_pk_f32_fp8(hs.z, false);
        f32x2 s5 = __builtin_amdgcn_cvt_pk_f32_fp8(hs.z, true);
        f32x2 s6 = __builtin_amdgcn_cvt_pk_f32_fp8(hs.w, false);
        f32x2 s7 = __builtin_amdgcn_cvt_pk_f32_fp8(hs.w, true);
        a[0]  = fmaf(di2, s0.x, a[0]);  a[1]  = fmaf(di2, s0.y, a[1]);
        a[2]  = fmaf(di2, s1.x, a[2]);  a[3]  = fmaf(di2, s1.y, a[3]);
        a[4]  = fmaf(di2, s2.x, a[4]);  a[5]  = fmaf(di2, s2.y, a[5]);
        a[6]  = fmaf(di2, s3.x, a[6]);  a[7]  = fmaf(di2, s3.y, a[7]);
        a[8]  = fmaf(di2, s4.x, a[8]);  a[9]  = fmaf(di2, s4.y, a[9]);
        a[10] = fmaf(di2, s5.x, a[10]); a[11] = fmaf(di2, s5.y, a[11]);
        a[12] = fmaf(di2, s6.x, a[12]); a[13] = fmaf(di2, s6.y, a[13]);
        a[14] = fmaf(di2, s7.x, a[14]); a[15] = fmaf(di2, s7.y, a[15]);
        const float* bp = &b1[l * 16];
        float4 b0 = *(const float4*)&bp[0];
        float4 b4 = *(const float4*)&bp[4];
        float4 b8 = *(const float4*)&bp[8];
        float4 bc = *(const float4*)&bp[12];
        float v0  = lrelu(a[0]  + b0.x), v1  = lrelu(a[1]  + b0.y);
        float v2  = lrelu(a[2]  + b0.z), v3  = lrelu(a[3]  + b0.w);
        float v4  = lrelu(a[4]  + b4.x), v5  = lrelu(a[5]  + b4.y);
        float v6  = lrelu(a[6]  + b4.z), v7  = lrelu(a[7]  + b4.w);
        float v8  = lrelu(a[8]  + b8.x), v9  = lrelu(a[9]  + b8.y);
        float v10 = lrelu(a[10] + b8.z), v11 = lrelu(a[11] + b8.w);
        float v12 = lrelu(a[12] + bc.x), v13 = lrelu(a[13] + bc.y);
        float v14 = lrelu(a[14] + bc.z), v15 = lrelu(a[15] + bc.w);
        uint4 o0, o1;
        o0.x = (unsigned)f2b(v0)  | ((unsigned)f2b(v1)  << 16);
        o0.y = (unsigned)f2b(v2)  | ((unsigned)f2b(v3)  << 16);
        o0.z = (unsigned)f2b(v4)  | ((unsigned)f2b(v5)  << 16);
        o0.w = (unsigned)f2b(v6)  | ((unsigned)f2b(v7)  << 16);
        o1.x = (unsigned)f2b(v8)  | ((unsigned)f2b(v9)  << 16);
        o1.y = (unsigned)f2b(v10) | ((unsigned)f2b(v11) << 16);
        o1.z = (unsigned)f2b(v12) | ((unsigned)f2b(v13) << 16);
        o1.w = (unsigned)f2b(v14) | ((unsigned)f2b(v15) << 16);
        *(uint4*)&out1[(size_t)node * 128 + l * 16]     = o0;
        *(uint4*)&out1[(size_t)node * 128 + l * 16 + 8] = o1;
    }
}

// ---- aggregate 2 + epilogue: out = leaky(agg(h2) + b2) + identity, 64 feats, fp8 h2 ----
// wave = 1 node; 8 groups x 8 lanes; lane covers 8 feats; packed f32x2 FMA
__global__ __launch_bounds__(256) void k_agg2(const unsigned char* __restrict__ h2,
                                              const uint2* __restrict__ csr,
                                              const int* __restrict__ rowptr,
                                              const float* __restrict__ dinv,
                                              const float* __restrict__ b2,
                                              const float* __restrict__ identity,
                                              float* __restrict__ out) {
    int node = blockIdx.x * 4 + (threadIdx.x >> 6);
    if (node >= N_NODES) return;
    const int lane = threadIdx.x & 63;
    const int g = lane >> 3;
    const int l = lane & 7;    // feature chunk: [l*8, l*8+8)
    const float di = dinv[node];
    f32x2 a2[4];
#pragma unroll
    for (int i = 0; i < 4; i++) a2[i] = (f32x2){0.f, 0.f};
    const int beg = rowptr[node], end = rowptr[node + 1];
    uint2 ce = csr[beg + g];
    for (int e0 = beg; e0 < end; e0 += 8) {
        uint2 ce_n = csr[e0 + 8 + g];
        int e = e0 + g;
        if (e < end) {
            float w = __uint_as_float(ce.y) * di;
            f32x2 w2 = (f32x2){w, w};
            uint2 h = *(const uint2*)&h2[(size_t)ce.x * 64 + l * 8];
            a2[0] = __builtin_elementwise_fma(w2, __builtin_amdgcn_cvt_pk_f32_fp8(h.x, false), a2[0]);
            a2[1] = __builtin_elementwise_fma(w2, __builtin_amdgcn_cvt_pk_f32_fp8(h.x, true),  a2[1]);
            a2[2] = __builtin_elementwise_fma(w2, __builtin_amdgcn_cvt_pk_f32_fp8(h.y, false), a2[2]);
            a2[3] = __builtin_elementwise_fma(w2, __builtin_amdgcn_cvt_pk_f32_fp8(h.y, true),  a2[3]);
        }
        ce = ce_n;
    }
    float a[8];
#pragma unroll
    for (int i = 0; i < 4; i++) { a[2 * i] = a2[i].x; a[2 * i + 1] = a2[i].y; }
#pragma unroll
    for (int i = 0; i < 8; i++) {
        a[i] += __shfl_xor(a[i], 8);
        a[i] += __shfl_xor(a[i], 16);
        a[i] += __shfl_xor(a[i], 32);
    }
    if (g == 0) {
        float di2 = di * di;
        uint2 hs = *(const uint2*)&h2[(size_t)node * 64 + l * 8];
        f32x2 s0 = __builtin_amdgcn_cvt_pk_f32_fp8(hs.x, false);
        f32x2 s1 = __builtin_amdgcn_cvt_pk_f32_fp8(hs.x, true);
        f32x2 s2 = __builtin_amdgcn_cvt_pk_f32_fp8(hs.y, false);
        f32x2 s3 = __builtin_amdgcn_cvt_pk_f32_fp8(hs.y, true);
        a[0] = fmaf(di2, s0.x, a[0]); a[1] = fmaf(di2, s0.y, a[1]);
        a[2] = fmaf(di2, s1.x, a[2]); a[3] = fmaf(di2, s1.y, a[3]);
        a[4] = fmaf(di2, s2.x, a[4]); a[5] = fmaf(di2, s2.y, a[5]);
        a[6] = fmaf(di2, s3.x, a[6]); a[7] = fmaf(di2, s3.y, a[7]);
        const float* bp = &b2[l * 8];
        float4 bb0 = *(const float4*)&bp[0];
        float4 bb4 = *(const float4*)&bp[4];
        const float* ip = &identity[(size_t)node * 64 + l * 8];
        float4 id0 = *(const float4*)&ip[0];
        float4 id4 = *(const float4*)&ip[4];
        float4 o0, o1;
        o0.x = lrelu(a[0] + bb0.x) + id0.x;
        o0.y = lrelu(a[1] + bb0.y) + id0.y;
        o0.z = lrelu(a[2] + bb0.z) + id0.z;
        o0.w = lrelu(a[3] + bb0.w) + id0.w;
        o1.x = lrelu(a[4] + bb4.x) + id4.x;
        o1.y = lrelu(a[5] + bb4.y) + id4.y;
        o1.z = lrelu(a[6] + bb4.z) + id4.z;
        o1.w = lrelu(a[7] + bb4.w) + id4.w;
        float* op = &out[(size_t)node * 64 + l * 8];
        *(float4*)&op[0] = o0;
        *(float4*)&op[4] = o1;
    }
}

extern "C" void kernel_launch(void* const* d_in, const int* in_sizes, int n_in,
                              void* d_out, int out_size, void* d_ws, size_t ws_size,
                              hipStream_t stream) {
    const float* x  = (const float*)d_in[0];
    const int* eidx = (const int*)d_in[1];
    const float* w1 = (const float*)d_in[2];
    const float* b1 = (const float*)d_in[3];
    const float* w2 = (const float*)d_in[4];
    const float* b2 = (const float*)d_in[5];
    const float* wd = (const float*)d_in[6];
    const float* bd = (const float*)d_in[7];
    const int* src = eidx;
    const int* dst = eidx + N_EDGES;
    float* out = (float*)d_out;

    char* ws = (char*)d_ws;
    size_t off = 0;
    auto take = [&](size_t bytes) -> char* {
        char* p = ws + off;
        off = (off + bytes + 255) & ~(size_t)255;
        return p;
    };
    int* cnt        = (int*)take((size_t)N_NODES * 4);
    int* rowptr     = (int*)take((size_t)(N_NODES + 1) * 4);
    int* bcur       = (int*)take((size_t)NBKT * 4);
    float* dinv     = (float*)take((size_t)N_NODES * 4);
    int* bsum       = (int*)take(256 * 4);
    int* tops       = (int*)take(256 * 4);
    uint2* csr      = (uint2*)take((size_t)(N_EDGES + 16) * 8);  // +16 zeroed pad entries
    unsigned char* h1   = (unsigned char*)take((size_t)N_NODES * 128);
    unsigned short* out1 = (unsigned short*)take((size_t)N_NODES * 128 * 2);
    unsigned char* h2   = (unsigned char*)take((size_t)N_NODES * 64);
    float* identity = (float*)take((size_t)N_NODES * 64 * 4);
    unsigned short* wT   = (unsigned short*)take((size_t)192 * 128 * 2);
    unsigned short* w2T  = (unsigned short*)take((size_t)64 * 128 * 2);

    hipMemsetAsync(cnt, 0, (size_t)N_NODES * 4, stream);
    hipMemsetAsync(csr + N_EDGES, 0, 16 * sizeof(uint2), stream);

    k_hist<<<(N_EDGES + 255) / 256, 256, 0, stream>>>(dst, cnt);
    k_prep<<<(192 * 128 + 255) / 256, 256, 0, stream>>>(w1, wd, w2, wT, w2T);
    k_dinv<<<(N_NODES + 255) / 256, 256, 0, stream>>>(cnt, dinv);
    k_scan1<<<NB1, 256, 0, stream>>>(cnt, rowptr, bsum);
    k_scan2<<<1, 256, 0, stream>>>(bsum, tops);
    k_scan3<<<(N_NODES + 255) / 256, 256, 0, stream>>>(rowptr, tops);
    k_binit<<<(NBKT + 255) / 256, 256, 0, stream>>>(rowptr, bcur);
    k_fillA<<<NBA, 256, 0, stream>>>(src, dst, bcur, csr);
    k_fillB<<<NBKT, 256, 0, stream>>>(dinv, rowptr, csr);
    k_gemm1<<<(N_NODES + 127) / 128, 256, 0, stream>>>(x, wT, bd, h1, identity);
    k_agg1<<<(N_NODES + 3) / 4, 256, 0, stream>>>(h1, csr, rowptr, dinv, b1, out1);
    k_gemm2<<<(N_NODES + 127) / 128, 256, 0, stream>>>(out1, w2T, h2);
    k_agg2<<<(N_NODES + 3) / 4, 256, 0, stream>>>(h2, csr, rowptr, dinv, b2, identity, out);
}

// Round 13
// 283.516 us; speedup vs baseline: 1.7636x; 1.0314x over previous
//
#include <hip/hip_runtime.h>
#include <hip/hip_bf16.h>

#define N_NODES 100000
#define N_EDGES 1600000
#define NFEAT 128
#define NHID 128
#define NOUT 64
#define NEG_SLOPE 0.01f
#define NB1 98   // ceil(100000/1024)
#define LDA 136  // 128 + 8 pad (bf16) — row stride 272B, keeps 16B alignment for b128 LDS ops
#define BKT_SHIFT 8
#define NBKT 391          // ceil(100000/256) buckets of 256 nodes
#define EPB_A 4096        // edges per block in fillA
#define NBA 391           // ceil(1600000/4096)
#define MAXB 6144         // LDS entry cap per bucket

typedef short bf16x8 __attribute__((ext_vector_type(8)));
typedef float f32x4 __attribute__((ext_vector_type(4)));
typedef float f32x2 __attribute__((ext_vector_type(2)));

__device__ __forceinline__ unsigned short f2b(float f) {
    unsigned u = __float_as_uint(f);
    unsigned r = u + 0x7FFFu + ((u >> 16) & 1u);
    return (unsigned short)(r >> 16);
}
__device__ __forceinline__ float b2f(unsigned short h) {
    return __uint_as_float(((unsigned)h) << 16);
}
__device__ __forceinline__ float lrelu(float v) {
    return v > 0.f ? v : v * NEG_SLOPE;
}
// OCP e4m3 via gfx950 HW converts
__device__ __forceinline__ unsigned char f2fp8(float f) {
    return (unsigned char)(__builtin_amdgcn_cvt_pk_fp8_f32(f, f, 0, false) & 0xFF);
}

// ---- degree histogram over dst ----
__global__ void k_hist(const int* __restrict__ dst, int* __restrict__ cnt) {
    int e = blockIdx.x * 256 + threadIdx.x;
    if (e < N_EDGES) atomicAdd(&cnt[dst[e]], 1);
}

// ---- dinv = rsqrt(deg), deg = cnt + 1 (self loop) ----
__global__ void k_dinv(const int* __restrict__ cnt, float* __restrict__ dinv) {
    int i = blockIdx.x * 256 + threadIdx.x;
    if (i < N_NODES) dinv[i] = rsqrtf((float)(cnt[i] + 1));
}

// ---- transposed bf16 weights: wT[192][128] = [w1 | wd]^T, w2T[64][128] ----
__global__ void k_prep(const float* __restrict__ w1, const float* __restrict__ wd,
                       const float* __restrict__ w2,
                       unsigned short* __restrict__ wT, unsigned short* __restrict__ w2T) {
    int i = blockIdx.x * 256 + threadIdx.x;
    if (i < 192 * 128) {
        int n = i >> 7, k = i & 127;
        float v = (n < 128) ? w1[k * 128 + n] : wd[k * 64 + (n - 128)];
        wT[i] = f2b(v);
    }
    if (i < 64 * 128) {
        int n = i >> 7, k = i & 127;
        w2T[i] = f2b(w2[k * 64 + n]);
    }
}

// ---- scan stage 1 ----
__global__ __launch_bounds__(256) void k_scan1(const int* __restrict__ cnt,
                                               int* __restrict__ rowptr,
                                               int* __restrict__ bsum) {
    __shared__ int sc[256];
    int t = threadIdx.x;
    int base = blockIdx.x * 1024 + t * 4;
    int v0 = (base + 0 < N_NODES) ? cnt[base + 0] : 0;
    int v1 = (base + 1 < N_NODES) ? cnt[base + 1] : 0;
    int v2 = (base + 2 < N_NODES) ? cnt[base + 2] : 0;
    int v3 = (base + 3 < N_NODES) ? cnt[base + 3] : 0;
    int s = v0 + v1 + v2 + v3;
    sc[t] = s;
    __syncthreads();
    for (int off = 1; off < 256; off <<= 1) {
        int xv = (t >= off) ? sc[t - off] : 0;
        __syncthreads();
        sc[t] += xv;
        __syncthreads();
    }
    int run = sc[t] - s;
    if (base + 0 < N_NODES) { rowptr[base + 0] = run; run += v0; }
    if (base + 1 < N_NODES) { rowptr[base + 1] = run; run += v1; }
    if (base + 2 < N_NODES) { rowptr[base + 2] = run; run += v2; }
    if (base + 3 < N_NODES) { rowptr[base + 3] = run; run += v3; }
    if (t == 0) bsum[blockIdx.x] = sc[255];
}

// ---- scan stage 2 ----
__global__ __launch_bounds__(256) void k_scan2(const int* __restrict__ bsum,
                                               int* __restrict__ tops) {
    __shared__ int sc[256];
    int t = threadIdx.x;
    int s = (t < NB1) ? bsum[t] : 0;
    sc[t] = s;
    __syncthreads();
    for (int off = 1; off < 256; off <<= 1) {
        int xv = (t >= off) ? sc[t - off] : 0;
        __syncthreads();
        sc[t] += xv;
        __syncthreads();
    }
    tops[t] = sc[t] - s;
}

// ---- scan stage 3 ----
__global__ void k_scan3(int* __restrict__ rowptr, const int* __restrict__ tops) {
    int i = blockIdx.x * 256 + threadIdx.x;
    if (i < N_NODES) rowptr[i] += tops[i >> 10];
    if (i == 0) rowptr[N_NODES] = N_EDGES;
}

// ---- bucket cursor init ----
__global__ void k_binit(const int* __restrict__ rowptr, int* __restrict__ bcur) {
    int i = blockIdx.x * 256 + threadIdx.x;
    if (i < NBKT) bcur[i] = rowptr[i << BKT_SHIFT];
}

// ---- fillA: coarse bucket scatter ----
__global__ __launch_bounds__(256) void k_fillA(const int* __restrict__ src,
                                               const int* __restrict__ dst,
                                               int* __restrict__ bcur,
                                               uint2* __restrict__ csr) {
    __shared__ int lcnt[NBKT];
    __shared__ int lbase[NBKT];
    const int t = threadIdx.x;
    const int e0 = blockIdx.x * EPB_A;
    const int nd = min(EPB_A, N_EDGES - e0);
    for (int i = t; i < NBKT; i += 256) lcnt[i] = 0;
    __syncthreads();
    for (int i = t; i < nd; i += 256) {
        int d = dst[e0 + i];
        atomicAdd(&lcnt[d >> BKT_SHIFT], 1);
    }
    __syncthreads();
    for (int i = t; i < NBKT; i += 256)
        lbase[i] = lcnt[i] ? atomicAdd(&bcur[i], lcnt[i]) : 0;
    __syncthreads();
    for (int i = t; i < NBKT; i += 256) lcnt[i] = 0;
    __syncthreads();
    for (int i = t; i < nd; i += 256) {
        int s = src[e0 + i];
        int d = dst[e0 + i];
        int b = d >> BKT_SHIFT;
        int off = atomicAdd(&lcnt[b], 1);
        csr[lbase[b] + off] = make_uint2((unsigned)s, (unsigned)d);
    }
}

// ---- fillB: in-place fine permutation within each bucket ----
__global__ __launch_bounds__(256) void k_fillB(const float* __restrict__ dinv,
                                               const int* __restrict__ rowptr,
                                               uint2* __restrict__ csr) {
    __shared__ uint2 lbuf[MAXB];
    __shared__ int lcur[256];
    __shared__ int lrp[256];
    const int t = threadIdx.x;
    const int b = blockIdx.x;
    const int n0 = b << BKT_SHIFT;
    const int n1 = min(n0 + 256, N_NODES);
    const int R0 = rowptr[n0], R1 = rowptr[n1];
    const int cnt = R1 - R0;
    for (int i = t; i < cnt; i += 256) lbuf[i] = csr[R0 + i];
    if (n0 + t < n1) lrp[t] = rowptr[n0 + t];
    lcur[t] = 0;
    __syncthreads();
    for (int i = t; i < cnt; i += 256) {
        uint2 e = lbuf[i];
        int li = (int)e.y & 255;
        int r = atomicAdd(&lcur[li], 1);
        int p = lrp[li] + r;
        csr[p] = make_uint2(e.x, __float_as_uint(dinv[e.x]));
    }
}

// ---- MFMA GEMM1: h1 = fp8(x@w1), identity = x@wd + bd ----
__global__ __launch_bounds__(256) void k_gemm1(const float* __restrict__ x,
                                               const unsigned short* __restrict__ wT,
                                               const float* __restrict__ bd,
                                               unsigned char* __restrict__ h1,
                                               float* __restrict__ identity) {
    __shared__ unsigned short As[128][LDA];
    const int t = threadIdx.x;
    const int rb = blockIdx.x * 128;
    {
        int row = t >> 1, half = t & 1;
        int grow = rb + row;
        if (grow < N_NODES) {
            const float* srcp = &x[(size_t)grow * 128 + half * 64];
#pragma unroll
            for (int i = 0; i < 8; i++) {
                float4 va = *(const float4*)&srcp[i * 8];
                float4 vb = *(const float4*)&srcp[i * 8 + 4];
                unsigned short u[8];
                u[0] = f2b(va.x); u[1] = f2b(va.y); u[2] = f2b(va.z); u[3] = f2b(va.w);
                u[4] = f2b(vb.x); u[5] = f2b(vb.y); u[6] = f2b(vb.z); u[7] = f2b(vb.w);
                *(bf16x8*)&As[row][half * 64 + i * 8] = *(bf16x8*)u;
            }
        } else {
            bf16x8 z = (bf16x8){0, 0, 0, 0, 0, 0, 0, 0};
#pragma unroll
            for (int i = 0; i < 8; i++) *(bf16x8*)&As[row][half * 64 + i * 8] = z;
        }
    }
    __syncthreads();
    const int wid = t >> 6, lane = t & 63;
    const int wr = wid >> 1, wc = wid & 1;
    const int mr = wr * 64, nc = wc * 96;
    const int lrow = lane & 15, lk = (lane >> 4) * 8;
    f32x4 acc[4][6];
#pragma unroll
    for (int m = 0; m < 4; m++)
#pragma unroll
        for (int n = 0; n < 6; n++) acc[m][n] = (f32x4){0.f, 0.f, 0.f, 0.f};

#pragma unroll
    for (int ki = 0; ki < 4; ki++) {
        const int k0 = ki * 32;
        bf16x8 a[4];
#pragma unroll
        for (int m = 0; m < 4; m++)
            a[m] = *(const bf16x8*)&As[mr + m * 16 + lrow][k0 + lk];
#pragma unroll
        for (int n = 0; n < 6; n++) {
            bf16x8 b = *(const bf16x8*)&wT[(size_t)(nc + n * 16 + lrow) * 128 + k0 + lk];
#pragma unroll
            for (int m = 0; m < 4; m++)
                acc[m][n] = __builtin_amdgcn_mfma_f32_16x16x32_bf16(a[m], b, acc[m][n], 0, 0, 0);
        }
    }
    const int crow0 = (lane >> 4) * 4;
#pragma unroll
    for (int m = 0; m < 4; m++) {
#pragma unroll
        for (int j = 0; j < 4; j++) {
            int grow = rb + mr + m * 16 + crow0 + j;
            if (grow >= N_NODES) continue;
#pragma unroll
            for (int n = 0; n < 6; n++) {
                int col = nc + n * 16 + lrow;
                float v = acc[m][n][j];
                if (col < 128) h1[(size_t)grow * 128 + col] = f2fp8(v);
                else           identity[(size_t)grow * 64 + (col - 128)] = v + bd[col - 128];
            }
        }
    }
}

// ---- MFMA GEMM2: h2 = fp8(out1 @ w2), tile 128 x 64 ----
__global__ __launch_bounds__(256) void k_gemm2(const unsigned short* __restrict__ a_in,
                                               const unsigned short* __restrict__ w2T,
                                               unsigned char* __restrict__ h2) {
    __shared__ unsigned short As[128][LDA];
    const int t = threadIdx.x;
    const int rb = blockIdx.x * 128;
    {
        int row = t >> 1, half = t & 1;
        int grow = rb + row;
        if (grow < N_NODES) {
#pragma unroll
            for (int i = 0; i < 8; i++)
                *(bf16x8*)&As[row][half * 64 + i * 8] =
                    *(const bf16x8*)&a_in[(size_t)grow * 128 + half * 64 + i * 8];
        } else {
            bf16x8 z = (bf16x8){0, 0, 0, 0, 0, 0, 0, 0};
#pragma unroll
            for (int i = 0; i < 8; i++) *(bf16x8*)&As[row][half * 64 + i * 8] = z;
        }
    }
    __syncthreads();
    const int wid = t >> 6, lane = t & 63;
    const int wr = wid >> 1, wc = wid & 1;
    const int mr = wr * 64, nc = wc * 32;
    const int lrow = lane & 15, lk = (lane >> 4) * 8;
    f32x4 acc[4][2];
#pragma unroll
    for (int m = 0; m < 4; m++)
#pragma unroll
        for (int n = 0; n < 2; n++) acc[m][n] = (f32x4){0.f, 0.f, 0.f, 0.f};

#pragma unroll
    for (int ki = 0; ki < 4; ki++) {
        const int k0 = ki * 32;
        bf16x8 a[4];
#pragma unroll
        for (int m = 0; m < 4; m++)
            a[m] = *(const bf16x8*)&As[mr + m * 16 + lrow][k0 + lk];
#pragma unroll
        for (int n = 0; n < 2; n++) {
            bf16x8 b = *(const bf16x8*)&w2T[(size_t)(nc + n * 16 + lrow) * 128 + k0 + lk];
#pragma unroll
            for (int m = 0; m < 4; m++)
                acc[m][n] = __builtin_amdgcn_mfma_f32_16x16x32_bf16(a[m], b, acc[m][n], 0, 0, 0);
        }
    }
    const int crow0 = (lane >> 4) * 4;
#pragma unroll
    for (int m = 0; m < 4; m++) {
#pragma unroll
        for (int j = 0; j < 4; j++) {
            int grow = rb + mr + m * 16 + crow0 + j;
            if (grow >= N_NODES) continue;
#pragma unroll
            for (int n = 0; n < 2; n++) {
                int col = nc + n * 16 + lrow;
                h2[(size_t)grow * 64 + col] = f2fp8(acc[m][n][j]);
            }
        }
    }
}

// ---- aggregate 1: out1 = leaky(di*(sum_e dinv_s*h1[src] + di*h1[i]) + b1) ----
// wave = 1 node; 8 groups x 8 lanes; lane covers 16 feats in loop.
// Epilogue DISTRIBUTED: after butterfly all-reduce, lane (g,l) writes feats
// f0 = l*16 + 2g, f0+1 using its replicated a2[g] — full 64-lane utilization.
__global__ __launch_bounds__(256) void k_agg1(const unsigned char* __restrict__ h1,
                                              const uint2* __restrict__ csr,
                                              const int* __restrict__ rowptr,
                                              const float* __restrict__ dinv,
                                              const float* __restrict__ b1,
                                              unsigned short* __restrict__ out1) {
    int node = blockIdx.x * 4 + (threadIdx.x >> 6);
    if (node >= N_NODES) return;
    const int lane = threadIdx.x & 63;
    const int g = lane >> 3;   // edge slot 0..7
    const int l = lane & 7;    // feature chunk: [l*16, l*16+16)
    const float di = dinv[node];
    f32x2 a2[8];
#pragma unroll
    for (int i = 0; i < 8; i++) a2[i] = (f32x2){0.f, 0.f};
    const int beg = rowptr[node], end = rowptr[node + 1];
    uint2 ce = csr[beg + g];                 // csr padded with 16 zeroed entries
    for (int e0 = beg; e0 < end; e0 += 8) {
        uint2 ce_n = csr[e0 + 8 + g];        // prefetch next iteration's entry
        int e = e0 + g;
        if (e < end) {
            float w = __uint_as_float(ce.y);  // dinv[src]; di folded into epilogue
            f32x2 w2 = (f32x2){w, w};
            uint4 h = *(const uint4*)&h1[(size_t)ce.x * 128 + l * 16];
            a2[0] = __builtin_elementwise_fma(w2, __builtin_amdgcn_cvt_pk_f32_fp8(h.x, false), a2[0]);
            a2[1] = __builtin_elementwise_fma(w2, __builtin_amdgcn_cvt_pk_f32_fp8(h.x, true),  a2[1]);
            a2[2] = __builtin_elementwise_fma(w2, __builtin_amdgcn_cvt_pk_f32_fp8(h.y, false), a2[2]);
            a2[3] = __builtin_elementwise_fma(w2, __builtin_amdgcn_cvt_pk_f32_fp8(h.y, true),  a2[3]);
            a2[4] = __builtin_elementwise_fma(w2, __builtin_amdgcn_cvt_pk_f32_fp8(h.z, false), a2[4]);
            a2[5] = __builtin_elementwise_fma(w2, __builtin_amdgcn_cvt_pk_f32_fp8(h.z, true),  a2[5]);
            a2[6] = __builtin_elementwise_fma(w2, __builtin_amdgcn_cvt_pk_f32_fp8(h.w, false), a2[6]);
            a2[7] = __builtin_elementwise_fma(w2, __builtin_amdgcn_cvt_pk_f32_fp8(h.w, true),  a2[7]);
        }
        ce = ce_n;
    }
    // butterfly all-reduce across the 8 groups (results replicated on all lanes)
#pragma unroll
    for (int i = 0; i < 8; i++) {
        a2[i].x += __shfl_xor(a2[i].x, 8);
        a2[i].y += __shfl_xor(a2[i].y, 8);
        a2[i].x += __shfl_xor(a2[i].x, 16);
        a2[i].y += __shfl_xor(a2[i].y, 16);
        a2[i].x += __shfl_xor(a2[i].x, 32);
        a2[i].y += __shfl_xor(a2[i].y, 32);
    }
    // distributed epilogue: this lane owns feats f0, f0+1 with values a2[g]
    {
        const int f0 = l * 16 + g * 2;
        unsigned hs = (unsigned)*(const unsigned short*)&h1[(size_t)node * 128 + f0];
        f32x2 sv = __builtin_amdgcn_cvt_pk_f32_fp8(hs, false);
        float2 bb = *(const float2*)&b1[f0];
        float t0 = a2[g].x + di * sv.x;
        float t1 = a2[g].y + di * sv.y;
        float o0 = lrelu(fmaf(t0, di, bb.x));
        float o1 = lrelu(fmaf(t1, di, bb.y));
        unsigned ov = (unsigned)f2b(o0) | ((unsigned)f2b(o1) << 16);
        *(unsigned*)&out1[(size_t)node * 128 + f0] = ov;
    }
}

// ---- aggregate 2 + epilogue: out = leaky(di*(agg + di*h_self) + b2) + identity ----
// wave = 1 node; 8 groups x 8 lanes; distributed epilogue: lane (g,l) writes feat l*8+g
__global__ __launch_bounds__(256) void k_agg2(const unsigned char* __restrict__ h2,
                                              const uint2* __restrict__ csr,
                                              const int* __restrict__ rowptr,
                                              const float* __restrict__ dinv,
                                              const float* __restrict__ b2,
                                              const float* __restrict__ identity,
                                              float* __restrict__ out) {
    int node = blockIdx.x * 4 + (threadIdx.x >> 6);
    if (node >= N_NODES) return;
    const int lane = threadIdx.x & 63;
    const int g = lane >> 3;
    const int l = lane & 7;    // feature chunk: [l*8, l*8+8)
    const float di = dinv[node];
    f32x2 a2[4];
#pragma unroll
    for (int i = 0; i < 4; i++) a2[i] = (f32x2){0.f, 0.f};
    const int beg = rowptr[node], end = rowptr[node + 1];
    uint2 ce = csr[beg + g];
    for (int e0 = beg; e0 < end; e0 += 8) {
        uint2 ce_n = csr[e0 + 8 + g];
        int e = e0 + g;
        if (e < end) {
            float w = __uint_as_float(ce.y);  // dinv[src]
            f32x2 w2 = (f32x2){w, w};
            uint2 h = *(const uint2*)&h2[(size_t)ce.x * 64 + l * 8];
            a2[0] = __builtin_elementwise_fma(w2, __builtin_amdgcn_cvt_pk_f32_fp8(h.x, false), a2[0]);
            a2[1] = __builtin_elementwise_fma(w2, __builtin_amdgcn_cvt_pk_f32_fp8(h.x, true),  a2[1]);
            a2[2] = __builtin_elementwise_fma(w2, __builtin_amdgcn_cvt_pk_f32_fp8(h.y, false), a2[2]);
            a2[3] = __builtin_elementwise_fma(w2, __builtin_amdgcn_cvt_pk_f32_fp8(h.y, true),  a2[3]);
        }
        ce = ce_n;
    }
    float a[8];
#pragma unroll
    for (int i = 0; i < 4; i++) { a[2 * i] = a2[i].x; a[2 * i + 1] = a2[i].y; }
#pragma unroll
    for (int i = 0; i < 8; i++) {
        a[i] += __shfl_xor(a[i], 8);
        a[i] += __shfl_xor(a[i], 16);
        a[i] += __shfl_xor(a[i], 32);
    }
    // distributed epilogue: this lane owns feat f0 = l*8 + g with value a[g]
    {
        const int f0 = l * 8 + g;
        unsigned c = (unsigned)h2[(size_t)node * 64 + f0];
        f32x2 svv = __builtin_amdgcn_cvt_pk_f32_fp8(c, false);
        float sv = svv.x;
        float t = a[g] + di * sv;
        float o = lrelu(fmaf(t, di, b2[f0])) + identity[(size_t)node * 64 + f0];
        out[(size_t)node * 64 + f0] = o;
    }
}

extern "C" void kernel_launch(void* const* d_in, const int* in_sizes, int n_in,
                              void* d_out, int out_size, void* d_ws, size_t ws_size,
                              hipStream_t stream) {
    const float* x  = (const float*)d_in[0];
    const int* eidx = (const int*)d_in[1];
    const float* w1 = (const float*)d_in[2];
    const float* b1 = (const float*)d_in[3];
    const float* w2 = (const float*)d_in[4];
    const float* b2 = (const float*)d_in[5];
    const float* wd = (const float*)d_in[6];
    const float* bd = (const float*)d_in[7];
    const int* src = eidx;
    const int* dst = eidx + N_EDGES;
    float* out = (float*)d_out;

    char* ws = (char*)d_ws;
    size_t off = 0;
    auto take = [&](size_t bytes) -> char* {
        char* p = ws + off;
        off = (off + bytes + 255) & ~(size_t)255;
        return p;
    };
    int* cnt        = (int*)take((size_t)N_NODES * 4);
    int* rowptr     = (int*)take((size_t)(N_NODES + 1) * 4);
    int* bcur       = (int*)take((size_t)NBKT * 4);
    float* dinv     = (float*)take((size_t)N_NODES * 4);
    int* bsum       = (int*)take(256 * 4);
    int* tops       = (int*)take(256 * 4);
    uint2* csr      = (uint2*)take((size_t)(N_EDGES + 16) * 8);  // +16 zeroed pad entries
    unsigned char* h1   = (unsigned char*)take((size_t)N_NODES * 128);
    unsigned short* out1 = (unsigned short*)take((size_t)N_NODES * 128 * 2);
    unsigned char* h2   = (unsigned char*)take((size_t)N_NODES * 64);
    float* identity = (float*)take((size_t)N_NODES * 64 * 4);
    unsigned short* wT   = (unsigned short*)take((size_t)192 * 128 * 2);
    unsigned short* w2T  = (unsigned short*)take((size_t)64 * 128 * 2);

    hipMemsetAsync(cnt, 0, (size_t)N_NODES * 4, stream);
    hipMemsetAsync(csr + N_EDGES, 0, 16 * sizeof(uint2), stream);

    k_hist<<<(N_EDGES + 255) / 256, 256, 0, stream>>>(dst, cnt);
    k_prep<<<(192 * 128 + 255) / 256, 256, 0, stream>>>(w1, wd, w2, wT, w2T);
    k_dinv<<<(N_NODES + 255) / 256, 256, 0, stream>>>(cnt, dinv);
    k_scan1<<<NB1, 256, 0, stream>>>(cnt, rowptr, bsum);
    k_scan2<<<1, 256, 0, stream>>>(bsum, tops);
    k_scan3<<<(N_NODES + 255) / 256, 256, 0, stream>>>(rowptr, tops);
    k_binit<<<(NBKT + 255) / 256, 256, 0, stream>>>(rowptr, bcur);
    k_fillA<<<NBA, 256, 0, stream>>>(src, dst, bcur, csr);
    k_fillB<<<NBKT, 256, 0, stream>>>(dinv, rowptr, csr);
    k_gemm1<<<(N_NODES + 127) / 128, 256, 0, stream>>>(x, wT, bd, h1, identity);
    k_agg1<<<(N_NODES + 3) / 4, 256, 0, stream>>>(h1, csr, rowptr, dinv, b1, out1);
    k_gemm2<<<(N_NODES + 127) / 128, 256, 0, stream>>>(out1, w2T, h2);
    k_agg2<<<(N_NODES + 3) / 4, 256, 0, stream>>>(h2, csr, rowptr, dinv, b2, identity, out);
}

// Round 14
// 228.001 us; speedup vs baseline: 2.1931x; 1.2435x over previous
//
#include <hip/hip_runtime.h>
#include <hip/hip_bf16.h>

#define N_NODES 100000
#define N_EDGES 1600000
#define NFEAT 128
#define NHID 128
#define NOUT 64
#define NEG_SLOPE 0.01f
#define LDA 136  // 128 + 8 pad (bf16) — row stride 272B, keeps 16B alignment for b128 LDS ops
#define BKT_SHIFT 8
#define NBKT 391          // ceil(100000/256) buckets of 256 nodes
#define EPB_A 4096        // edges per block in fillA/bhist
#define NBA 391           // ceil(1600000/4096)
#define MAXB 6144         // LDS entry cap per bucket

typedef short bf16x8 __attribute__((ext_vector_type(8)));
typedef float f32x4 __attribute__((ext_vector_type(4)));
typedef float f32x2 __attribute__((ext_vector_type(2)));

__device__ __forceinline__ unsigned short f2b(float f) {
    unsigned u = __float_as_uint(f);
    unsigned r = u + 0x7FFFu + ((u >> 16) & 1u);
    return (unsigned short)(r >> 16);
}
__device__ __forceinline__ float b2f(unsigned short h) {
    return __uint_as_float(((unsigned)h) << 16);
}
__device__ __forceinline__ float lrelu(float v) {
    return v > 0.f ? v : v * NEG_SLOPE;
}
// OCP e4m3 via gfx950 HW converts
__device__ __forceinline__ unsigned char f2fp8(float f) {
    return (unsigned char)(__builtin_amdgcn_cvt_pk_fp8_f32(f, f, 0, false) & 0xFF);
}

// ---- transposed bf16 weights: wT[192][128] = [w1 | wd]^T, w2T[64][128] ----
__global__ void k_prep(const float* __restrict__ w1, const float* __restrict__ wd,
                       const float* __restrict__ w2,
                       unsigned short* __restrict__ wT, unsigned short* __restrict__ w2T) {
    int i = blockIdx.x * 256 + threadIdx.x;
    if (i < 192 * 128) {
        int n = i >> 7, k = i & 127;
        float v = (n < 128) ? w1[k * 128 + n] : wd[k * 64 + (n - 128)];
        wT[i] = f2b(v);
    }
    if (i < 64 * 128) {
        int n = i >> 7, k = i & 127;
        w2T[i] = f2b(w2[k * 64 + n]);
    }
}

// ---- bucket-level histogram (391 bins, LDS-aggregated) ----
__global__ __launch_bounds__(256) void k_bhist(const int* __restrict__ dst,
                                               int* __restrict__ bcnt) {
    __shared__ int lcnt[NBKT];
    const int t = threadIdx.x;
    const int e0 = blockIdx.x * EPB_A;
    const int nd = min(EPB_A, N_EDGES - e0);
    for (int i = t; i < NBKT; i += 256) lcnt[i] = 0;
    __syncthreads();
    for (int i = t; i < nd; i += 256) {
        int d = dst[e0 + i];
        atomicAdd(&lcnt[d >> BKT_SHIFT], 1);
    }
    __syncthreads();
    for (int i = t; i < NBKT; i += 256)
        if (lcnt[i]) atomicAdd(&bcnt[i], lcnt[i]);
}

// ---- scan of bucket counts -> bucket bases + cursors (single block) ----
__global__ __launch_bounds__(512) void k_bscan(const int* __restrict__ bcnt,
                                               int* __restrict__ bbase,
                                               int* __restrict__ bcur) {
    __shared__ int sc[512];
    int t = threadIdx.x;
    int v = (t < NBKT) ? bcnt[t] : 0;
    sc[t] = v;
    __syncthreads();
    for (int off = 1; off < 512; off <<= 1) {
        int xv = (t >= off) ? sc[t - off] : 0;
        __syncthreads();
        sc[t] += xv;
        __syncthreads();
    }
    if (t < NBKT) {
        int base = sc[t] - v;
        bbase[t] = base;
        bcur[t] = base;
    }
}

// ---- fillA: coarse bucket scatter of {src, dst} ----
__global__ __launch_bounds__(256) void k_fillA(const int* __restrict__ src,
                                               const int* __restrict__ dst,
                                               int* __restrict__ bcur,
                                               uint2* __restrict__ csr) {
    __shared__ int lcnt[NBKT];
    __shared__ int lbase[NBKT];
    const int t = threadIdx.x;
    const int e0 = blockIdx.x * EPB_A;
    const int nd = min(EPB_A, N_EDGES - e0);
    for (int i = t; i < NBKT; i += 256) lcnt[i] = 0;
    __syncthreads();
    for (int i = t; i < nd; i += 256) {
        int d = dst[e0 + i];
        atomicAdd(&lcnt[d >> BKT_SHIFT], 1);
    }
    __syncthreads();
    for (int i = t; i < NBKT; i += 256)
        lbase[i] = lcnt[i] ? atomicAdd(&bcur[i], lcnt[i]) : 0;
    __syncthreads();
    for (int i = t; i < NBKT; i += 256) lcnt[i] = 0;
    __syncthreads();
    for (int i = t; i < nd; i += 256) {
        int s = src[e0 + i];
        int d = dst[e0 + i];
        int b = d >> BKT_SHIFT;
        int off = atomicAdd(&lcnt[b], 1);
        csr[lbase[b] + off] = make_uint2((unsigned)s, (unsigned)d);
    }
}

// ---- fillB1: per-bucket node counts -> rowptr + dinv (no global atomics) ----
__global__ __launch_bounds__(256) void k_fillB1(const uint2* __restrict__ csr,
                                                const int* __restrict__ bbase,
                                                const int* __restrict__ bcnt,
                                                int* __restrict__ rowptr,
                                                float* __restrict__ dinv) {
    __shared__ int lcnt[256];
    __shared__ int sc[256];
    const int t = threadIdx.x;
    const int b = blockIdx.x;
    const int n0 = b << BKT_SHIFT;
    const int n1 = min(n0 + 256, N_NODES);
    const int R0 = bbase[b];
    const int cntE = bcnt[b];
    lcnt[t] = 0;
    __syncthreads();
    for (int i = t; i < cntE; i += 256) {
        uint2 e = csr[R0 + i];
        atomicAdd(&lcnt[(int)e.y & 255], 1);
    }
    __syncthreads();
    int myc = lcnt[t];
    sc[t] = myc;
    __syncthreads();
    for (int off = 1; off < 256; off <<= 1) {
        int xv = (t >= off) ? sc[t - off] : 0;
        __syncthreads();
        sc[t] += xv;
        __syncthreads();
    }
    if (n0 + t < n1) {
        rowptr[n0 + t] = R0 + sc[t] - myc;
        dinv[n0 + t] = rsqrtf((float)(myc + 1));
    }
    if (b == NBKT - 1 && t == 0) rowptr[N_NODES] = N_EDGES;
}

// ---- fillB2: in-place fine permutation within each bucket ----
__global__ __launch_bounds__(256) void k_fillB2(const float* __restrict__ dinv,
                                                const int* __restrict__ rowptr,
                                                uint2* __restrict__ csr) {
    __shared__ uint2 lbuf[MAXB];
    __shared__ int lcur[256];
    __shared__ int lrp[256];
    const int t = threadIdx.x;
    const int b = blockIdx.x;
    const int n0 = b << BKT_SHIFT;
    const int n1 = min(n0 + 256, N_NODES);
    const int R0 = rowptr[n0], R1 = rowptr[n1];
    const int cnt = R1 - R0;
    for (int i = t; i < cnt; i += 256) lbuf[i] = csr[R0 + i];
    if (n0 + t < n1) lrp[t] = rowptr[n0 + t];
    lcur[t] = 0;
    __syncthreads();  // all region reads complete before any region write
    for (int i = t; i < cnt; i += 256) {
        uint2 e = lbuf[i];
        int li = (int)e.y & 255;
        int r = atomicAdd(&lcur[li], 1);
        int p = lrp[li] + r;
        csr[p] = make_uint2(e.x, __float_as_uint(dinv[e.x]));
    }
}

// ---- MFMA GEMM1: h1 = fp8(x@w1), identity = x@wd + bd ----
__global__ __launch_bounds__(256) void k_gemm1(const float* __restrict__ x,
                                               const unsigned short* __restrict__ wT,
                                               const float* __restrict__ bd,
                                               unsigned char* __restrict__ h1,
                                               float* __restrict__ identity) {
    __shared__ unsigned short As[128][LDA];
    const int t = threadIdx.x;
    const int rb = blockIdx.x * 128;
    {
        int row = t >> 1, half = t & 1;
        int grow = rb + row;
        if (grow < N_NODES) {
            const float* srcp = &x[(size_t)grow * 128 + half * 64];
#pragma unroll
            for (int i = 0; i < 8; i++) {
                float4 va = *(const float4*)&srcp[i * 8];
                float4 vb = *(const float4*)&srcp[i * 8 + 4];
                unsigned short u[8];
                u[0] = f2b(va.x); u[1] = f2b(va.y); u[2] = f2b(va.z); u[3] = f2b(va.w);
                u[4] = f2b(vb.x); u[5] = f2b(vb.y); u[6] = f2b(vb.z); u[7] = f2b(vb.w);
                *(bf16x8*)&As[row][half * 64 + i * 8] = *(bf16x8*)u;
            }
        } else {
            bf16x8 z = (bf16x8){0, 0, 0, 0, 0, 0, 0, 0};
#pragma unroll
            for (int i = 0; i < 8; i++) *(bf16x8*)&As[row][half * 64 + i * 8] = z;
        }
    }
    __syncthreads();
    const int wid = t >> 6, lane = t & 63;
    const int wr = wid >> 1, wc = wid & 1;
    const int mr = wr * 64, nc = wc * 96;
    const int lrow = lane & 15, lk = (lane >> 4) * 8;
    f32x4 acc[4][6];
#pragma unroll
    for (int m = 0; m < 4; m++)
#pragma unroll
        for (int n = 0; n < 6; n++) acc[m][n] = (f32x4){0.f, 0.f, 0.f, 0.f};

#pragma unroll
    for (int ki = 0; ki < 4; ki++) {
        const int k0 = ki * 32;
        bf16x8 a[4];
#pragma unroll
        for (int m = 0; m < 4; m++)
            a[m] = *(const bf16x8*)&As[mr + m * 16 + lrow][k0 + lk];
#pragma unroll
        for (int n = 0; n < 6; n++) {
            bf16x8 b = *(const bf16x8*)&wT[(size_t)(nc + n * 16 + lrow) * 128 + k0 + lk];
#pragma unroll
            for (int m = 0; m < 4; m++)
                acc[m][n] = __builtin_amdgcn_mfma_f32_16x16x32_bf16(a[m], b, acc[m][n], 0, 0, 0);
        }
    }
    const int crow0 = (lane >> 4) * 4;
#pragma unroll
    for (int m = 0; m < 4; m++) {
#pragma unroll
        for (int j = 0; j < 4; j++) {
            int grow = rb + mr + m * 16 + crow0 + j;
            if (grow >= N_NODES) continue;
#pragma unroll
            for (int n = 0; n < 6; n++) {
                int col = nc + n * 16 + lrow;
                float v = acc[m][n][j];
                if (col < 128) h1[(size_t)grow * 128 + col] = f2fp8(v);
                else           identity[(size_t)grow * 64 + (col - 128)] = v + bd[col - 128];
            }
        }
    }
}

// ---- MFMA GEMM2: h2 = fp8(out1 @ w2), tile 128 x 64 ----
__global__ __launch_bounds__(256) void k_gemm2(const unsigned short* __restrict__ a_in,
                                               const unsigned short* __restrict__ w2T,
                                               unsigned char* __restrict__ h2) {
    __shared__ unsigned short As[128][LDA];
    const int t = threadIdx.x;
    const int rb = blockIdx.x * 128;
    {
        int row = t >> 1, half = t & 1;
        int grow = rb + row;
        if (grow < N_NODES) {
#pragma unroll
            for (int i = 0; i < 8; i++)
                *(bf16x8*)&As[row][half * 64 + i * 8] =
                    *(const bf16x8*)&a_in[(size_t)grow * 128 + half * 64 + i * 8];
        } else {
            bf16x8 z = (bf16x8){0, 0, 0, 0, 0, 0, 0, 0};
#pragma unroll
            for (int i = 0; i < 8; i++) *(bf16x8*)&As[row][half * 64 + i * 8] = z;
        }
    }
    __syncthreads();
    const int wid = t >> 6, lane = t & 63;
    const int wr = wid >> 1, wc = wid & 1;
    const int mr = wr * 64, nc = wc * 32;
    const int lrow = lane & 15, lk = (lane >> 4) * 8;
    f32x4 acc[4][2];
#pragma unroll
    for (int m = 0; m < 4; m++)
#pragma unroll
        for (int n = 0; n < 2; n++) acc[m][n] = (f32x4){0.f, 0.f, 0.f, 0.f};

#pragma unroll
    for (int ki = 0; ki < 4; ki++) {
        const int k0 = ki * 32;
        bf16x8 a[4];
#pragma unroll
        for (int m = 0; m < 4; m++)
            a[m] = *(const bf16x8*)&As[mr + m * 16 + lrow][k0 + lk];
#pragma unroll
        for (int n = 0; n < 2; n++) {
            bf16x8 b = *(const bf16x8*)&w2T[(size_t)(nc + n * 16 + lrow) * 128 + k0 + lk];
#pragma unroll
            for (int m = 0; m < 4; m++)
                acc[m][n] = __builtin_amdgcn_mfma_f32_16x16x32_bf16(a[m], b, acc[m][n], 0, 0, 0);
        }
    }
    const int crow0 = (lane >> 4) * 4;
#pragma unroll
    for (int m = 0; m < 4; m++) {
#pragma unroll
        for (int j = 0; j < 4; j++) {
            int grow = rb + mr + m * 16 + crow0 + j;
            if (grow >= N_NODES) continue;
#pragma unroll
            for (int n = 0; n < 2; n++) {
                int col = nc + n * 16 + lrow;
                h2[(size_t)grow * 64 + col] = f2fp8(acc[m][n][j]);
            }
        }
    }
}

// ---- aggregate 1: out1 = leaky(di*(sum_e dinv_s*h1[src] + di*h1[i]) + b1) ----
// wave = 1 node; 8 groups x 8 lanes; distributed full-wave epilogue
__global__ __launch_bounds__(256) void k_agg1(const unsigned char* __restrict__ h1,
                                              const uint2* __restrict__ csr,
                                              const int* __restrict__ rowptr,
                                              const float* __restrict__ dinv,
                                              const float* __restrict__ b1,
                                              unsigned short* __restrict__ out1) {
    int node = blockIdx.x * 4 + (threadIdx.x >> 6);
    if (node >= N_NODES) return;
    const int lane = threadIdx.x & 63;
    const int g = lane >> 3;   // edge slot 0..7
    const int l = lane & 7;    // feature chunk: [l*16, l*16+16)
    const float di = dinv[node];
    f32x2 a2[8];
#pragma unroll
    for (int i = 0; i < 8; i++) a2[i] = (f32x2){0.f, 0.f};
    const int beg = rowptr[node], end = rowptr[node + 1];
    uint2 ce = csr[beg + g];                 // csr padded with 16 zeroed entries
    for (int e0 = beg; e0 < end; e0 += 8) {
        uint2 ce_n = csr[e0 + 8 + g];        // prefetch next iteration's entry
        int e = e0 + g;
        if (e < end) {
            float w = __uint_as_float(ce.y);  // dinv[src]; di folded into epilogue
            f32x2 w2 = (f32x2){w, w};
            uint4 h = *(const uint4*)&h1[(size_t)ce.x * 128 + l * 16];
            a2[0] = __builtin_elementwise_fma(w2, __builtin_amdgcn_cvt_pk_f32_fp8(h.x, false), a2[0]);
            a2[1] = __builtin_elementwise_fma(w2, __builtin_amdgcn_cvt_pk_f32_fp8(h.x, true),  a2[1]);
            a2[2] = __builtin_elementwise_fma(w2, __builtin_amdgcn_cvt_pk_f32_fp8(h.y, false), a2[2]);
            a2[3] = __builtin_elementwise_fma(w2, __builtin_amdgcn_cvt_pk_f32_fp8(h.y, true),  a2[3]);
            a2[4] = __builtin_elementwise_fma(w2, __builtin_amdgcn_cvt_pk_f32_fp8(h.z, false), a2[4]);
            a2[5] = __builtin_elementwise_fma(w2, __builtin_amdgcn_cvt_pk_f32_fp8(h.z, true),  a2[5]);
            a2[6] = __builtin_elementwise_fma(w2, __builtin_amdgcn_cvt_pk_f32_fp8(h.w, false), a2[6]);
            a2[7] = __builtin_elementwise_fma(w2, __builtin_amdgcn_cvt_pk_f32_fp8(h.w, true),  a2[7]);
        }
        ce = ce_n;
    }
    // butterfly all-reduce across the 8 groups (results replicated on all lanes)
#pragma unroll
    for (int i = 0; i < 8; i++) {
        a2[i].x += __shfl_xor(a2[i].x, 8);
        a2[i].y += __shfl_xor(a2[i].y, 8);
        a2[i].x += __shfl_xor(a2[i].x, 16);
        a2[i].y += __shfl_xor(a2[i].y, 16);
        a2[i].x += __shfl_xor(a2[i].x, 32);
        a2[i].y += __shfl_xor(a2[i].y, 32);
    }
    // distributed epilogue: this lane owns feats f0, f0+1 with values a2[g]
    {
        const int f0 = l * 16 + g * 2;
        unsigned hs = (unsigned)*(const unsigned short*)&h1[(size_t)node * 128 + f0];
        f32x2 sv = __builtin_amdgcn_cvt_pk_f32_fp8(hs, false);
        float2 bb = *(const float2*)&b1[f0];
        float t0 = a2[g].x + di * sv.x;
        float t1 = a2[g].y + di * sv.y;
        float o0 = lrelu(fmaf(t0, di, bb.x));
        float o1 = lrelu(fmaf(t1, di, bb.y));
        unsigned ov = (unsigned)f2b(o0) | ((unsigned)f2b(o1) << 16);
        *(unsigned*)&out1[(size_t)node * 128 + f0] = ov;
    }
}

// ---- aggregate 2 + epilogue: out = leaky(di*(agg + di*h_self) + b2) + identity ----
// wave = 1 node; 8 groups x 8 lanes; distributed epilogue: lane (g,l) writes feat l*8+g
__global__ __launch_bounds__(256) void k_agg2(const unsigned char* __restrict__ h2,
                                              const uint2* __restrict__ csr,
                                              const int* __restrict__ rowptr,
                                              const float* __restrict__ dinv,
                                              const float* __restrict__ b2,
                                              const float* __restrict__ identity,
                                              float* __restrict__ out) {
    int node = blockIdx.x * 4 + (threadIdx.x >> 6);
    if (node >= N_NODES) return;
    const int lane = threadIdx.x & 63;
    const int g = lane >> 3;
    const int l = lane & 7;    // feature chunk: [l*8, l*8+8)
    const float di = dinv[node];
    f32x2 a2[4];
#pragma unroll
    for (int i = 0; i < 4; i++) a2[i] = (f32x2){0.f, 0.f};
    const int beg = rowptr[node], end = rowptr[node + 1];
    uint2 ce = csr[beg + g];
    for (int e0 = beg; e0 < end; e0 += 8) {
        uint2 ce_n = csr[e0 + 8 + g];
        int e = e0 + g;
        if (e < end) {
            float w = __uint_as_float(ce.y);  // dinv[src]
            f32x2 w2 = (f32x2){w, w};
            uint2 h = *(const uint2*)&h2[(size_t)ce.x * 64 + l * 8];
            a2[0] = __builtin_elementwise_fma(w2, __builtin_amdgcn_cvt_pk_f32_fp8(h.x, false), a2[0]);
            a2[1] = __builtin_elementwise_fma(w2, __builtin_amdgcn_cvt_pk_f32_fp8(h.x, true),  a2[1]);
            a2[2] = __builtin_elementwise_fma(w2, __builtin_amdgcn_cvt_pk_f32_fp8(h.y, false), a2[2]);
            a2[3] = __builtin_elementwise_fma(w2, __builtin_amdgcn_cvt_pk_f32_fp8(h.y, true),  a2[3]);
        }
        ce = ce_n;
    }
    float a[8];
#pragma unroll
    for (int i = 0; i < 4; i++) { a[2 * i] = a2[i].x; a[2 * i + 1] = a2[i].y; }
#pragma unroll
    for (int i = 0; i < 8; i++) {
        a[i] += __shfl_xor(a[i], 8);
        a[i] += __shfl_xor(a[i], 16);
        a[i] += __shfl_xor(a[i], 32);
    }
    // distributed epilogue: this lane owns feat f0 = l*8 + g with value a[g]
    {
        const int f0 = l * 8 + g;
        unsigned c = (unsigned)h2[(size_t)node * 64 + f0];
        f32x2 svv = __builtin_amdgcn_cvt_pk_f32_fp8(c, false);
        float sv = svv.x;
        float t = a[g] + di * sv;
        float o = lrelu(fmaf(t, di, b2[f0])) + identity[(size_t)node * 64 + f0];
        out[(size_t)node * 64 + f0] = o;
    }
}

extern "C" void kernel_launch(void* const* d_in, const int* in_sizes, int n_in,
                              void* d_out, int out_size, void* d_ws, size_t ws_size,
                              hipStream_t stream) {
    const float* x  = (const float*)d_in[0];
    const int* eidx = (const int*)d_in[1];
    const float* w1 = (const float*)d_in[2];
    const float* b1 = (const float*)d_in[3];
    const float* w2 = (const float*)d_in[4];
    const float* b2 = (const float*)d_in[5];
    const float* wd = (const float*)d_in[6];
    const float* bd = (const float*)d_in[7];
    const int* src = eidx;
    const int* dst = eidx + N_EDGES;
    float* out = (float*)d_out;

    char* ws = (char*)d_ws;
    size_t off = 0;
    auto take = [&](size_t bytes) -> char* {
        char* p = ws + off;
        off = (off + bytes + 255) & ~(size_t)255;
        return p;
    };
    int* bcnt       = (int*)take((size_t)NBKT * 4);
    int* bbase      = (int*)take((size_t)NBKT * 4);
    int* bcur       = (int*)take((size_t)NBKT * 4);
    int* rowptr     = (int*)take((size_t)(N_NODES + 1) * 4);
    float* dinv     = (float*)take((size_t)N_NODES * 4);
    uint2* csr      = (uint2*)take((size_t)(N_EDGES + 16) * 8);  // +16 zeroed pad entries
    unsigned char* h1   = (unsigned char*)take((size_t)N_NODES * 128);
    unsigned short* out1 = (unsigned short*)take((size_t)N_NODES * 128 * 2);
    unsigned char* h2   = (unsigned char*)take((size_t)N_NODES * 64);
    float* identity = (float*)take((size_t)N_NODES * 64 * 4);
    unsigned short* wT   = (unsigned short*)take((size_t)192 * 128 * 2);
    unsigned short* w2T  = (unsigned short*)take((size_t)64 * 128 * 2);

    hipMemsetAsync(bcnt, 0, (size_t)NBKT * 4, stream);
    hipMemsetAsync(csr + N_EDGES, 0, 16 * sizeof(uint2), stream);

    k_prep<<<(192 * 128 + 255) / 256, 256, 0, stream>>>(w1, wd, w2, wT, w2T);
    k_bhist<<<NBA, 256, 0, stream>>>(dst, bcnt);
    k_bscan<<<1, 512, 0, stream>>>(bcnt, bbase, bcur);
    k_fillA<<<NBA, 256, 0, stream>>>(src, dst, bcur, csr);
    k_fillB1<<<NBKT, 256, 0, stream>>>(csr, bbase, bcnt, rowptr, dinv);
    k_fillB2<<<NBKT, 256, 0, stream>>>(dinv, rowptr, csr);
    k_gemm1<<<(N_NODES + 127) / 128, 256, 0, stream>>>(x, wT, bd, h1, identity);
    k_agg1<<<(N_NODES + 3) / 4, 256, 0, stream>>>(h1, csr, rowptr, dinv, b1, out1);
    k_gemm2<<<(N_NODES + 127) / 128, 256, 0, stream>>>(out1, w2T, h2);
    k_agg2<<<(N_NODES + 3) / 4, 256, 0, stream>>>(h2, csr, rowptr, dinv, b2, identity, out);
}

// Round 15
// 218.281 us; speedup vs baseline: 2.2907x; 1.0445x over previous
//
#include <hip/hip_runtime.h>
#include <hip/hip_bf16.h>

#define N_NODES 100000
#define N_EDGES 1600000
#define NFEAT 128
#define NHID 128
#define NOUT 64
#define NEG_SLOPE 0.01f
#define LDA 136  // 128 + 8 pad (bf16) — row stride 272B, keeps 16B alignment for b128 LDS ops
#define BKT_SHIFT 8
#define NBKT 391          // ceil(100000/256) buckets of 256 nodes
#define EPB_A 4096        // edges per block in fillA/bhist
#define NBA 391           // ceil(1600000/4096)
#define MAXB 6144         // LDS entry cap per bucket

typedef short bf16x8 __attribute__((ext_vector_type(8)));
typedef float f32x4 __attribute__((ext_vector_type(4)));
typedef float f32x2 __attribute__((ext_vector_type(2)));

__device__ __forceinline__ unsigned short f2b(float f) {
    unsigned u = __float_as_uint(f);
    unsigned r = u + 0x7FFFu + ((u >> 16) & 1u);
    return (unsigned short)(r >> 16);
}
__device__ __forceinline__ float b2f(unsigned short h) {
    return __uint_as_float(((unsigned)h) << 16);
}
__device__ __forceinline__ float lrelu(float v) {
    return v > 0.f ? v : v * NEG_SLOPE;
}
// OCP e4m3 via gfx950 HW converts
__device__ __forceinline__ unsigned char f2fp8(float f) {
    return (unsigned char)(__builtin_amdgcn_cvt_pk_fp8_f32(f, f, 0, false) & 0xFF);
}

// ---- transposed bf16 weights: wT[192][128] = [w1 | wd]^T, w2T[64][128] ----
__global__ void k_prep(const float* __restrict__ w1, const float* __restrict__ wd,
                       const float* __restrict__ w2,
                       unsigned short* __restrict__ wT, unsigned short* __restrict__ w2T) {
    int i = blockIdx.x * 256 + threadIdx.x;
    if (i < 192 * 128) {
        int n = i >> 7, k = i & 127;
        float v = (n < 128) ? w1[k * 128 + n] : wd[k * 64 + (n - 128)];
        wT[i] = f2b(v);
    }
    if (i < 64 * 128) {
        int n = i >> 7, k = i & 127;
        w2T[i] = f2b(w2[k * 64 + n]);
    }
}

// ---- bucket-level histogram (391 bins, LDS-aggregated) ----
__global__ __launch_bounds__(256) void k_bhist(const int* __restrict__ dst,
                                               int* __restrict__ bcnt) {
    __shared__ int lcnt[NBKT];
    const int t = threadIdx.x;
    const int e0 = blockIdx.x * EPB_A;
    const int nd = min(EPB_A, N_EDGES - e0);
    for (int i = t; i < NBKT; i += 256) lcnt[i] = 0;
    __syncthreads();
    for (int i = t; i < nd; i += 256) {
        int d = dst[e0 + i];
        atomicAdd(&lcnt[d >> BKT_SHIFT], 1);
    }
    __syncthreads();
    for (int i = t; i < NBKT; i += 256)
        if (lcnt[i]) atomicAdd(&bcnt[i], lcnt[i]);
}

// ---- scan of bucket counts -> bucket bases + cursors (single block) ----
__global__ __launch_bounds__(512) void k_bscan(const int* __restrict__ bcnt,
                                               int* __restrict__ bbase,
                                               int* __restrict__ bcur) {
    __shared__ int sc[512];
    int t = threadIdx.x;
    int v = (t < NBKT) ? bcnt[t] : 0;
    sc[t] = v;
    __syncthreads();
    for (int off = 1; off < 512; off <<= 1) {
        int xv = (t >= off) ? sc[t - off] : 0;
        __syncthreads();
        sc[t] += xv;
        __syncthreads();
    }
    if (t < NBKT) {
        int base = sc[t] - v;
        bbase[t] = base;
        bcur[t] = base;
    }
}

// ---- fillA: coarse bucket scatter of {src, dst} ----
__global__ __launch_bounds__(256) void k_fillA(const int* __restrict__ src,
                                               const int* __restrict__ dst,
                                               int* __restrict__ bcur,
                                               uint2* __restrict__ csr) {
    __shared__ int lcnt[NBKT];
    __shared__ int lbase[NBKT];
    const int t = threadIdx.x;
    const int e0 = blockIdx.x * EPB_A;
    const int nd = min(EPB_A, N_EDGES - e0);
    for (int i = t; i < NBKT; i += 256) lcnt[i] = 0;
    __syncthreads();
    for (int i = t; i < nd; i += 256) {
        int d = dst[e0 + i];
        atomicAdd(&lcnt[d >> BKT_SHIFT], 1);
    }
    __syncthreads();
    for (int i = t; i < NBKT; i += 256)
        lbase[i] = lcnt[i] ? atomicAdd(&bcur[i], lcnt[i]) : 0;
    __syncthreads();
    for (int i = t; i < NBKT; i += 256) lcnt[i] = 0;
    __syncthreads();
    for (int i = t; i < nd; i += 256) {
        int s = src[e0 + i];
        int d = dst[e0 + i];
        int b = d >> BKT_SHIFT;
        int off = atomicAdd(&lcnt[b], 1);
        csr[lbase[b] + off] = make_uint2((unsigned)s, (unsigned)d);
    }
}

// ---- fillB1: per-bucket node counts -> rowptr + dinv (no global atomics) ----
__global__ __launch_bounds__(256) void k_fillB1(const uint2* __restrict__ csr,
                                                const int* __restrict__ bbase,
                                                const int* __restrict__ bcnt,
                                                int* __restrict__ rowptr,
                                                float* __restrict__ dinv) {
    __shared__ int lcnt[256];
    __shared__ int sc[256];
    const int t = threadIdx.x;
    const int b = blockIdx.x;
    const int n0 = b << BKT_SHIFT;
    const int n1 = min(n0 + 256, N_NODES);
    const int R0 = bbase[b];
    const int cntE = bcnt[b];
    lcnt[t] = 0;
    __syncthreads();
    for (int i = t; i < cntE; i += 256) {
        uint2 e = csr[R0 + i];
        atomicAdd(&lcnt[(int)e.y & 255], 1);
    }
    __syncthreads();
    int myc = lcnt[t];
    sc[t] = myc;
    __syncthreads();
    for (int off = 1; off < 256; off <<= 1) {
        int xv = (t >= off) ? sc[t - off] : 0;
        __syncthreads();
        sc[t] += xv;
        __syncthreads();
    }
    if (n0 + t < n1) {
        rowptr[n0 + t] = R0 + sc[t] - myc;
        dinv[n0 + t] = rsqrtf((float)(myc + 1));
    }
    if (b == NBKT - 1 && t == 0) rowptr[N_NODES] = N_EDGES;
}

// ---- fillB2: in-place fine permutation within each bucket ----
__global__ __launch_bounds__(256) void k_fillB2(const float* __restrict__ dinv,
                                                const int* __restrict__ rowptr,
                                                uint2* __restrict__ csr) {
    __shared__ uint2 lbuf[MAXB];
    __shared__ int lcur[256];
    __shared__ int lrp[256];
    const int t = threadIdx.x;
    const int b = blockIdx.x;
    const int n0 = b << BKT_SHIFT;
    const int n1 = min(n0 + 256, N_NODES);
    const int R0 = rowptr[n0], R1 = rowptr[n1];
    const int cnt = R1 - R0;
    for (int i = t; i < cnt; i += 256) lbuf[i] = csr[R0 + i];
    if (n0 + t < n1) lrp[t] = rowptr[n0 + t];
    lcur[t] = 0;
    __syncthreads();  // all region reads complete before any region write
    for (int i = t; i < cnt; i += 256) {
        uint2 e = lbuf[i];
        int li = (int)e.y & 255;
        int r = atomicAdd(&lcur[li], 1);
        int p = lrp[li] + r;
        csr[p] = make_uint2(e.x, __float_as_uint(dinv[e.x]));
    }
}

// ---- MFMA GEMM1: h1 = fp8(x@w1), identity = x@wd + bd ----
__global__ __launch_bounds__(256) void k_gemm1(const float* __restrict__ x,
                                               const unsigned short* __restrict__ wT,
                                               const float* __restrict__ bd,
                                               unsigned char* __restrict__ h1,
                                               float* __restrict__ identity) {
    __shared__ unsigned short As[128][LDA];
    const int t = threadIdx.x;
    const int rb = blockIdx.x * 128;
    {
        int row = t >> 1, half = t & 1;
        int grow = rb + row;
        if (grow < N_NODES) {
            const float* srcp = &x[(size_t)grow * 128 + half * 64];
#pragma unroll
            for (int i = 0; i < 8; i++) {
                float4 va = *(const float4*)&srcp[i * 8];
                float4 vb = *(const float4*)&srcp[i * 8 + 4];
                unsigned short u[8];
                u[0] = f2b(va.x); u[1] = f2b(va.y); u[2] = f2b(va.z); u[3] = f2b(va.w);
                u[4] = f2b(vb.x); u[5] = f2b(vb.y); u[6] = f2b(vb.z); u[7] = f2b(vb.w);
                *(bf16x8*)&As[row][half * 64 + i * 8] = *(bf16x8*)u;
            }
        } else {
            bf16x8 z = (bf16x8){0, 0, 0, 0, 0, 0, 0, 0};
#pragma unroll
            for (int i = 0; i < 8; i++) *(bf16x8*)&As[row][half * 64 + i * 8] = z;
        }
    }
    __syncthreads();
    const int wid = t >> 6, lane = t & 63;
    const int wr = wid >> 1, wc = wid & 1;
    const int mr = wr * 64, nc = wc * 96;
    const int lrow = lane & 15, lk = (lane >> 4) * 8;
    f32x4 acc[4][6];
#pragma unroll
    for (int m = 0; m < 4; m++)
#pragma unroll
        for (int n = 0; n < 6; n++) acc[m][n] = (f32x4){0.f, 0.f, 0.f, 0.f};

#pragma unroll
    for (int ki = 0; ki < 4; ki++) {
        const int k0 = ki * 32;
        bf16x8 a[4];
#pragma unroll
        for (int m = 0; m < 4; m++)
            a[m] = *(const bf16x8*)&As[mr + m * 16 + lrow][k0 + lk];
#pragma unroll
        for (int n = 0; n < 6; n++) {
            bf16x8 b = *(const bf16x8*)&wT[(size_t)(nc + n * 16 + lrow) * 128 + k0 + lk];
#pragma unroll
            for (int m = 0; m < 4; m++)
                acc[m][n] = __builtin_amdgcn_mfma_f32_16x16x32_bf16(a[m], b, acc[m][n], 0, 0, 0);
        }
    }
    const int crow0 = (lane >> 4) * 4;
#pragma unroll
    for (int m = 0; m < 4; m++) {
#pragma unroll
        for (int j = 0; j < 4; j++) {
            int grow = rb + mr + m * 16 + crow0 + j;
            if (grow >= N_NODES) continue;
#pragma unroll
            for (int n = 0; n < 6; n++) {
                int col = nc + n * 16 + lrow;
                float v = acc[m][n][j];
                if (col < 128) h1[(size_t)grow * 128 + col] = f2fp8(v);
                else           identity[(size_t)grow * 64 + (col - 128)] = v + bd[col - 128];
            }
        }
    }
}

// ---- MFMA GEMM2: h2 = fp8(out1 @ w2), tile 128 x 64 ----
__global__ __launch_bounds__(256) void k_gemm2(const unsigned short* __restrict__ a_in,
                                               const unsigned short* __restrict__ w2T,
                                               unsigned char* __restrict__ h2) {
    __shared__ unsigned short As[128][LDA];
    const int t = threadIdx.x;
    const int rb = blockIdx.x * 128;
    {
        int row = t >> 1, half = t & 1;
        int grow = rb + row;
        if (grow < N_NODES) {
#pragma unroll
            for (int i = 0; i < 8; i++)
                *(bf16x8*)&As[row][half * 64 + i * 8] =
                    *(const bf16x8*)&a_in[(size_t)grow * 128 + half * 64 + i * 8];
        } else {
            bf16x8 z = (bf16x8){0, 0, 0, 0, 0, 0, 0, 0};
#pragma unroll
            for (int i = 0; i < 8; i++) *(bf16x8*)&As[row][half * 64 + i * 8] = z;
        }
    }
    __syncthreads();
    const int wid = t >> 6, lane = t & 63;
    const int wr = wid >> 1, wc = wid & 1;
    const int mr = wr * 64, nc = wc * 32;
    const int lrow = lane & 15, lk = (lane >> 4) * 8;
    f32x4 acc[4][2];
#pragma unroll
    for (int m = 0; m < 4; m++)
#pragma unroll
        for (int n = 0; n < 2; n++) acc[m][n] = (f32x4){0.f, 0.f, 0.f, 0.f};

#pragma unroll
    for (int ki = 0; ki < 4; ki++) {
        const int k0 = ki * 32;
        bf16x8 a[4];
#pragma unroll
        for (int m = 0; m < 4; m++)
            a[m] = *(const bf16x8*)&As[mr + m * 16 + lrow][k0 + lk];
#pragma unroll
        for (int n = 0; n < 2; n++) {
            bf16x8 b = *(const bf16x8*)&w2T[(size_t)(nc + n * 16 + lrow) * 128 + k0 + lk];
#pragma unroll
            for (int m = 0; m < 4; m++)
                acc[m][n] = __builtin_amdgcn_mfma_f32_16x16x32_bf16(a[m], b, acc[m][n], 0, 0, 0);
        }
    }
    const int crow0 = (lane >> 4) * 4;
#pragma unroll
    for (int m = 0; m < 4; m++) {
#pragma unroll
        for (int j = 0; j < 4; j++) {
            int grow = rb + mr + m * 16 + crow0 + j;
            if (grow >= N_NODES) continue;
#pragma unroll
            for (int n = 0; n < 2; n++) {
                int col = nc + n * 16 + lrow;
                h2[(size_t)grow * 64 + col] = f2fp8(acc[m][n][j]);
            }
        }
    }
}

// ---- aggregate 1: out1 = leaky(di*(sum_e dinv_s*h1[src] + di*h1[i]) + b1) ----
// wave = 1 node; 8 groups x 8 lanes. Reduce-SCATTER butterfly (3 steps, value
// set halves each step) instead of all-reduce: lane (g,l) ends with exactly
// the sum for its owned feats f0 = l*16 + 2g — all indices static.
__global__ __launch_bounds__(256) void k_agg1(const unsigned char* __restrict__ h1,
                                              const uint2* __restrict__ csr,
                                              const int* __restrict__ rowptr,
                                              const float* __restrict__ dinv,
                                              const float* __restrict__ b1,
                                              unsigned short* __restrict__ out1) {
    int node = blockIdx.x * 4 + (threadIdx.x >> 6);
    if (node >= N_NODES) return;
    const int lane = threadIdx.x & 63;
    const int g = lane >> 3;   // edge slot 0..7
    const int l = lane & 7;    // feature chunk: [l*16, l*16+16)
    const float di = dinv[node];
    f32x2 a2[8];
#pragma unroll
    for (int i = 0; i < 8; i++) a2[i] = (f32x2){0.f, 0.f};
    const int beg = rowptr[node], end = rowptr[node + 1];
    uint2 ce = csr[beg + g];                 // csr padded with 16 zeroed entries
    for (int e0 = beg; e0 < end; e0 += 8) {
        uint2 ce_n = csr[e0 + 8 + g];        // prefetch next iteration's entry
        int e = e0 + g;
        if (e < end) {
            float w = __uint_as_float(ce.y);  // dinv[src]; di folded into epilogue
            f32x2 w2 = (f32x2){w, w};
            uint4 h = *(const uint4*)&h1[(size_t)ce.x * 128 + l * 16];
            a2[0] = __builtin_elementwise_fma(w2, __builtin_amdgcn_cvt_pk_f32_fp8(h.x, false), a2[0]);
            a2[1] = __builtin_elementwise_fma(w2, __builtin_amdgcn_cvt_pk_f32_fp8(h.x, true),  a2[1]);
            a2[2] = __builtin_elementwise_fma(w2, __builtin_amdgcn_cvt_pk_f32_fp8(h.y, false), a2[2]);
            a2[3] = __builtin_elementwise_fma(w2, __builtin_amdgcn_cvt_pk_f32_fp8(h.y, true),  a2[3]);
            a2[4] = __builtin_elementwise_fma(w2, __builtin_amdgcn_cvt_pk_f32_fp8(h.z, false), a2[4]);
            a2[5] = __builtin_elementwise_fma(w2, __builtin_amdgcn_cvt_pk_f32_fp8(h.z, true),  a2[5]);
            a2[6] = __builtin_elementwise_fma(w2, __builtin_amdgcn_cvt_pk_f32_fp8(h.w, false), a2[6]);
            a2[7] = __builtin_elementwise_fma(w2, __builtin_amdgcn_cvt_pk_f32_fp8(h.w, true),  a2[7]);
        }
        ce = ce_n;
    }
    // reduce-scatter butterfly over group bits g2 (xor32), g1 (xor16), g0 (xor8)
    const bool s2 = (lane & 32) != 0;
    const bool s1 = (lane & 16) != 0;
    const bool s0 = (lane & 8) != 0;
    f32x2 rA[4];
#pragma unroll
    for (int j = 0; j < 4; j++) {
        f32x2 keep = s2 ? a2[j + 4] : a2[j];
        f32x2 send = s2 ? a2[j] : a2[j + 4];
        rA[j].x = keep.x + __shfl_xor(send.x, 32);
        rA[j].y = keep.y + __shfl_xor(send.y, 32);
    }
    f32x2 rB[2];
#pragma unroll
    for (int j = 0; j < 2; j++) {
        f32x2 keep = s1 ? rA[j + 2] : rA[j];
        f32x2 send = s1 ? rA[j] : rA[j + 2];
        rB[j].x = keep.x + __shfl_xor(send.x, 16);
        rB[j].y = keep.y + __shfl_xor(send.y, 16);
    }
    f32x2 rC;
    {
        f32x2 keep = s0 ? rB[1] : rB[0];
        f32x2 send = s0 ? rB[0] : rB[1];
        rC.x = keep.x + __shfl_xor(send.x, 8);
        rC.y = keep.y + __shfl_xor(send.y, 8);
    }
    // distributed epilogue: this lane owns feats f0, f0+1 with values rC
    {
        const int f0 = l * 16 + g * 2;
        unsigned hs = (unsigned)*(const unsigned short*)&h1[(size_t)node * 128 + f0];
        f32x2 sv = __builtin_amdgcn_cvt_pk_f32_fp8(hs, false);
        float2 bb = *(const float2*)&b1[f0];
        float t0 = rC.x + di * sv.x;
        float t1 = rC.y + di * sv.y;
        float o0 = lrelu(fmaf(t0, di, bb.x));
        float o1 = lrelu(fmaf(t1, di, bb.y));
        unsigned ov = (unsigned)f2b(o0) | ((unsigned)f2b(o1) << 16);
        *(unsigned*)&out1[(size_t)node * 128 + f0] = ov;
    }
}

// ---- aggregate 2 + epilogue: out = leaky(di*(agg + di*h_self) + b2) + identity ----
// wave = 1 node; 8 groups x 8 lanes; reduce-scatter; lane (g,l) writes feat l*8+g
__global__ __launch_bounds__(256) void k_agg2(const unsigned char* __restrict__ h2,
                                              const uint2* __restrict__ csr,
                                              const int* __restrict__ rowptr,
                                              const float* __restrict__ dinv,
                                              const float* __restrict__ b2,
                                              const float* __restrict__ identity,
                                              float* __restrict__ out) {
    int node = blockIdx.x * 4 + (threadIdx.x >> 6);
    if (node >= N_NODES) return;
    const int lane = threadIdx.x & 63;
    const int g = lane >> 3;
    const int l = lane & 7;    // feature chunk: [l*8, l*8+8)
    const float di = dinv[node];
    f32x2 a2[4];
#pragma unroll
    for (int i = 0; i < 4; i++) a2[i] = (f32x2){0.f, 0.f};
    const int beg = rowptr[node], end = rowptr[node + 1];
    uint2 ce = csr[beg + g];
    for (int e0 = beg; e0 < end; e0 += 8) {
        uint2 ce_n = csr[e0 + 8 + g];
        int e = e0 + g;
        if (e < end) {
            float w = __uint_as_float(ce.y);  // dinv[src]
            f32x2 w2 = (f32x2){w, w};
            uint2 h = *(const uint2*)&h2[(size_t)ce.x * 64 + l * 8];
            a2[0] = __builtin_elementwise_fma(w2, __builtin_amdgcn_cvt_pk_f32_fp8(h.x, false), a2[0]);
            a2[1] = __builtin_elementwise_fma(w2, __builtin_amdgcn_cvt_pk_f32_fp8(h.x, true),  a2[1]);
            a2[2] = __builtin_elementwise_fma(w2, __builtin_amdgcn_cvt_pk_f32_fp8(h.y, false), a2[2]);
            a2[3] = __builtin_elementwise_fma(w2, __builtin_amdgcn_cvt_pk_f32_fp8(h.y, true),  a2[3]);
        }
        ce = ce_n;
    }
    float a[8];
#pragma unroll
    for (int i = 0; i < 4; i++) { a[2 * i] = a2[i].x; a[2 * i + 1] = a2[i].y; }
    // reduce-scatter over group bits
    const bool s2 = (lane & 32) != 0;
    const bool s1 = (lane & 16) != 0;
    const bool s0 = (lane & 8) != 0;
    float kA[4];
#pragma unroll
    for (int j = 0; j < 4; j++) {
        float keep = s2 ? a[j + 4] : a[j];
        float send = s2 ? a[j] : a[j + 4];
        kA[j] = keep + __shfl_xor(send, 32);
    }
    float kB[2];
#pragma unroll
    for (int j = 0; j < 2; j++) {
        float keep = s1 ? kA[j + 2] : kA[j];
        float send = s1 ? kA[j] : kA[j + 2];
        kB[j] = keep + __shfl_xor(send, 16);
    }
    float kC;
    {
        float keep = s0 ? kB[1] : kB[0];
        float send = s0 ? kB[0] : kB[1];
        kC = keep + __shfl_xor(send, 8);
    }
    // distributed epilogue: this lane owns feat f0 = l*8 + g with value kC
    {
        const int f0 = l * 8 + g;
        unsigned c = (unsigned)h2[(size_t)node * 64 + f0];
        f32x2 svv = __builtin_amdgcn_cvt_pk_f32_fp8(c, false);
        float sv = svv.x;
        float t = kC + di * sv;
        float o = lrelu(fmaf(t, di, b2[f0])) + identity[(size_t)node * 64 + f0];
        out[(size_t)node * 64 + f0] = o;
    }
}

extern "C" void kernel_launch(void* const* d_in, const int* in_sizes, int n_in,
                              void* d_out, int out_size, void* d_ws, size_t ws_size,
                              hipStream_t stream) {
    const float* x  = (const float*)d_in[0];
    const int* eidx = (const int*)d_in[1];
    const float* w1 = (const float*)d_in[2];
    const float* b1 = (const float*)d_in[3];
    const float* w2 = (const float*)d_in[4];
    const float* b2 = (const float*)d_in[5];
    const float* wd = (const float*)d_in[6];
    const float* bd = (const float*)d_in[7];
    const int* src = eidx;
    const int* dst = eidx + N_EDGES;
    float* out = (float*)d_out;

    char* ws = (char*)d_ws;
    size_t off = 0;
    auto take = [&](size_t bytes) -> char* {
        char* p = ws + off;
        off = (off + bytes + 255) & ~(size_t)255;
        return p;
    };
    int* bcnt       = (int*)take((size_t)NBKT * 4);
    int* bbase      = (int*)take((size_t)NBKT * 4);
    int* bcur       = (int*)take((size_t)NBKT * 4);
    int* rowptr     = (int*)take((size_t)(N_NODES + 1) * 4);
    float* dinv     = (float*)take((size_t)N_NODES * 4);
    uint2* csr      = (uint2*)take((size_t)(N_EDGES + 16) * 8);  // +16 zeroed pad entries
    unsigned char* h1   = (unsigned char*)take((size_t)N_NODES * 128);
    unsigned short* out1 = (unsigned short*)take((size_t)N_NODES * 128 * 2);
    unsigned char* h2   = (unsigned char*)take((size_t)N_NODES * 64);
    float* identity = (float*)take((size_t)N_NODES * 64 * 4);
    unsigned short* wT   = (unsigned short*)take((size_t)192 * 128 * 2);
    unsigned short* w2T  = (unsigned short*)take((size_t)64 * 128 * 2);

    hipMemsetAsync(bcnt, 0, (size_t)NBKT * 4, stream);
    hipMemsetAsync(csr + N_EDGES, 0, 16 * sizeof(uint2), stream);

    k_prep<<<(192 * 128 + 255) / 256, 256, 0, stream>>>(w1, wd, w2, wT, w2T);
    k_bhist<<<NBA, 256, 0, stream>>>(dst, bcnt);
    k_bscan<<<1, 512, 0, stream>>>(bcnt, bbase, bcur);
    k_fillA<<<NBA, 256, 0, stream>>>(src, dst, bcur, csr);
    k_fillB1<<<NBKT, 256, 0, stream>>>(csr, bbase, bcnt, rowptr, dinv);
    k_fillB2<<<NBKT, 256, 0, stream>>>(dinv, rowptr, csr);
    k_gemm1<<<(N_NODES + 127) / 128, 256, 0, stream>>>(x, wT, bd, h1, identity);
    k_agg1<<<(N_NODES + 3) / 4, 256, 0, stream>>>(h1, csr, rowptr, dinv, b1, out1);
    k_gemm2<<<(N_NODES + 127) / 128, 256, 0, stream>>>(out1, w2T, h2);
    k_agg2<<<(N_NODES + 3) / 4, 256, 0, stream>>>(h2, csr, rowptr, dinv, b2, identity, out);
}

// Round 16
// 216.076 us; speedup vs baseline: 2.3141x; 1.0102x over previous
//
#include <hip/hip_runtime.h>
#include <hip/hip_bf16.h>

#define N_NODES 100000
#define N_EDGES 1600000
#define NFEAT 128
#define NHID 128
#define NOUT 64
#define NEG_SLOPE 0.01f
#define LDA 136  // 128 + 8 pad (bf16) — row stride 272B, keeps 16B alignment for b128 LDS ops
#define BKT_SHIFT 8
#define NBKT 391          // ceil(100000/256) buckets of 256 nodes
#define EPB_A 4096        // edges per block in fillA/bhist
#define NBA 391           // ceil(1600000/4096)
#define MAXB 6144         // LDS entry cap per bucket

typedef short bf16x8 __attribute__((ext_vector_type(8)));
typedef float f32x4 __attribute__((ext_vector_type(4)));
typedef float f32x2 __attribute__((ext_vector_type(2)));

__device__ __forceinline__ unsigned short f2b(float f) {
    unsigned u = __float_as_uint(f);
    unsigned r = u + 0x7FFFu + ((u >> 16) & 1u);
    return (unsigned short)(r >> 16);
}
__device__ __forceinline__ float b2f(unsigned short h) {
    return __uint_as_float(((unsigned)h) << 16);
}
__device__ __forceinline__ float lrelu(float v) {
    return v > 0.f ? v : v * NEG_SLOPE;
}
// OCP e4m3 via gfx950 HW converts
__device__ __forceinline__ unsigned char f2fp8(float f) {
    return (unsigned char)(__builtin_amdgcn_cvt_pk_fp8_f32(f, f, 0, false) & 0xFF);
}

// ---- transposed bf16 weights: wT[192][128] = [w1 | wd]^T, w2T[64][128] ----
__global__ void k_prep(const float* __restrict__ w1, const float* __restrict__ wd,
                       const float* __restrict__ w2,
                       unsigned short* __restrict__ wT, unsigned short* __restrict__ w2T) {
    int i = blockIdx.x * 256 + threadIdx.x;
    if (i < 192 * 128) {
        int n = i >> 7, k = i & 127;
        float v = (n < 128) ? w1[k * 128 + n] : wd[k * 64 + (n - 128)];
        wT[i] = f2b(v);
    }
    if (i < 64 * 128) {
        int n = i >> 7, k = i & 127;
        w2T[i] = f2b(w2[k * 64 + n]);
    }
}

// ---- bucket-level histogram (391 bins, LDS-aggregated) ----
__global__ __launch_bounds__(256) void k_bhist(const int* __restrict__ dst,
                                               int* __restrict__ bcnt) {
    __shared__ int lcnt[NBKT];
    const int t = threadIdx.x;
    const int e0 = blockIdx.x * EPB_A;
    const int nd = min(EPB_A, N_EDGES - e0);
    for (int i = t; i < NBKT; i += 256) lcnt[i] = 0;
    __syncthreads();
    for (int i = t; i < nd; i += 256) {
        int d = dst[e0 + i];
        atomicAdd(&lcnt[d >> BKT_SHIFT], 1);
    }
    __syncthreads();
    for (int i = t; i < NBKT; i += 256)
        if (lcnt[i]) atomicAdd(&bcnt[i], lcnt[i]);
}

// ---- scan of bucket counts -> bucket bases + cursors (single block) ----
__global__ __launch_bounds__(512) void k_bscan(const int* __restrict__ bcnt,
                                               int* __restrict__ bbase,
                                               int* __restrict__ bcur) {
    __shared__ int sc[512];
    int t = threadIdx.x;
    int v = (t < NBKT) ? bcnt[t] : 0;
    sc[t] = v;
    __syncthreads();
    for (int off = 1; off < 512; off <<= 1) {
        int xv = (t >= off) ? sc[t - off] : 0;
        __syncthreads();
        sc[t] += xv;
        __syncthreads();
    }
    if (t < NBKT) {
        int base = sc[t] - v;
        bbase[t] = base;
        bcur[t] = base;
    }
}

// ---- fillA: coarse bucket scatter of {src, dst} ----
__global__ __launch_bounds__(256) void k_fillA(const int* __restrict__ src,
                                               const int* __restrict__ dst,
                                               int* __restrict__ bcur,
                                               uint2* __restrict__ csr) {
    __shared__ int lcnt[NBKT];
    __shared__ int lbase[NBKT];
    const int t = threadIdx.x;
    const int e0 = blockIdx.x * EPB_A;
    const int nd = min(EPB_A, N_EDGES - e0);
    for (int i = t; i < NBKT; i += 256) lcnt[i] = 0;
    __syncthreads();
    for (int i = t; i < nd; i += 256) {
        int d = dst[e0 + i];
        atomicAdd(&lcnt[d >> BKT_SHIFT], 1);
    }
    __syncthreads();
    for (int i = t; i < NBKT; i += 256)
        lbase[i] = lcnt[i] ? atomicAdd(&bcur[i], lcnt[i]) : 0;
    __syncthreads();
    for (int i = t; i < NBKT; i += 256) lcnt[i] = 0;
    __syncthreads();
    for (int i = t; i < nd; i += 256) {
        int s = src[e0 + i];
        int d = dst[e0 + i];
        int b = d >> BKT_SHIFT;
        int off = atomicAdd(&lcnt[b], 1);
        csr[lbase[b] + off] = make_uint2((unsigned)s, (unsigned)d);
    }
}

// ---- fillB1: per-bucket node counts -> rowptr + dinv (no global atomics) ----
__global__ __launch_bounds__(256) void k_fillB1(const uint2* __restrict__ csr,
                                                const int* __restrict__ bbase,
                                                const int* __restrict__ bcnt,
                                                int* __restrict__ rowptr,
                                                float* __restrict__ dinv) {
    __shared__ int lcnt[256];
    __shared__ int sc[256];
    const int t = threadIdx.x;
    const int b = blockIdx.x;
    const int n0 = b << BKT_SHIFT;
    const int n1 = min(n0 + 256, N_NODES);
    const int R0 = bbase[b];
    const int cntE = bcnt[b];
    lcnt[t] = 0;
    __syncthreads();
    for (int i = t; i < cntE; i += 256) {
        uint2 e = csr[R0 + i];
        atomicAdd(&lcnt[(int)e.y & 255], 1);
    }
    __syncthreads();
    int myc = lcnt[t];
    sc[t] = myc;
    __syncthreads();
    for (int off = 1; off < 256; off <<= 1) {
        int xv = (t >= off) ? sc[t - off] : 0;
        __syncthreads();
        sc[t] += xv;
        __syncthreads();
    }
    if (n0 + t < n1) {
        rowptr[n0 + t] = R0 + sc[t] - myc;
        dinv[n0 + t] = rsqrtf((float)(myc + 1));
    }
    if (b == NBKT - 1 && t == 0) rowptr[N_NODES] = N_EDGES;
}

// ---- fillB2: in-place fine permutation within each bucket ----
__global__ __launch_bounds__(256) void k_fillB2(const float* __restrict__ dinv,
                                                const int* __restrict__ rowptr,
                                                uint2* __restrict__ csr) {
    __shared__ uint2 lbuf[MAXB];
    __shared__ int lcur[256];
    __shared__ int lrp[256];
    const int t = threadIdx.x;
    const int b = blockIdx.x;
    const int n0 = b << BKT_SHIFT;
    const int n1 = min(n0 + 256, N_NODES);
    const int R0 = rowptr[n0], R1 = rowptr[n1];
    const int cnt = R1 - R0;
    for (int i = t; i < cnt; i += 256) lbuf[i] = csr[R0 + i];
    if (n0 + t < n1) lrp[t] = rowptr[n0 + t];
    lcur[t] = 0;
    __syncthreads();  // all region reads complete before any region write
    for (int i = t; i < cnt; i += 256) {
        uint2 e = lbuf[i];
        int li = (int)e.y & 255;
        int r = atomicAdd(&lcur[li], 1);
        int p = lrp[li] + r;
        csr[p] = make_uint2(e.x, __float_as_uint(dinv[e.x]));
    }
}

// ---- MFMA GEMM1: h1 = fp8(x@w1), identity = x@wd + bd ----
// 64-row tile (1563 blocks), LDS 17.4KB; A-fragments hoisted to regs; B loaded
// 4-at-a-time per n-column so loads overlap MFMAs (latency tolerance).
__global__ __launch_bounds__(256) void k_gemm1(const float* __restrict__ x,
                                               const unsigned short* __restrict__ wT,
                                               const float* __restrict__ bd,
                                               unsigned char* __restrict__ h1,
                                               float* __restrict__ identity) {
    __shared__ unsigned short As[64][LDA];
    const int t = threadIdx.x;
    const int rb = blockIdx.x * 64;
    {
        int row = t >> 2, q = t & 3;   // 4 threads per row, 32 elems each
        int grow = rb + row;
        if (grow < N_NODES) {
            const float* srcp = &x[(size_t)grow * 128 + q * 32];
#pragma unroll
            for (int i = 0; i < 4; i++) {
                float4 va = *(const float4*)&srcp[i * 8];
                float4 vb = *(const float4*)&srcp[i * 8 + 4];
                unsigned short u[8];
                u[0] = f2b(va.x); u[1] = f2b(va.y); u[2] = f2b(va.z); u[3] = f2b(va.w);
                u[4] = f2b(vb.x); u[5] = f2b(vb.y); u[6] = f2b(vb.z); u[7] = f2b(vb.w);
                *(bf16x8*)&As[row][q * 32 + i * 8] = *(bf16x8*)u;
            }
        } else {
            bf16x8 z = (bf16x8){0, 0, 0, 0, 0, 0, 0, 0};
#pragma unroll
            for (int i = 0; i < 4; i++) *(bf16x8*)&As[row][q * 32 + i * 8] = z;
        }
    }
    __syncthreads();
    const int wid = t >> 6, lane = t & 63;
    const int wr = wid >> 1, wc = wid & 1;
    const int mr = wr * 32, nc = wc * 96;
    const int lrow = lane & 15, lk = (lane >> 4) * 8;
    // hoist all A fragments to registers (8 x bf16x8 = 32 VGPRs)
    bf16x8 a[4][2];
#pragma unroll
    for (int ki = 0; ki < 4; ki++)
#pragma unroll
        for (int m = 0; m < 2; m++)
            a[ki][m] = *(const bf16x8*)&As[mr + m * 16 + lrow][ki * 32 + lk];
    f32x4 acc[2][6];
#pragma unroll
    for (int m = 0; m < 2; m++)
#pragma unroll
        for (int n = 0; n < 6; n++) acc[m][n] = (f32x4){0.f, 0.f, 0.f, 0.f};

#pragma unroll
    for (int n = 0; n < 6; n++) {
        bf16x8 b[4];
#pragma unroll
        for (int ki = 0; ki < 4; ki++)
            b[ki] = *(const bf16x8*)&wT[(size_t)(nc + n * 16 + lrow) * 128 + ki * 32 + lk];
#pragma unroll
        for (int ki = 0; ki < 4; ki++)
#pragma unroll
            for (int m = 0; m < 2; m++)
                acc[m][n] = __builtin_amdgcn_mfma_f32_16x16x32_bf16(a[ki][m], b[ki], acc[m][n], 0, 0, 0);
    }
    const int crow0 = (lane >> 4) * 4;
#pragma unroll
    for (int m = 0; m < 2; m++) {
#pragma unroll
        for (int j = 0; j < 4; j++) {
            int grow = rb + mr + m * 16 + crow0 + j;
            if (grow >= N_NODES) continue;
#pragma unroll
            for (int n = 0; n < 6; n++) {
                int col = nc + n * 16 + lrow;
                float v = acc[m][n][j];
                if (col < 128) h1[(size_t)grow * 128 + col] = f2fp8(v);
                else           identity[(size_t)grow * 64 + (col - 128)] = v + bd[col - 128];
            }
        }
    }
}

// ---- MFMA GEMM2: h2 = fp8(out1 @ w2), 64-row tile, same latency structure ----
__global__ __launch_bounds__(256) void k_gemm2(const unsigned short* __restrict__ a_in,
                                               const unsigned short* __restrict__ w2T,
                                               unsigned char* __restrict__ h2) {
    __shared__ unsigned short As[64][LDA];
    const int t = threadIdx.x;
    const int rb = blockIdx.x * 64;
    {
        int row = t >> 2, q = t & 3;
        int grow = rb + row;
        if (grow < N_NODES) {
#pragma unroll
            for (int i = 0; i < 4; i++)
                *(bf16x8*)&As[row][q * 32 + i * 8] =
                    *(const bf16x8*)&a_in[(size_t)grow * 128 + q * 32 + i * 8];
        } else {
            bf16x8 z = (bf16x8){0, 0, 0, 0, 0, 0, 0, 0};
#pragma unroll
            for (int i = 0; i < 4; i++) *(bf16x8*)&As[row][q * 32 + i * 8] = z;
        }
    }
    __syncthreads();
    const int wid = t >> 6, lane = t & 63;
    const int wr = wid >> 1, wc = wid & 1;
    const int mr = wr * 32, nc = wc * 32;
    const int lrow = lane & 15, lk = (lane >> 4) * 8;
    bf16x8 a[4][2];
#pragma unroll
    for (int ki = 0; ki < 4; ki++)
#pragma unroll
        for (int m = 0; m < 2; m++)
            a[ki][m] = *(const bf16x8*)&As[mr + m * 16 + lrow][ki * 32 + lk];
    f32x4 acc[2][2];
#pragma unroll
    for (int m = 0; m < 2; m++)
#pragma unroll
        for (int n = 0; n < 2; n++) acc[m][n] = (f32x4){0.f, 0.f, 0.f, 0.f};

#pragma unroll
    for (int n = 0; n < 2; n++) {
        bf16x8 b[4];
#pragma unroll
        for (int ki = 0; ki < 4; ki++)
            b[ki] = *(const bf16x8*)&w2T[(size_t)(nc + n * 16 + lrow) * 128 + ki * 32 + lk];
#pragma unroll
        for (int ki = 0; ki < 4; ki++)
#pragma unroll
            for (int m = 0; m < 2; m++)
                acc[m][n] = __builtin_amdgcn_mfma_f32_16x16x32_bf16(a[ki][m], b[ki], acc[m][n], 0, 0, 0);
    }
    const int crow0 = (lane >> 4) * 4;
#pragma unroll
    for (int m = 0; m < 2; m++) {
#pragma unroll
        for (int j = 0; j < 4; j++) {
            int grow = rb + mr + m * 16 + crow0 + j;
            if (grow >= N_NODES) continue;
#pragma unroll
            for (int n = 0; n < 2; n++) {
                int col = nc + n * 16 + lrow;
                h2[(size_t)grow * 64 + col] = f2fp8(acc[m][n][j]);
            }
        }
    }
}

// ---- aggregate 1: out1 = leaky(di*(sum_e dinv_s*h1[src] + di*h1[i]) + b1) ----
// wave = 1 node; 8 groups x 8 lanes; reduce-scatter butterfly + distributed epilogue
__global__ __launch_bounds__(256) void k_agg1(const unsigned char* __restrict__ h1,
                                              const uint2* __restrict__ csr,
                                              const int* __restrict__ rowptr,
                                              const float* __restrict__ dinv,
                                              const float* __restrict__ b1,
                                              unsigned short* __restrict__ out1) {
    int node = blockIdx.x * 4 + (threadIdx.x >> 6);
    if (node >= N_NODES) return;
    const int lane = threadIdx.x & 63;
    const int g = lane >> 3;   // edge slot 0..7
    const int l = lane & 7;    // feature chunk: [l*16, l*16+16)
    const float di = dinv[node];
    f32x2 a2[8];
#pragma unroll
    for (int i = 0; i < 8; i++) a2[i] = (f32x2){0.f, 0.f};
    const int beg = rowptr[node], end = rowptr[node + 1];
    uint2 ce = csr[beg + g];                 // csr padded with 16 zeroed entries
    for (int e0 = beg; e0 < end; e0 += 8) {
        uint2 ce_n = csr[e0 + 8 + g];        // prefetch next iteration's entry
        int e = e0 + g;
        if (e < end) {
            float w = __uint_as_float(ce.y);  // dinv[src]; di folded into epilogue
            f32x2 w2 = (f32x2){w, w};
            uint4 h = *(const uint4*)&h1[(size_t)ce.x * 128 + l * 16];
            a2[0] = __builtin_elementwise_fma(w2, __builtin_amdgcn_cvt_pk_f32_fp8(h.x, false), a2[0]);
            a2[1] = __builtin_elementwise_fma(w2, __builtin_amdgcn_cvt_pk_f32_fp8(h.x, true),  a2[1]);
            a2[2] = __builtin_elementwise_fma(w2, __builtin_amdgcn_cvt_pk_f32_fp8(h.y, false), a2[2]);
            a2[3] = __builtin_elementwise_fma(w2, __builtin_amdgcn_cvt_pk_f32_fp8(h.y, true),  a2[3]);
            a2[4] = __builtin_elementwise_fma(w2, __builtin_amdgcn_cvt_pk_f32_fp8(h.z, false), a2[4]);
            a2[5] = __builtin_elementwise_fma(w2, __builtin_amdgcn_cvt_pk_f32_fp8(h.z, true),  a2[5]);
            a2[6] = __builtin_elementwise_fma(w2, __builtin_amdgcn_cvt_pk_f32_fp8(h.w, false), a2[6]);
            a2[7] = __builtin_elementwise_fma(w2, __builtin_amdgcn_cvt_pk_f32_fp8(h.w, true),  a2[7]);
        }
        ce = ce_n;
    }
    // reduce-scatter butterfly over group bits g2 (xor32), g1 (xor16), g0 (xor8)
    const bool s2 = (lane & 32) != 0;
    const bool s1 = (lane & 16) != 0;
    const bool s0 = (lane & 8) != 0;
    f32x2 rA[4];
#pragma unroll
    for (int j = 0; j < 4; j++) {
        f32x2 keep = s2 ? a2[j + 4] : a2[j];
        f32x2 send = s2 ? a2[j] : a2[j + 4];
        rA[j].x = keep.x + __shfl_xor(send.x, 32);
        rA[j].y = keep.y + __shfl_xor(send.y, 32);
    }
    f32x2 rB[2];
#pragma unroll
    for (int j = 0; j < 2; j++) {
        f32x2 keep = s1 ? rA[j + 2] : rA[j];
        f32x2 send = s1 ? rA[j] : rA[j + 2];
        rB[j].x = keep.x + __shfl_xor(send.x, 16);
        rB[j].y = keep.y + __shfl_xor(send.y, 16);
    }
    f32x2 rC;
    {
        f32x2 keep = s0 ? rB[1] : rB[0];
        f32x2 send = s0 ? rB[0] : rB[1];
        rC.x = keep.x + __shfl_xor(send.x, 8);
        rC.y = keep.y + __shfl_xor(send.y, 8);
    }
    // distributed epilogue: this lane owns feats f0, f0+1 with values rC
    {
        const int f0 = l * 16 + g * 2;
        unsigned hs = (unsigned)*(const unsigned short*)&h1[(size_t)node * 128 + f0];
        f32x2 sv = __builtin_amdgcn_cvt_pk_f32_fp8(hs, false);
        float2 bb = *(const float2*)&b1[f0];
        float t0 = rC.x + di * sv.x;
        float t1 = rC.y + di * sv.y;
        float o0 = lrelu(fmaf(t0, di, bb.x));
        float o1 = lrelu(fmaf(t1, di, bb.y));
        unsigned ov = (unsigned)f2b(o0) | ((unsigned)f2b(o1) << 16);
        *(unsigned*)&out1[(size_t)node * 128 + f0] = ov;
    }
}

// ---- aggregate 2 + epilogue: out = leaky(di*(agg + di*h_self) + b2) + identity ----
// wave = 1 node; 8 groups x 8 lanes; reduce-scatter; lane (g,l) writes feat l*8+g
__global__ __launch_bounds__(256) void k_agg2(const unsigned char* __restrict__ h2,
                                              const uint2* __restrict__ csr,
                                              const int* __restrict__ rowptr,
                                              const float* __restrict__ dinv,
                                              const float* __restrict__ b2,
                                              const float* __restrict__ identity,
                                              float* __restrict__ out) {
    int node = blockIdx.x * 4 + (threadIdx.x >> 6);
    if (node >= N_NODES) return;
    const int lane = threadIdx.x & 63;
    const int g = lane >> 3;
    const int l = lane & 7;    // feature chunk: [l*8, l*8+8)
    const float di = dinv[node];
    f32x2 a2[4];
#pragma unroll
    for (int i = 0; i < 4; i++) a2[i] = (f32x2){0.f, 0.f};
    const int beg = rowptr[node], end = rowptr[node + 1];
    uint2 ce = csr[beg + g];
    for (int e0 = beg; e0 < end; e0 += 8) {
        uint2 ce_n = csr[e0 + 8 + g];
        int e = e0 + g;
        if (e < end) {
            float w = __uint_as_float(ce.y);  // dinv[src]
            f32x2 w2 = (f32x2){w, w};
            uint2 h = *(const uint2*)&h2[(size_t)ce.x * 64 + l * 8];
            a2[0] = __builtin_elementwise_fma(w2, __builtin_amdgcn_cvt_pk_f32_fp8(h.x, false), a2[0]);
            a2[1] = __builtin_elementwise_fma(w2, __builtin_amdgcn_cvt_pk_f32_fp8(h.x, true),  a2[1]);
            a2[2] = __builtin_elementwise_fma(w2, __builtin_amdgcn_cvt_pk_f32_fp8(h.y, false), a2[2]);
            a2[3] = __builtin_elementwise_fma(w2, __builtin_amdgcn_cvt_pk_f32_fp8(h.y, true),  a2[3]);
        }
        ce = ce_n;
    }
    float a[8];
#pragma unroll
    for (int i = 0; i < 4; i++) { a[2 * i] = a2[i].x; a[2 * i + 1] = a2[i].y; }
    // reduce-scatter over group bits
    const bool s2 = (lane & 32) != 0;
    const bool s1 = (lane & 16) != 0;
    const bool s0 = (lane & 8) != 0;
    float kA[4];
#pragma unroll
    for (int j = 0; j < 4; j++) {
        float keep = s2 ? a[j + 4] : a[j];
        float send = s2 ? a[j] : a[j + 4];
        kA[j] = keep + __shfl_xor(send, 32);
    }
    float kB[2];
#pragma unroll
    for (int j = 0; j < 2; j++) {
        float keep = s1 ? kA[j + 2] : kA[j];
        float send = s1 ? kA[j] : kA[j + 2];
        kB[j] = keep + __shfl_xor(send, 16);
    }
    float kC;
    {
        float keep = s0 ? kB[1] : kB[0];
        float send = s0 ? kB[0] : kB[1];
        kC = keep + __shfl_xor(send, 8);
    }
    // distributed epilogue: this lane owns feat f0 = l*8 + g with value kC
    {
        const int f0 = l * 8 + g;
        unsigned c = (unsigned)h2[(size_t)node * 64 + f0];
        f32x2 svv = __builtin_amdgcn_cvt_pk_f32_fp8(c, false);
        float sv = svv.x;
        float t = kC + di * sv;
        float o = lrelu(fmaf(t, di, b2[f0])) + identity[(size_t)node * 64 + f0];
        out[(size_t)node * 64 + f0] = o;
    }
}

extern "C" void kernel_launch(void* const* d_in, const int* in_sizes, int n_in,
                              void* d_out, int out_size, void* d_ws, size_t ws_size,
                              hipStream_t stream) {
    const float* x  = (const float*)d_in[0];
    const int* eidx = (const int*)d_in[1];
    const float* w1 = (const float*)d_in[2];
    const float* b1 = (const float*)d_in[3];
    const float* w2 = (const float*)d_in[4];
    const float* b2 = (const float*)d_in[5];
    const float* wd = (const float*)d_in[6];
    const float* bd = (const float*)d_in[7];
    const int* src = eidx;
    const int* dst = eidx + N_EDGES;
    float* out = (float*)d_out;

    char* ws = (char*)d_ws;
    size_t off = 0;
    auto take = [&](size_t bytes) -> char* {
        char* p = ws + off;
        off = (off + bytes + 255) & ~(size_t)255;
        return p;
    };
    int* bcnt       = (int*)take((size_t)NBKT * 4);
    int* bbase      = (int*)take((size_t)NBKT * 4);
    int* bcur       = (int*)take((size_t)NBKT * 4);
    int* rowptr     = (int*)take((size_t)(N_NODES + 1) * 4);
    float* dinv     = (float*)take((size_t)N_NODES * 4);
    uint2* csr      = (uint2*)take((size_t)(N_EDGES + 16) * 8);  // +16 zeroed pad entries
    unsigned char* h1   = (unsigned char*)take((size_t)N_NODES * 128);
    unsigned short* out1 = (unsigned short*)take((size_t)N_NODES * 128 * 2);
    unsigned char* h2   = (unsigned char*)take((size_t)N_NODES * 64);
    float* identity = (float*)take((size_t)N_NODES * 64 * 4);
    unsigned short* wT   = (unsigned short*)take((size_t)192 * 128 * 2);
    unsigned short* w2T  = (unsigned short*)take((size_t)64 * 128 * 2);

    hipMemsetAsync(bcnt, 0, (size_t)NBKT * 4, stream);
    hipMemsetAsync(csr + N_EDGES, 0, 16 * sizeof(uint2), stream);

    k_prep<<<(192 * 128 + 255) / 256, 256, 0, stream>>>(w1, wd, w2, wT, w2T);
    k_bhist<<<NBA, 256, 0, stream>>>(dst, bcnt);
    k_bscan<<<1, 512, 0, stream>>>(bcnt, bbase, bcur);
    k_fillA<<<NBA, 256, 0, stream>>>(src, dst, bcur, csr);
    k_fillB1<<<NBKT, 256, 0, stream>>>(csr, bbase, bcnt, rowptr, dinv);
    k_fillB2<<<NBKT, 256, 0, stream>>>(dinv, rowptr, csr);
    k_gemm1<<<(N_NODES + 63) / 64, 256, 0, stream>>>(x, wT, bd, h1, identity);
    k_agg1<<<(N_NODES + 3) / 4, 256, 0, stream>>>(h1, csr, rowptr, dinv, b1, out1);
    k_gemm2<<<(N_NODES + 63) / 64, 256, 0, stream>>>(out1, w2T, h2);
    k_agg2<<<(N_NODES + 3) / 4, 256, 0, stream>>>(h2, csr, rowptr, dinv, b2, identity, out);
}

// Round 17
// 215.659 us; speedup vs baseline: 2.3186x; 1.0019x over previous
//
#include <hip/hip_runtime.h>
#include <hip/hip_bf16.h>

#define N_NODES 100000
#define N_EDGES 1600000
#define NFEAT 128
#define NHID 128
#define NOUT 64
#define NEG_SLOPE 0.01f
#define LDA 136  // 128 + 8 pad (bf16) — row stride 272B, keeps 16B alignment for b128 LDS ops
#define BKT_SHIFT 8
#define NBKT 391          // ceil(100000/256) buckets of 256 nodes
#define EPB_A 4096        // edges per block in fillA/bhist
#define NBA 391           // ceil(1600000/4096)
#define MAXB 6144         // LDS entry cap per bucket

typedef short bf16x8 __attribute__((ext_vector_type(8)));
typedef float f32x4 __attribute__((ext_vector_type(4)));
typedef float f32x2 __attribute__((ext_vector_type(2)));

__device__ __forceinline__ unsigned short f2b(float f) {
    unsigned u = __float_as_uint(f);
    unsigned r = u + 0x7FFFu + ((u >> 16) & 1u);
    return (unsigned short)(r >> 16);
}
__device__ __forceinline__ float b2f(unsigned short h) {
    return __uint_as_float(((unsigned)h) << 16);
}
__device__ __forceinline__ float lrelu(float v) {
    return v > 0.f ? v : v * NEG_SLOPE;
}
// OCP e4m3 via gfx950 HW converts
__device__ __forceinline__ unsigned char f2fp8(float f) {
    return (unsigned char)(__builtin_amdgcn_cvt_pk_fp8_f32(f, f, 0, false) & 0xFF);
}

// ---- transposed bf16 weights: wT[192][128] = [w1 | wd]^T, w2T[64][128] ----
__global__ void k_prep(const float* __restrict__ w1, const float* __restrict__ wd,
                       const float* __restrict__ w2,
                       unsigned short* __restrict__ wT, unsigned short* __restrict__ w2T) {
    int i = blockIdx.x * 256 + threadIdx.x;
    if (i < 192 * 128) {
        int n = i >> 7, k = i & 127;
        float v = (n < 128) ? w1[k * 128 + n] : wd[k * 64 + (n - 128)];
        wT[i] = f2b(v);
    }
    if (i < 64 * 128) {
        int n = i >> 7, k = i & 127;
        w2T[i] = f2b(w2[k * 64 + n]);
    }
}

// ---- bucket-level histogram (391 bins, LDS-aggregated) ----
__global__ __launch_bounds__(256) void k_bhist(const int* __restrict__ dst,
                                               int* __restrict__ bcnt) {
    __shared__ int lcnt[NBKT];
    const int t = threadIdx.x;
    const int e0 = blockIdx.x * EPB_A;
    const int nd = min(EPB_A, N_EDGES - e0);
    for (int i = t; i < NBKT; i += 256) lcnt[i] = 0;
    __syncthreads();
    for (int i = t; i < nd; i += 256) {
        int d = dst[e0 + i];
        atomicAdd(&lcnt[d >> BKT_SHIFT], 1);
    }
    __syncthreads();
    for (int i = t; i < NBKT; i += 256)
        if (lcnt[i]) atomicAdd(&bcnt[i], lcnt[i]);
}

// ---- scan of bucket counts -> bucket bases + cursors (single block) ----
__global__ __launch_bounds__(512) void k_bscan(const int* __restrict__ bcnt,
                                               int* __restrict__ bbase,
                                               int* __restrict__ bcur) {
    __shared__ int sc[512];
    int t = threadIdx.x;
    int v = (t < NBKT) ? bcnt[t] : 0;
    sc[t] = v;
    __syncthreads();
    for (int off = 1; off < 512; off <<= 1) {
        int xv = (t >= off) ? sc[t - off] : 0;
        __syncthreads();
        sc[t] += xv;
        __syncthreads();
    }
    if (t < NBKT) {
        int base = sc[t] - v;
        bbase[t] = base;
        bcur[t] = base;
    }
}

// ---- fillA: coarse bucket scatter of {src, dst} ----
__global__ __launch_bounds__(256) void k_fillA(const int* __restrict__ src,
                                               const int* __restrict__ dst,
                                               int* __restrict__ bcur,
                                               uint2* __restrict__ csr) {
    __shared__ int lcnt[NBKT];
    __shared__ int lbase[NBKT];
    const int t = threadIdx.x;
    const int e0 = blockIdx.x * EPB_A;
    const int nd = min(EPB_A, N_EDGES - e0);
    for (int i = t; i < NBKT; i += 256) lcnt[i] = 0;
    __syncthreads();
    for (int i = t; i < nd; i += 256) {
        int d = dst[e0 + i];
        atomicAdd(&lcnt[d >> BKT_SHIFT], 1);
    }
    __syncthreads();
    for (int i = t; i < NBKT; i += 256)
        lbase[i] = lcnt[i] ? atomicAdd(&bcur[i], lcnt[i]) : 0;
    __syncthreads();
    for (int i = t; i < NBKT; i += 256) lcnt[i] = 0;
    __syncthreads();
    for (int i = t; i < nd; i += 256) {
        int s = src[e0 + i];
        int d = dst[e0 + i];
        int b = d >> BKT_SHIFT;
        int off = atomicAdd(&lcnt[b], 1);
        csr[lbase[b] + off] = make_uint2((unsigned)s, (unsigned)d);
    }
}

// ---- fillB1: per-bucket node counts -> rowptr + dinv (no global atomics) ----
__global__ __launch_bounds__(256) void k_fillB1(const uint2* __restrict__ csr,
                                                const int* __restrict__ bbase,
                                                const int* __restrict__ bcnt,
                                                int* __restrict__ rowptr,
                                                float* __restrict__ dinv) {
    __shared__ int lcnt[256];
    __shared__ int sc[256];
    const int t = threadIdx.x;
    const int b = blockIdx.x;
    const int n0 = b << BKT_SHIFT;
    const int n1 = min(n0 + 256, N_NODES);
    const int R0 = bbase[b];
    const int cntE = bcnt[b];
    lcnt[t] = 0;
    __syncthreads();
    for (int i = t; i < cntE; i += 256) {
        uint2 e = csr[R0 + i];
        atomicAdd(&lcnt[(int)e.y & 255], 1);
    }
    __syncthreads();
    int myc = lcnt[t];
    sc[t] = myc;
    __syncthreads();
    for (int off = 1; off < 256; off <<= 1) {
        int xv = (t >= off) ? sc[t - off] : 0;
        __syncthreads();
        sc[t] += xv;
        __syncthreads();
    }
    if (n0 + t < n1) {
        rowptr[n0 + t] = R0 + sc[t] - myc;
        dinv[n0 + t] = rsqrtf((float)(myc + 1));
    }
    if (b == NBKT - 1 && t == 0) rowptr[N_NODES] = N_EDGES;
}

// ---- fillB2: in-place fine permutation within each bucket ----
__global__ __launch_bounds__(256) void k_fillB2(const float* __restrict__ dinv,
                                                const int* __restrict__ rowptr,
                                                uint2* __restrict__ csr) {
    __shared__ uint2 lbuf[MAXB];
    __shared__ int lcur[256];
    __shared__ int lrp[256];
    const int t = threadIdx.x;
    const int b = blockIdx.x;
    const int n0 = b << BKT_SHIFT;
    const int n1 = min(n0 + 256, N_NODES);
    const int R0 = rowptr[n0], R1 = rowptr[n1];
    const int cnt = R1 - R0;
    for (int i = t; i < cnt; i += 256) lbuf[i] = csr[R0 + i];
    if (n0 + t < n1) lrp[t] = rowptr[n0 + t];
    lcur[t] = 0;
    __syncthreads();  // all region reads complete before any region write
    for (int i = t; i < cnt; i += 256) {
        uint2 e = lbuf[i];
        int li = (int)e.y & 255;
        int r = atomicAdd(&lcur[li], 1);
        int p = lrp[li] + r;
        csr[p] = make_uint2(e.x, __float_as_uint(dinv[e.x]));
    }
}

// ---- MFMA GEMM1: h1 = fp8(x@w1), identity = x@wd + bd ----
// 64-row tile; __launch_bounds__(256,1) releases VGPRs so ALL staging loads
// (8x16B) and ALL B loads (24x16B) are issued as independent batches.
__global__ __launch_bounds__(256, 1) void k_gemm1(const float* __restrict__ x,
                                                  const unsigned short* __restrict__ wT,
                                                  const float* __restrict__ bd,
                                                  unsigned char* __restrict__ h1,
                                                  float* __restrict__ identity) {
    __shared__ unsigned short As[64][LDA];
    const int t = threadIdx.x;
    const int rb = blockIdx.x * 64;
    {
        int row = t >> 2, q = t & 3;   // 4 threads per row, 32 elems each
        int grow = rb + row;
        if (grow < N_NODES) {
            const float* srcp = &x[(size_t)grow * 128 + q * 32];
            // phase 1: issue all 8 loads (64 VGPRs of payload in flight)
            float4 va0 = *(const float4*)&srcp[0];
            float4 vb0 = *(const float4*)&srcp[4];
            float4 va1 = *(const float4*)&srcp[8];
            float4 vb1 = *(const float4*)&srcp[12];
            float4 va2 = *(const float4*)&srcp[16];
            float4 vb2 = *(const float4*)&srcp[20];
            float4 va3 = *(const float4*)&srcp[24];
            float4 vb3 = *(const float4*)&srcp[28];
            // phase 2: convert + LDS write
            unsigned short u[8];
            u[0]=f2b(va0.x); u[1]=f2b(va0.y); u[2]=f2b(va0.z); u[3]=f2b(va0.w);
            u[4]=f2b(vb0.x); u[5]=f2b(vb0.y); u[6]=f2b(vb0.z); u[7]=f2b(vb0.w);
            *(bf16x8*)&As[row][q * 32 + 0] = *(bf16x8*)u;
            u[0]=f2b(va1.x); u[1]=f2b(va1.y); u[2]=f2b(va1.z); u[3]=f2b(va1.w);
            u[4]=f2b(vb1.x); u[5]=f2b(vb1.y); u[6]=f2b(vb1.z); u[7]=f2b(vb1.w);
            *(bf16x8*)&As[row][q * 32 + 8] = *(bf16x8*)u;
            u[0]=f2b(va2.x); u[1]=f2b(va2.y); u[2]=f2b(va2.z); u[3]=f2b(va2.w);
            u[4]=f2b(vb2.x); u[5]=f2b(vb2.y); u[6]=f2b(vb2.z); u[7]=f2b(vb2.w);
            *(bf16x8*)&As[row][q * 32 + 16] = *(bf16x8*)u;
            u[0]=f2b(va3.x); u[1]=f2b(va3.y); u[2]=f2b(va3.z); u[3]=f2b(va3.w);
            u[4]=f2b(vb3.x); u[5]=f2b(vb3.y); u[6]=f2b(vb3.z); u[7]=f2b(vb3.w);
            *(bf16x8*)&As[row][q * 32 + 24] = *(bf16x8*)u;
        } else {
            bf16x8 z = (bf16x8){0, 0, 0, 0, 0, 0, 0, 0};
#pragma unroll
            for (int i = 0; i < 4; i++) *(bf16x8*)&As[row][q * 32 + i * 8] = z;
        }
    }
    __syncthreads();
    const int wid = t >> 6, lane = t & 63;
    const int wr = wid >> 1, wc = wid & 1;
    const int mr = wr * 32, nc = wc * 96;
    const int lrow = lane & 15, lk = (lane >> 4) * 8;
    // hoist all A fragments to registers (8 x bf16x8 = 32 VGPRs)
    bf16x8 a[4][2];
#pragma unroll
    for (int ki = 0; ki < 4; ki++)
#pragma unroll
        for (int m = 0; m < 2; m++)
            a[ki][m] = *(const bf16x8*)&As[mr + m * 16 + lrow][ki * 32 + lk];
    // hoist ALL B fragments (24 x bf16x8 = 96 VGPRs) — one batch of independent loads
    bf16x8 b[6][4];
#pragma unroll
    for (int n = 0; n < 6; n++)
#pragma unroll
        for (int ki = 0; ki < 4; ki++)
            b[n][ki] = *(const bf16x8*)&wT[(size_t)(nc + n * 16 + lrow) * 128 + ki * 32 + lk];
    f32x4 acc[2][6];
#pragma unroll
    for (int m = 0; m < 2; m++)
#pragma unroll
        for (int n = 0; n < 6; n++) acc[m][n] = (f32x4){0.f, 0.f, 0.f, 0.f};
#pragma unroll
    for (int n = 0; n < 6; n++)
#pragma unroll
        for (int ki = 0; ki < 4; ki++)
#pragma unroll
            for (int m = 0; m < 2; m++)
                acc[m][n] = __builtin_amdgcn_mfma_f32_16x16x32_bf16(a[ki][m], b[n][ki], acc[m][n], 0, 0, 0);
    const int crow0 = (lane >> 4) * 4;
#pragma unroll
    for (int m = 0; m < 2; m++) {
#pragma unroll
        for (int j = 0; j < 4; j++) {
            int grow = rb + mr + m * 16 + crow0 + j;
            if (grow >= N_NODES) continue;
#pragma unroll
            for (int n = 0; n < 6; n++) {
                int col = nc + n * 16 + lrow;
                float v = acc[m][n][j];
                if (col < 128) h1[(size_t)grow * 128 + col] = f2fp8(v);
                else           identity[(size_t)grow * 64 + (col - 128)] = v + bd[col - 128];
            }
        }
    }
}

// ---- MFMA GEMM2: h2 = fp8(out1 @ w2), 64-row tile, same latency structure ----
__global__ __launch_bounds__(256, 1) void k_gemm2(const unsigned short* __restrict__ a_in,
                                                  const unsigned short* __restrict__ w2T,
                                                  unsigned char* __restrict__ h2) {
    __shared__ unsigned short As[64][LDA];
    const int t = threadIdx.x;
    const int rb = blockIdx.x * 64;
    {
        int row = t >> 2, q = t & 3;
        int grow = rb + row;
        if (grow < N_NODES) {
            const unsigned short* sp = &a_in[(size_t)grow * 128 + q * 32];
            bf16x8 v0 = *(const bf16x8*)&sp[0];
            bf16x8 v1 = *(const bf16x8*)&sp[8];
            bf16x8 v2 = *(const bf16x8*)&sp[16];
            bf16x8 v3 = *(const bf16x8*)&sp[24];
            *(bf16x8*)&As[row][q * 32 + 0]  = v0;
            *(bf16x8*)&As[row][q * 32 + 8]  = v1;
            *(bf16x8*)&As[row][q * 32 + 16] = v2;
            *(bf16x8*)&As[row][q * 32 + 24] = v3;
        } else {
            bf16x8 z = (bf16x8){0, 0, 0, 0, 0, 0, 0, 0};
#pragma unroll
            for (int i = 0; i < 4; i++) *(bf16x8*)&As[row][q * 32 + i * 8] = z;
        }
    }
    __syncthreads();
    const int wid = t >> 6, lane = t & 63;
    const int wr = wid >> 1, wc = wid & 1;
    const int mr = wr * 32, nc = wc * 32;
    const int lrow = lane & 15, lk = (lane >> 4) * 8;
    bf16x8 a[4][2];
#pragma unroll
    for (int ki = 0; ki < 4; ki++)
#pragma unroll
        for (int m = 0; m < 2; m++)
            a[ki][m] = *(const bf16x8*)&As[mr + m * 16 + lrow][ki * 32 + lk];
    bf16x8 b[2][4];
#pragma unroll
    for (int n = 0; n < 2; n++)
#pragma unroll
        for (int ki = 0; ki < 4; ki++)
            b[n][ki] = *(const bf16x8*)&w2T[(size_t)(nc + n * 16 + lrow) * 128 + ki * 32 + lk];
    f32x4 acc[2][2];
#pragma unroll
    for (int m = 0; m < 2; m++)
#pragma unroll
        for (int n = 0; n < 2; n++) acc[m][n] = (f32x4){0.f, 0.f, 0.f, 0.f};
#pragma unroll
    for (int n = 0; n < 2; n++)
#pragma unroll
        for (int ki = 0; ki < 4; ki++)
#pragma unroll
            for (int m = 0; m < 2; m++)
                acc[m][n] = __builtin_amdgcn_mfma_f32_16x16x32_bf16(a[ki][m], b[n][ki], acc[m][n], 0, 0, 0);
    const int crow0 = (lane >> 4) * 4;
#pragma unroll
    for (int m = 0; m < 2; m++) {
#pragma unroll
        for (int j = 0; j < 4; j++) {
            int grow = rb + mr + m * 16 + crow0 + j;
            if (grow >= N_NODES) continue;
#pragma unroll
            for (int n = 0; n < 2; n++) {
                int col = nc + n * 16 + lrow;
                h2[(size_t)grow * 64 + col] = f2fp8(acc[m][n][j]);
            }
        }
    }
}

// ---- aggregate 1: out1 = leaky(di*(sum_e dinv_s*h1[src] + di*h1[i]) + b1) ----
// wave = 1 node; 8 groups x 8 lanes; reduce-scatter butterfly + distributed epilogue
__global__ __launch_bounds__(256) void k_agg1(const unsigned char* __restrict__ h1,
                                              const uint2* __restrict__ csr,
                                              const int* __restrict__ rowptr,
                                              const float* __restrict__ dinv,
                                              const float* __restrict__ b1,
                                              unsigned short* __restrict__ out1) {
    int node = blockIdx.x * 4 + (threadIdx.x >> 6);
    if (node >= N_NODES) return;
    const int lane = threadIdx.x & 63;
    const int g = lane >> 3;   // edge slot 0..7
    const int l = lane & 7;    // feature chunk: [l*16, l*16+16)
    const float di = dinv[node];
    f32x2 a2[8];
#pragma unroll
    for (int i = 0; i < 8; i++) a2[i] = (f32x2){0.f, 0.f};
    const int beg = rowptr[node], end = rowptr[node + 1];
    uint2 ce = csr[beg + g];                 // csr padded with 16 zeroed entries
    for (int e0 = beg; e0 < end; e0 += 8) {
        uint2 ce_n = csr[e0 + 8 + g];        // prefetch next iteration's entry
        int e = e0 + g;
        if (e < end) {
            float w = __uint_as_float(ce.y);  // dinv[src]; di folded into epilogue
            f32x2 w2 = (f32x2){w, w};
            uint4 h = *(const uint4*)&h1[(size_t)ce.x * 128 + l * 16];
            a2[0] = __builtin_elementwise_fma(w2, __builtin_amdgcn_cvt_pk_f32_fp8(h.x, false), a2[0]);
            a2[1] = __builtin_elementwise_fma(w2, __builtin_amdgcn_cvt_pk_f32_fp8(h.x, true),  a2[1]);
            a2[2] = __builtin_elementwise_fma(w2, __builtin_amdgcn_cvt_pk_f32_fp8(h.y, false), a2[2]);
            a2[3] = __builtin_elementwise_fma(w2, __builtin_amdgcn_cvt_pk_f32_fp8(h.y, true),  a2[3]);
            a2[4] = __builtin_elementwise_fma(w2, __builtin_amdgcn_cvt_pk_f32_fp8(h.z, false), a2[4]);
            a2[5] = __builtin_elementwise_fma(w2, __builtin_amdgcn_cvt_pk_f32_fp8(h.z, true),  a2[5]);
            a2[6] = __builtin_elementwise_fma(w2, __builtin_amdgcn_cvt_pk_f32_fp8(h.w, false), a2[6]);
            a2[7] = __builtin_elementwise_fma(w2, __builtin_amdgcn_cvt_pk_f32_fp8(h.w, true),  a2[7]);
        }
        ce = ce_n;
    }
    // reduce-scatter butterfly over group bits g2 (xor32), g1 (xor16), g0 (xor8)
    const bool s2 = (lane & 32) != 0;
    const bool s1 = (lane & 16) != 0;
    const bool s0 = (lane & 8) != 0;
    f32x2 rA[4];
#pragma unroll
    for (int j = 0; j < 4; j++) {
        f32x2 keep = s2 ? a2[j + 4] : a2[j];
        f32x2 send = s2 ? a2[j] : a2[j + 4];
        rA[j].x = keep.x + __shfl_xor(send.x, 32);
        rA[j].y = keep.y + __shfl_xor(send.y, 32);
    }
    f32x2 rB[2];
#pragma unroll
    for (int j = 0; j < 2; j++) {
        f32x2 keep = s1 ? rA[j + 2] : rA[j];
        f32x2 send = s1 ? rA[j] : rA[j + 2];
        rB[j].x = keep.x + __shfl_xor(send.x, 16);
        rB[j].y = keep.y + __shfl_xor(send.y, 16);
    }
    f32x2 rC;
    {
        f32x2 keep = s0 ? rB[1] : rB[0];
        f32x2 send = s0 ? rB[0] : rB[1];
        rC.x = keep.x + __shfl_xor(send.x, 8);
        rC.y = keep.y + __shfl_xor(send.y, 8);
    }
    // distributed epilogue: this lane owns feats f0, f0+1 with values rC
    {
        const int f0 = l * 16 + g * 2;
        unsigned hs = (unsigned)*(const unsigned short*)&h1[(size_t)node * 128 + f0];
        f32x2 sv = __builtin_amdgcn_cvt_pk_f32_fp8(hs, false);
        float2 bb = *(const float2*)&b1[f0];
        float t0 = rC.x + di * sv.x;
        float t1 = rC.y + di * sv.y;
        float o0 = lrelu(fmaf(t0, di, bb.x));
        float o1 = lrelu(fmaf(t1, di, bb.y));
        unsigned ov = (unsigned)f2b(o0) | ((unsigned)f2b(o1) << 16);
        *(unsigned*)&out1[(size_t)node * 128 + f0] = ov;
    }
}

// ---- aggregate 2 + epilogue: out = leaky(di*(agg + di*h_self) + b2) + identity ----
// wave = 1 node; 8 groups x 8 lanes; reduce-scatter; lane (g,l) writes feat l*8+g
__global__ __launch_bounds__(256) void k_agg2(const unsigned char* __restrict__ h2,
                                              const uint2* __restrict__ csr,
                                              const int* __restrict__ rowptr,
                                              const float* __restrict__ dinv,
                                              const float* __restrict__ b2,
                                              const float* __restrict__ identity,
                                              float* __restrict__ out) {
    int node = blockIdx.x * 4 + (threadIdx.x >> 6);
    if (node >= N_NODES) return;
    const int lane = threadIdx.x & 63;
    const int g = lane >> 3;
    const int l = lane & 7;    // feature chunk: [l*8, l*8+8)
    const float di = dinv[node];
    f32x2 a2[4];
#pragma unroll
    for (int i = 0; i < 4; i++) a2[i] = (f32x2){0.f, 0.f};
    const int beg = rowptr[node], end = rowptr[node + 1];
    uint2 ce = csr[beg + g];
    for (int e0 = beg; e0 < end; e0 += 8) {
        uint2 ce_n = csr[e0 + 8 + g];
        int e = e0 + g;
        if (e < end) {
            float w = __uint_as_float(ce.y);  // dinv[src]
            f32x2 w2 = (f32x2){w, w};
            uint2 h = *(const uint2*)&h2[(size_t)ce.x * 64 + l * 8];
            a2[0] = __builtin_elementwise_fma(w2, __builtin_amdgcn_cvt_pk_f32_fp8(h.x, false), a2[0]);
            a2[1] = __builtin_elementwise_fma(w2, __builtin_amdgcn_cvt_pk_f32_fp8(h.x, true),  a2[1]);
            a2[2] = __builtin_elementwise_fma(w2, __builtin_amdgcn_cvt_pk_f32_fp8(h.y, false), a2[2]);
            a2[3] = __builtin_elementwise_fma(w2, __builtin_amdgcn_cvt_pk_f32_fp8(h.y, true),  a2[3]);
        }
        ce = ce_n;
    }
    float a[8];
#pragma unroll
    for (int i = 0; i < 4; i++) { a[2 * i] = a2[i].x; a[2 * i + 1] = a2[i].y; }
    // reduce-scatter over group bits
    const bool s2 = (lane & 32) != 0;
    const bool s1 = (lane & 16) != 0;
    const bool s0 = (lane & 8) != 0;
    float kA[4];
#pragma unroll
    for (int j = 0; j < 4; j++) {
        float keep = s2 ? a[j + 4] : a[j];
        float send = s2 ? a[j] : a[j + 4];
        kA[j] = keep + __shfl_xor(send, 32);
    }
    float kB[2];
#pragma unroll
    for (int j = 0; j < 2; j++) {
        float keep = s1 ? kA[j + 2] : kA[j];
        float send = s1 ? kA[j] : kA[j + 2];
        kB[j] = keep + __shfl_xor(send, 16);
    }
    float kC;
    {
        float keep = s0 ? kB[1] : kB[0];
        float send = s0 ? kB[0] : kB[1];
        kC = keep + __shfl_xor(send, 8);
    }
    // distributed epilogue: this lane owns feat f0 = l*8 + g with value kC
    {
        const int f0 = l * 8 + g;
        unsigned c = (unsigned)h2[(size_t)node * 64 + f0];
        f32x2 svv = __builtin_amdgcn_cvt_pk_f32_fp8(c, false);
        float sv = svv.x;
        float t = kC + di * sv;
        float o = lrelu(fmaf(t, di, b2[f0])) + identity[(size_t)node * 64 + f0];
        out[(size_t)node * 64 + f0] = o;
    }
}

extern "C" void kernel_launch(void* const* d_in, const int* in_sizes, int n_in,
                              void* d_out, int out_size, void* d_ws, size_t ws_size,
                              hipStream_t stream) {
    const float* x  = (const float*)d_in[0];
    const int* eidx = (const int*)d_in[1];
    const float* w1 = (const float*)d_in[2];
    const float* b1 = (const float*)d_in[3];
    const float* w2 = (const float*)d_in[4];
    const float* b2 = (const float*)d_in[5];
    const float* wd = (const float*)d_in[6];
    const float* bd = (const float*)d_in[7];
    const int* src = eidx;
    const int* dst = eidx + N_EDGES;
    float* out = (float*)d_out;

    char* ws = (char*)d_ws;
    size_t off = 0;
    auto take = [&](size_t bytes) -> char* {
        char* p = ws + off;
        off = (off + bytes + 255) & ~(size_t)255;
        return p;
    };
    int* bcnt       = (int*)take((size_t)NBKT * 4);
    int* bbase      = (int*)take((size_t)NBKT * 4);
    int* bcur       = (int*)take((size_t)NBKT * 4);
    int* rowptr     = (int*)take((size_t)(N_NODES + 1) * 4);
    float* dinv     = (float*)take((size_t)N_NODES * 4);
    uint2* csr      = (uint2*)take((size_t)(N_EDGES + 16) * 8);  // +16 zeroed pad entries
    unsigned char* h1   = (unsigned char*)take((size_t)N_NODES * 128);
    unsigned short* out1 = (unsigned short*)take((size_t)N_NODES * 128 * 2);
    unsigned char* h2   = (unsigned char*)take((size_t)N_NODES * 64);
    float* identity = (float*)take((size_t)N_NODES * 64 * 4);
    unsigned short* wT   = (unsigned short*)take((size_t)192 * 128 * 2);
    unsigned short* w2T  = (unsigned short*)take((size_t)64 * 128 * 2);

    hipMemsetAsync(bcnt, 0, (size_t)NBKT * 4, stream);
    hipMemsetAsync(csr + N_EDGES, 0, 16 * sizeof(uint2), stream);

    k_prep<<<(192 * 128 + 255) / 256, 256, 0, stream>>>(w1, wd, w2, wT, w2T);
    k_bhist<<<NBA, 256, 0, stream>>>(dst, bcnt);
    k_bscan<<<1, 512, 0, stream>>>(bcnt, bbase, bcur);
    k_fillA<<<NBA, 256, 0, stream>>>(src, dst, bcur, csr);
    k_fillB1<<<NBKT, 256, 0, stream>>>(csr, bbase, bcnt, rowptr, dinv);
    k_fillB2<<<NBKT, 256, 0, stream>>>(dinv, rowptr, csr);
    k_gemm1<<<(N_NODES + 63) / 64, 256, 0, stream>>>(x, wT, bd, h1, identity);
    k_agg1<<<(N_NODES + 3) / 4, 256, 0, stream>>>(h1, csr, rowptr, dinv, b1, out1);
    k_gemm2<<<(N_NODES + 63) / 64, 256, 0, stream>>>(out1, w2T, h2);
    k_agg2<<<(N_NODES + 3) / 4, 256, 0, stream>>>(h2, csr, rowptr, dinv, b2, identity, out);
}

// Round 19
// 211.195 us; speedup vs baseline: 2.3676x; 1.0211x over previous
//
#include <hip/hip_runtime.h>
#include <hip/hip_bf16.h>

#define N_NODES 100000
#define N_EDGES 1600000
#define NFEAT 128
#define NHID 128
#define NOUT 64
#define NEG_SLOPE 0.01f
#define LDA 136  // 128 + 8 pad (bf16) — row stride 272B, keeps 16B alignment for b128 LDS ops
#define BKT_SHIFT 8
#define NBKT 391          // ceil(100000/256) buckets of 256 nodes
#define EPB_A 4096        // edges per block in fillA/bhist
#define NBA 391           // ceil(1600000/4096)
#define MAXB 6144         // LDS entry cap per bucket
#define NT64 1563         // ceil(100000/64) row tiles
#define GEMM_GRID 512

typedef short bf16x8 __attribute__((ext_vector_type(8)));
typedef float f32x4 __attribute__((ext_vector_type(4)));
typedef float f32x2 __attribute__((ext_vector_type(2)));

__device__ __forceinline__ unsigned short f2b(float f) {
    unsigned u = __float_as_uint(f);
    unsigned r = u + 0x7FFFu + ((u >> 16) & 1u);
    return (unsigned short)(r >> 16);
}
__device__ __forceinline__ float b2f(unsigned short h) {
    return __uint_as_float(((unsigned)h) << 16);
}
__device__ __forceinline__ float lrelu(float v) {
    return v > 0.f ? v : v * NEG_SLOPE;
}
// OCP e4m3 via gfx950 HW converts
__device__ __forceinline__ unsigned char f2fp8(float f) {
    return (unsigned char)(__builtin_amdgcn_cvt_pk_fp8_f32(f, f, 0, false) & 0xFF);
}

// ---- weight fragments, pre-swizzled to MFMA order ----
// wTs[ct][ki][lane] = bf16x8 { w[k=ki*32+(lane>>4)*8+j][col=ct*16+(lane&15)] }
// (w = [w1 | wd] columns 0..191 -> ct 0..11); w2Ts same with 4 col-tiles.
__global__ void k_prep(const float* __restrict__ w1, const float* __restrict__ wd,
                       const float* __restrict__ w2,
                       unsigned short* __restrict__ wTs, unsigned short* __restrict__ w2Ts) {
    int tid = blockIdx.x * 256 + threadIdx.x;
    if (tid < 3072) {
        int lane = tid & 63;
        int ki = (tid >> 6) & 3;
        int ct = tid >> 8;
        int col = ct * 16 + (lane & 15);
        int kb = ki * 32 + (lane >> 4) * 8;
        unsigned short u[8];
#pragma unroll
        for (int j = 0; j < 8; j++) {
            int k = kb + j;
            float v = (col < 128) ? w1[k * 128 + col] : wd[k * 64 + (col - 128)];
            u[j] = f2b(v);
        }
        *(bf16x8*)&wTs[tid * 8] = *(bf16x8*)u;
    }
    if (tid < 1024) {
        int lane = tid & 63;
        int ki = (tid >> 6) & 3;
        int ct = tid >> 8;
        int col = ct * 16 + (lane & 15);
        int kb = ki * 32 + (lane >> 4) * 8;
        unsigned short u[8];
#pragma unroll
        for (int j = 0; j < 8; j++) u[j] = f2b(w2[(kb + j) * 64 + col]);
        *(bf16x8*)&w2Ts[tid * 8] = *(bf16x8*)u;
    }
}

// ---- bucket-level histogram (391 bins, LDS-aggregated) ----
__global__ __launch_bounds__(256) void k_bhist(const int* __restrict__ dst,
                                               int* __restrict__ bcnt) {
    __shared__ int lcnt[NBKT];
    const int t = threadIdx.x;
    const int e0 = blockIdx.x * EPB_A;
    const int nd = min(EPB_A, N_EDGES - e0);
    for (int i = t; i < NBKT; i += 256) lcnt[i] = 0;
    __syncthreads();
    for (int i = t; i < nd; i += 256) {
        int d = dst[e0 + i];
        atomicAdd(&lcnt[d >> BKT_SHIFT], 1);
    }
    __syncthreads();
    for (int i = t; i < NBKT; i += 256)
        if (lcnt[i]) atomicAdd(&bcnt[i], lcnt[i]);
}

// ---- scan of bucket counts -> bucket bases + cursors (single block) ----
__global__ __launch_bounds__(512) void k_bscan(const int* __restrict__ bcnt,
                                               int* __restrict__ bbase,
                                               int* __restrict__ bcur) {
    __shared__ int sc[512];
    int t = threadIdx.x;
    int v = (t < NBKT) ? bcnt[t] : 0;
    sc[t] = v;
    __syncthreads();
    for (int off = 1; off < 512; off <<= 1) {
        int xv = (t >= off) ? sc[t - off] : 0;
        __syncthreads();
        sc[t] += xv;
        __syncthreads();
    }
    if (t < NBKT) {
        int base = sc[t] - v;
        bbase[t] = base;
        bcur[t] = base;
    }
}

// ---- fillA: coarse bucket scatter of {src, dst} ----
__global__ __launch_bounds__(256) void k_fillA(const int* __restrict__ src,
                                               const int* __restrict__ dst,
                                               int* __restrict__ bcur,
                                               uint2* __restrict__ csr) {
    __shared__ int lcnt[NBKT];
    __shared__ int lbase[NBKT];
    const int t = threadIdx.x;
    const int e0 = blockIdx.x * EPB_A;
    const int nd = min(EPB_A, N_EDGES - e0);
    for (int i = t; i < NBKT; i += 256) lcnt[i] = 0;
    __syncthreads();
    for (int i = t; i < nd; i += 256) {
        int d = dst[e0 + i];
        atomicAdd(&lcnt[d >> BKT_SHIFT], 1);
    }
    __syncthreads();
    for (int i = t; i < NBKT; i += 256)
        lbase[i] = lcnt[i] ? atomicAdd(&bcur[i], lcnt[i]) : 0;
    __syncthreads();
    for (int i = t; i < NBKT; i += 256) lcnt[i] = 0;
    __syncthreads();
    for (int i = t; i < nd; i += 256) {
        int s = src[e0 + i];
        int d = dst[e0 + i];
        int b = d >> BKT_SHIFT;
        int off = atomicAdd(&lcnt[b], 1);
        csr[lbase[b] + off] = make_uint2((unsigned)s, (unsigned)d);
    }
}

// ---- fillB1: per-bucket node counts -> rowptr + dinv (no global atomics) ----
__global__ __launch_bounds__(256) void k_fillB1(const uint2* __restrict__ csr,
                                                const int* __restrict__ bbase,
                                                const int* __restrict__ bcnt,
                                                int* __restrict__ rowptr,
                                                float* __restrict__ dinv) {
    __shared__ int lcnt[256];
    __shared__ int sc[256];
    const int t = threadIdx.x;
    const int b = blockIdx.x;
    const int n0 = b << BKT_SHIFT;
    const int n1 = min(n0 + 256, N_NODES);
    const int R0 = bbase[b];
    const int cntE = bcnt[b];
    lcnt[t] = 0;
    __syncthreads();
    for (int i = t; i < cntE; i += 256) {
        uint2 e = csr[R0 + i];
        atomicAdd(&lcnt[(int)e.y & 255], 1);
    }
    __syncthreads();
    int myc = lcnt[t];
    sc[t] = myc;
    __syncthreads();
    for (int off = 1; off < 256; off <<= 1) {
        int xv = (t >= off) ? sc[t - off] : 0;
        __syncthreads();
        sc[t] += xv;
        __syncthreads();
    }
    if (n0 + t < n1) {
        rowptr[n0 + t] = R0 + sc[t] - myc;
        dinv[n0 + t] = rsqrtf((float)(myc + 1));
    }
    if (b == NBKT - 1 && t == 0) rowptr[N_NODES] = N_EDGES;
}

// ---- fillB2: in-place fine permutation within each bucket ----
__global__ __launch_bounds__(256) void k_fillB2(const float* __restrict__ dinv,
                                                const int* __restrict__ rowptr,
                                                uint2* __restrict__ csr) {
    __shared__ uint2 lbuf[MAXB];
    __shared__ int lcur[256];
    __shared__ int lrp[256];
    const int t = threadIdx.x;
    const int b = blockIdx.x;
    const int n0 = b << BKT_SHIFT;
    const int n1 = min(n0 + 256, N_NODES);
    const int R0 = rowptr[n0], R1 = rowptr[n1];
    const int cnt = R1 - R0;
    for (int i = t; i < cnt; i += 256) lbuf[i] = csr[R0 + i];
    if (n0 + t < n1) lrp[t] = rowptr[n0 + t];
    lcur[t] = 0;
    __syncthreads();  // all region reads complete before any region write
    for (int i = t; i < cnt; i += 256) {
        uint2 e = lbuf[i];
        int li = (int)e.y & 255;
        int r = atomicAdd(&lcur[li], 1);
        int p = lrp[li] + r;
        csr[p] = make_uint2(e.x, __float_as_uint(dinv[e.x]));
    }
}

// ---- MFMA GEMM1: h1 = fp8(x@w1), identity = x@wd + bd ----
// Persistent B-fragments (loaded once, wave-contiguous from wTs), grid-stride
// over 64-row tiles, COALESCED staging (each load instr = 1KB contiguous).
__global__ __launch_bounds__(256, 1) void k_gemm1(const float* __restrict__ x,
                                                  const unsigned short* __restrict__ wTs,
                                                  const float* __restrict__ bd,
                                                  unsigned char* __restrict__ h1,
                                                  float* __restrict__ identity) {
    __shared__ unsigned short As[64][LDA];
    const int t = threadIdx.x;
    const int wid = t >> 6, lane = t & 63;
    const int wr = wid >> 1, wc = wid & 1;
    const int mr = wr * 32, nc = wc * 96;
    const int lrow = lane & 15;
    // persistent B fragments: col-tiles wc*6+n, wave-contiguous loads
    bf16x8 b[6][4];
#pragma unroll
    for (int n = 0; n < 6; n++)
#pragma unroll
        for (int ki = 0; ki < 4; ki++)
            b[n][ki] = *(const bf16x8*)&wTs[(((wc * 6 + n) * 4 + ki) * 64 + lane) * 8];

    for (int tile = blockIdx.x; tile < NT64; tile += GEMM_GRID) {
        const int rb = tile * 64;
        __syncthreads();   // previous iteration's LDS reads complete
        {
            const float* xb = x + (size_t)rb * 128;
#pragma unroll
            for (int i = 0; i < 8; i++) {
                int c = i * 256 + t;         // 16B fp32 chunk id; lane-contiguous
                int row = c >> 5, off = c & 31;
                uint2 wv;
                if (rb + row < N_NODES) {
                    float4 v = *(const float4*)&xb[c * 4];
                    wv.x = (unsigned)f2b(v.x) | ((unsigned)f2b(v.y) << 16);
                    wv.y = (unsigned)f2b(v.z) | ((unsigned)f2b(v.w) << 16);
                } else {
                    wv = make_uint2(0u, 0u);
                }
                *(uint2*)&As[row][off * 4] = wv;
            }
        }
        __syncthreads();
        const int lk = (lane >> 4) * 8;
        bf16x8 a[4][2];
#pragma unroll
        for (int ki = 0; ki < 4; ki++)
#pragma unroll
            for (int m = 0; m < 2; m++)
                a[ki][m] = *(const bf16x8*)&As[mr + m * 16 + lrow][ki * 32 + lk];
        f32x4 acc[2][6];
#pragma unroll
        for (int m = 0; m < 2; m++)
#pragma unroll
            for (int n = 0; n < 6; n++) acc[m][n] = (f32x4){0.f, 0.f, 0.f, 0.f};
#pragma unroll
        for (int n = 0; n < 6; n++)
#pragma unroll
            for (int ki = 0; ki < 4; ki++)
#pragma unroll
                for (int m = 0; m < 2; m++)
                    acc[m][n] = __builtin_amdgcn_mfma_f32_16x16x32_bf16(a[ki][m], b[n][ki], acc[m][n], 0, 0, 0);
        const int crow0 = (lane >> 4) * 4;
#pragma unroll
        for (int m = 0; m < 2; m++) {
#pragma unroll
            for (int j = 0; j < 4; j++) {
                int grow = rb + mr + m * 16 + crow0 + j;
                if (grow >= N_NODES) continue;
#pragma unroll
                for (int n = 0; n < 6; n++) {
                    int col = nc + n * 16 + lrow;
                    float v = acc[m][n][j];
                    if (col < 128) h1[(size_t)grow * 128 + col] = f2fp8(v);
                    else           identity[(size_t)grow * 64 + (col - 128)] = v + bd[col - 128];
                }
            }
        }
    }
}

// ---- MFMA GEMM2: h2 = fp8(out1 @ w2), same persistent/coalesced structure ----
__global__ __launch_bounds__(256, 1) void k_gemm2(const unsigned short* __restrict__ a_in,
                                                  const unsigned short* __restrict__ w2Ts,
                                                  unsigned char* __restrict__ h2) {
    __shared__ unsigned short As[64][LDA];
    const int t = threadIdx.x;
    const int wid = t >> 6, lane = t & 63;
    const int wr = wid >> 1, wc = wid & 1;
    const int mr = wr * 32, nc = wc * 32;
    const int lrow = lane & 15;
    bf16x8 b[2][4];
#pragma unroll
    for (int n = 0; n < 2; n++)
#pragma unroll
        for (int ki = 0; ki < 4; ki++)
            b[n][ki] = *(const bf16x8*)&w2Ts[(((wc * 2 + n) * 4 + ki) * 64 + lane) * 8];

    for (int tile = blockIdx.x; tile < NT64; tile += GEMM_GRID) {
        const int rb = tile * 64;
        __syncthreads();
        {
#pragma unroll
            for (int i = 0; i < 4; i++) {
                int c = i * 256 + t;         // 16B bf16 chunk id; lane-contiguous
                int row = c >> 4, off = c & 15;
                bf16x8 v = (bf16x8){0, 0, 0, 0, 0, 0, 0, 0};
                if (rb + row < N_NODES)
                    v = *(const bf16x8*)&a_in[(size_t)(rb + row) * 128 + off * 8];
                *(bf16x8*)&As[row][off * 8] = v;
            }
        }
        __syncthreads();
        const int lk = (lane >> 4) * 8;
        bf16x8 a[4][2];
#pragma unroll
        for (int ki = 0; ki < 4; ki++)
#pragma unroll
            for (int m = 0; m < 2; m++)
                a[ki][m] = *(const bf16x8*)&As[mr + m * 16 + lrow][ki * 32 + lk];
        f32x4 acc[2][2];
#pragma unroll
        for (int m = 0; m < 2; m++)
#pragma unroll
            for (int n = 0; n < 2; n++) acc[m][n] = (f32x4){0.f, 0.f, 0.f, 0.f};
#pragma unroll
        for (int n = 0; n < 2; n++)
#pragma unroll
            for (int ki = 0; ki < 4; ki++)
#pragma unroll
                for (int m = 0; m < 2; m++)
                    acc[m][n] = __builtin_amdgcn_mfma_f32_16x16x32_bf16(a[ki][m], b[n][ki], acc[m][n], 0, 0, 0);
        const int crow0 = (lane >> 4) * 4;
#pragma unroll
        for (int m = 0; m < 2; m++) {
#pragma unroll
            for (int j = 0; j < 4; j++) {
                int grow = rb + mr + m * 16 + crow0 + j;
                if (grow >= N_NODES) continue;
#pragma unroll
                for (int n = 0; n < 2; n++) {
                    int col = nc + n * 16 + lrow;
                    h2[(size_t)grow * 64 + col] = f2fp8(acc[m][n][j]);
                }
            }
        }
    }
}

// ---- aggregate 1: out1 = leaky(di*(sum_e dinv_s*h1[src] + di*h1[i]) + b1) ----
// wave = 1 node; 8 groups x 8 lanes; reduce-scatter butterfly + distributed epilogue
__global__ __launch_bounds__(256) void k_agg1(const unsigned char* __restrict__ h1,
                                              const uint2* __restrict__ csr,
                                              const int* __restrict__ rowptr,
                                              const float* __restrict__ dinv,
                                              const float* __restrict__ b1,
                                              unsigned short* __restrict__ out1) {
    int node = blockIdx.x * 4 + (threadIdx.x >> 6);
    if (node >= N_NODES) return;
    const int lane = threadIdx.x & 63;
    const int g = lane >> 3;   // edge slot 0..7
    const int l = lane & 7;    // feature chunk: [l*16, l*16+16)
    const float di = dinv[node];
    f32x2 a2[8];
#pragma unroll
    for (int i = 0; i < 8; i++) a2[i] = (f32x2){0.f, 0.f};
    const int beg = rowptr[node], end = rowptr[node + 1];
    uint2 ce = csr[beg + g];                 // csr padded with 16 zeroed entries
    for (int e0 = beg; e0 < end; e0 += 8) {
        uint2 ce_n = csr[e0 + 8 + g];        // prefetch next iteration's entry
        int e = e0 + g;
        if (e < end) {
            float w = __uint_as_float(ce.y);  // dinv[src]; di folded into epilogue
            f32x2 w2 = (f32x2){w, w};
            uint4 h = *(const uint4*)&h1[(size_t)ce.x * 128 + l * 16];
            a2[0] = __builtin_elementwise_fma(w2, __builtin_amdgcn_cvt_pk_f32_fp8(h.x, false), a2[0]);
            a2[1] = __builtin_elementwise_fma(w2, __builtin_amdgcn_cvt_pk_f32_fp8(h.x, true),  a2[1]);
            a2[2] = __builtin_elementwise_fma(w2, __builtin_amdgcn_cvt_pk_f32_fp8(h.y, false), a2[2]);
            a2[3] = __builtin_elementwise_fma(w2, __builtin_amdgcn_cvt_pk_f32_fp8(h.y, true),  a2[3]);
            a2[4] = __builtin_elementwise_fma(w2, __builtin_amdgcn_cvt_pk_f32_fp8(h.z, false), a2[4]);
            a2[5] = __builtin_elementwise_fma(w2, __builtin_amdgcn_cvt_pk_f32_fp8(h.z, true),  a2[5]);
            a2[6] = __builtin_elementwise_fma(w2, __builtin_amdgcn_cvt_pk_f32_fp8(h.w, false), a2[6]);
            a2[7] = __builtin_elementwise_fma(w2, __builtin_amdgcn_cvt_pk_f32_fp8(h.w, true),  a2[7]);
        }
        ce = ce_n;
    }
    // reduce-scatter butterfly over group bits g2 (xor32), g1 (xor16), g0 (xor8)
    const bool s2 = (lane & 32) != 0;
    const bool s1 = (lane & 16) != 0;
    const bool s0 = (lane & 8) != 0;
    f32x2 rA[4];
#pragma unroll
    for (int j = 0; j < 4; j++) {
        f32x2 keep = s2 ? a2[j + 4] : a2[j];
        f32x2 send = s2 ? a2[j] : a2[j + 4];
        rA[j].x = keep.x + __shfl_xor(send.x, 32);
        rA[j].y = keep.y + __shfl_xor(send.y, 32);
    }
    f32x2 rB[2];
#pragma unroll
    for (int j = 0; j < 2; j++) {
        f32x2 keep = s1 ? rA[j + 2] : rA[j];
        f32x2 send = s1 ? rA[j] : rA[j + 2];
        rB[j].x = keep.x + __shfl_xor(send.x, 16);
        rB[j].y = keep.y + __shfl_xor(send.y, 16);
    }
    f32x2 rC;
    {
        f32x2 keep = s0 ? rB[1] : rB[0];
        f32x2 send = s0 ? rB[0] : rB[1];
        rC.x = keep.x + __shfl_xor(send.x, 8);
        rC.y = keep.y + __shfl_xor(send.y, 8);
    }
    // distributed epilogue: this lane owns feats f0, f0+1 with values rC
    {
        const int f0 = l * 16 + g * 2;
        unsigned hs = (unsigned)*(const unsigned short*)&h1[(size_t)node * 128 + f0];
        f32x2 sv = __builtin_amdgcn_cvt_pk_f32_fp8(hs, false);
        float2 bb = *(const float2*)&b1[f0];
        float t0 = rC.x + di * sv.x;
        float t1 = rC.y + di * sv.y;
        float o0 = lrelu(fmaf(t0, di, bb.x));
        float o1 = lrelu(fmaf(t1, di, bb.y));
        unsigned ov = (unsigned)f2b(o0) | ((unsigned)f2b(o1) << 16);
        *(unsigned*)&out1[(size_t)node * 128 + f0] = ov;
    }
}

// ---- aggregate 2 + epilogue: out = leaky(di*(agg + di*h_self) + b2) + identity ----
// wave = 1 node; 8 groups x 8 lanes; reduce-scatter; lane (g,l) writes feat l*8+g
__global__ __launch_bounds__(256) void k_agg2(const unsigned char* __restrict__ h2,
                                              const uint2* __restrict__ csr,
                                              const int* __restrict__ rowptr,
                                              const float* __restrict__ dinv,
                                              const float* __restrict__ b2,
                                              const float* __restrict__ identity,
                                              float* __restrict__ out) {
    int node = blockIdx.x * 4 + (threadIdx.x >> 6);
    if (node >= N_NODES) return;
    const int lane = threadIdx.x & 63;
    const int g = lane >> 3;
    const int l = lane & 7;    // feature chunk: [l*8, l*8+8)
    const float di = dinv[node];
    f32x2 a2[4];
#pragma unroll
    for (int i = 0; i < 4; i++) a2[i] = (f32x2){0.f, 0.f};
    const int beg = rowptr[node], end = rowptr[node + 1];
    uint2 ce = csr[beg + g];
    for (int e0 = beg; e0 < end; e0 += 8) {
        uint2 ce_n = csr[e0 + 8 + g];
        int e = e0 + g;
        if (e < end) {
            float w = __uint_as_float(ce.y);  // dinv[src]
            f32x2 w2 = (f32x2){w, w};
            uint2 h = *(const uint2*)&h2[(size_t)ce.x * 64 + l * 8];
            a2[0] = __builtin_elementwise_fma(w2, __builtin_amdgcn_cvt_pk_f32_fp8(h.x, false), a2[0]);
            a2[1] = __builtin_elementwise_fma(w2, __builtin_amdgcn_cvt_pk_f32_fp8(h.x, true),  a2[1]);
            a2[2] = __builtin_elementwise_fma(w2, __builtin_amdgcn_cvt_pk_f32_fp8(h.y, false), a2[2]);
            a2[3] = __builtin_elementwise_fma(w2, __builtin_amdgcn_cvt_pk_f32_fp8(h.y, true),  a2[3]);
        }
        ce = ce_n;
    }
    float a[8];
#pragma unroll
    for (int i = 0; i < 4; i++) { a[2 * i] = a2[i].x; a[2 * i + 1] = a2[i].y; }
    // reduce-scatter over group bits
    const bool s2 = (lane & 32) != 0;
    const bool s1 = (lane & 16) != 0;
    const bool s0 = (lane & 8) != 0;
    float kA[4];
#pragma unroll
    for (int j = 0; j < 4; j++) {
        float keep = s2 ? a[j + 4] : a[j];
        float send = s2 ? a[j] : a[j + 4];
        kA[j] = keep + __shfl_xor(send, 32);
    }
    float kB[2];
#pragma unroll
    for (int j = 0; j < 2; j++) {
        float keep = s1 ? kA[j + 2] : kA[j];
        float send = s1 ? kA[j] : kA[j + 2];
        kB[j] = keep + __shfl_xor(send, 16);
    }
    float kC;
    {
        float keep = s0 ? kB[1] : kB[0];
        float send = s0 ? kB[0] : kB[1];
        kC = keep + __shfl_xor(send, 8);
    }
    // distributed epilogue: this lane owns feat f0 = l*8 + g with value kC
    {
        const int f0 = l * 8 + g;
        unsigned c = (unsigned)h2[(size_t)node * 64 + f0];
        f32x2 svv = __builtin_amdgcn_cvt_pk_f32_fp8(c, false);
        float sv = svv.x;
        float t = kC + di * sv;
        float o = lrelu(fmaf(t, di, b2[f0])) + identity[(size_t)node * 64 + f0];
        out[(size_t)node * 64 + f0] = o;
    }
}

extern "C" void kernel_launch(void* const* d_in, const int* in_sizes, int n_in,
                              void* d_out, int out_size, void* d_ws, size_t ws_size,
                              hipStream_t stream) {
    const float* x  = (const float*)d_in[0];
    const int* eidx = (const int*)d_in[1];
    const float* w1 = (const float*)d_in[2];
    const float* b1 = (const float*)d_in[3];
    const float* w2 = (const float*)d_in[4];
    const float* b2 = (const float*)d_in[5];
    const float* wd = (const float*)d_in[6];
    const float* bd = (const float*)d_in[7];
    const int* src = eidx;
    const int* dst = eidx + N_EDGES;
    float* out = (float*)d_out;

    char* ws = (char*)d_ws;
    size_t off = 0;
    auto take = [&](size_t bytes) -> char* {
        char* p = ws + off;
        off = (off + bytes + 255) & ~(size_t)255;
        return p;
    };
    int* bcnt       = (int*)take((size_t)NBKT * 4);
    int* bbase      = (int*)take((size_t)NBKT * 4);
    int* bcur       = (int*)take((size_t)NBKT * 4);
    int* rowptr     = (int*)take((size_t)(N_NODES + 1) * 4);
    float* dinv     = (float*)take((size_t)N_NODES * 4);
    uint2* csr      = (uint2*)take((size_t)(N_EDGES + 16) * 8);  // +16 zeroed pad entries
    unsigned char* h1   = (unsigned char*)take((size_t)N_NODES * 128);
    unsigned short* out1 = (unsigned short*)take((size_t)N_NODES * 128 * 2);
    unsigned char* h2   = (unsigned char*)take((size_t)N_NODES * 64);
    float* identity = (float*)take((size_t)N_NODES * 64 * 4);
    unsigned short* wTs  = (unsigned short*)take((size_t)3072 * 8 * 2);
    unsigned short* w2Ts = (unsigned short*)take((size_t)1024 * 8 * 2);

    hipMemsetAsync(bcnt, 0, (size_t)NBKT * 4, stream);
    hipMemsetAsync(csr + N_EDGES, 0, 16 * sizeof(uint2), stream);

    k_prep<<<12, 256, 0, stream>>>(w1, wd, w2, wTs, w2Ts);
    k_bhist<<<NBA, 256, 0, stream>>>(dst, bcnt);
    k_bscan<<<1, 512, 0, stream>>>(bcnt, bbase, bcur);
    k_fillA<<<NBA, 256, 0, stream>>>(src, dst, bcur, csr);
    k_fillB1<<<NBKT, 256, 0, stream>>>(csr, bbase, bcnt, rowptr, dinv);
    k_fillB2<<<NBKT, 256, 0, stream>>>(dinv, rowptr, csr);
    k_gemm1<<<GEMM_GRID, 256, 0, stream>>>(x, wTs, bd, h1, identity);
    k_agg1<<<(N_NODES + 3) / 4, 256, 0, stream>>>(h1, csr, rowptr, dinv, b1, out1);
    k_gemm2<<<GEMM_GRID, 256, 0, stream>>>(out1, w2Ts, h2);
    k_agg2<<<(N_NODES + 3) / 4, 256, 0, stream>>>(h2, csr, rowptr, dinv, b2, identity, out);
}